// Round 1
// baseline (496.503 us; speedup 1.0000x reference)
//
#include <hip/hip_runtime.h>
#include <cstdint>
#include <cstddef>

// ---------------------------------------------------------------------------
// QBasicBlock: qconv3x3(s2) -> inorm -> quant_a -> qconv3x3(s1) -> inorm
//            + qconv1x1(s2) -> inorm  (shortcut), output sum, NCHW f32.
// Strategy: bf16 implicit-GEMM convs on MFMA, NHWC internal layout.
// ---------------------------------------------------------------------------

typedef unsigned short ushort_t;
typedef __attribute__((ext_vector_type(8))) short bf16x8;
typedef __attribute__((ext_vector_type(4))) float f32x4;

// ---- problem constants ----
#define NB   32
#define C_IN 256
#define HIN  56
#define CO   512
#define OHW  784           // 28*28
#define OWD  28
#define MTOT (NB * OHW)    // 25088

// ---- workspace layout (bytes) ----
constexpr size_t OFF_XH   = 0;                        // x NHWC bf16: 32*56*56*256
constexpr size_t OFF_A1   = OFF_XH  + 51380224;       // a1 NHWC bf16: 32*784*512
constexpr size_t OFF_H2   = OFF_A1  + 25690112;       // h2 NHWC f32
constexpr size_t OFF_S    = OFF_H2  + 51380224;       // shortcut NHWC f32
constexpr size_t OFF_WT1  = OFF_S   + 51380224;       // wt1 bf16 [9][512][256]
constexpr size_t OFF_WT2  = OFF_WT1 + 2359296;        // wt2 bf16 [9][512][512]
constexpr size_t OFF_WTP  = OFF_WT2 + 4718592;        // wtp bf16 [1][512][256]
constexpr size_t OFF_PSUM = OFF_WTP + 262144;         // [32][8][512] f32
constexpr size_t OFF_PSS  = OFF_PSUM + 524288;
constexpr size_t OFF_A1N  = OFF_PSS  + 524288;        // per-(n,c) affine, 16384 f32 each
constexpr size_t OFF_B1N  = OFF_A1N + 65536;
constexpr size_t OFF_A2N  = OFF_B1N + 65536;
constexpr size_t OFF_B2N  = OFF_A2N + 65536;
constexpr size_t OFF_APN  = OFF_B2N + 65536;
constexpr size_t OFF_BPN  = OFF_APN + 65536;
constexpr size_t OFF_MX   = OFF_BPN + 65536;          // 3 uint absmax slots (16 B)
constexpr size_t OFF_ZB   = OFF_MX  + 16;             // 256 B zero page for OOB rows

// ---- helpers ----
__device__ __forceinline__ ushort_t f2bf(float f) {  // RNE f32->bf16
    unsigned u = __float_as_uint(f);
    u += 0x7FFFu + ((u >> 16) & 1u);
    return (ushort_t)(u >> 16);
}

__device__ __forceinline__ void async_copy16(const void* g, const void* l) {
    // global -> LDS direct copy, 16 B per lane. LDS dest is wave-uniform base
    // + lane*16 (hardware); global src is per-lane.
    auto gp = (const __attribute__((address_space(1))) unsigned int*)(uintptr_t)g;
    auto lp = (__attribute__((address_space(3))) unsigned int*)(unsigned int)(uintptr_t)l;
    __builtin_amdgcn_global_load_lds(gp, lp, 16, 0, 0);
}

// ---------------------------------------------------------------------------
// 1) x NCHW f32 -> NHWC bf16 (LDS tile transpose, coalesced both sides)
// ---------------------------------------------------------------------------
__global__ void to_nhwc_k(const float* __restrict__ x, ushort_t* __restrict__ xh) {
    __shared__ float tile[32][33];
    const int wt0 = blockIdx.x * 32;           // w tile: 0 or 32 (56 wide)
    const int ct0 = blockIdx.y * 32;           // c tile
    const int nh  = blockIdx.z;                // n*56 + h
    const int n = nh / HIN, h = nh - n * HIN;
    const int tx = threadIdx.x & 31;
    const int ty = threadIdx.x >> 5;
#pragma unroll
    for (int j = 0; j < 4; ++j) {
        int cl = ty + j * 8;
        int w  = wt0 + tx;
        if (w < HIN)
            tile[cl][tx] = x[(((size_t)n * C_IN + ct0 + cl) * HIN + h) * HIN + w];
    }
    __syncthreads();
#pragma unroll
    for (int j = 0; j < 4; ++j) {
        int wl = ty + j * 8;
        int w  = wt0 + wl;
        if (w < HIN)
            xh[(((size_t)n * HIN + h) * HIN + w) * C_IN + ct0 + tx] = f2bf(tile[tx][wl]);
    }
}

// ---------------------------------------------------------------------------
// 2) per-tensor |w| max (wave shuffle reduce + uint atomicMax)
// ---------------------------------------------------------------------------
__global__ void absmax_k(const float* __restrict__ w, int nelem, unsigned* out) {
    int stride = gridDim.x * blockDim.x;
    float m = 0.f;
    for (int i = blockIdx.x * blockDim.x + threadIdx.x; i < nelem; i += stride)
        m = fmaxf(m, fabsf(w[i]));
#pragma unroll
    for (int off = 32; off > 0; off >>= 1)
        m = fmaxf(m, __shfl_down(m, off));
    if ((threadIdx.x & 63) == 0) atomicMax(out, __float_as_uint(m));
}

// ---------------------------------------------------------------------------
// 3) quantize weights (symmetric per-tensor, qmax=127) and transform
//    OIHW f32 -> [kh*kw][co][ci] bf16 (ci contiguous for staging)
// ---------------------------------------------------------------------------
template <int CO_, int CI_, int KHW_>
__global__ void quantw_k(const float* __restrict__ w, const unsigned* __restrict__ mx,
                         ushort_t* __restrict__ wt) {
    const int total = KHW_ * CO_ * CI_;
    int idx = blockIdx.x * 256 + threadIdx.x;
    if (idx >= total) return;
    float scale = __uint_as_float(*mx) * (1.0f / 127.0f);
    float inv   = scale > 0.f ? 1.0f / scale : 0.f;
    int khw = idx / (CO_ * CI_);
    int r   = idx - khw * (CO_ * CI_);
    int co  = r / CI_;
    int ci  = r - co * CI_;
    float v  = w[((size_t)co * CI_ + ci) * KHW_ + khw];
    float qv = rintf(v * inv);
    qv = fminf(127.f, fmaxf(-127.f, qv));
    wt[idx] = f2bf(qv * scale);
}

// ---------------------------------------------------------------------------
// 4) implicit-GEMM conv: out[M=n*oh*ow][CO] f32 (NHWC) = gather(x) * wt
//    128x128 tile, BK=64, 4 waves (2x2 of 64x64), mfma 16x16x32 bf16.
//    global_load_lds staging with XOR-swizzled global source (rule #21);
//    padding handled by zero-page redirect.
// ---------------------------------------------------------------------------
template <int CIN, int KH, int KW, int STRIDE, int PAD, int IH, int IW>
__launch_bounds__(256, 2)
__global__ void conv_gemm_k(const ushort_t* __restrict__ xin,
                            const ushort_t* __restrict__ wt,
                            float* __restrict__ out,
                            const ushort_t* __restrict__ zbuf) {
    constexpr int BK  = 64;
    constexpr int CKT = CIN / BK;
    constexpr int KT  = KH * KW * CKT;

    __shared__ alignas(16) short As[128 * BK];
    __shared__ alignas(16) short Bs[128 * BK];

    const int tid  = threadIdx.x;
    const int lane = tid & 63;
    const int wv   = tid >> 6;
    const int lrow = lane & 15;
    const int q    = lane >> 4;
    const int wm   = wv >> 1;
    const int wn   = wv & 1;
    const int sw   = lrow & 7;

    const int m0  = blockIdx.x * 128;
    const int co0 = blockIdx.y * 128;

    int nbase[4], ihb[4], iwb[4], aoff[4], brow[4], boff[4];
#pragma unroll
    for (int i = 0; i < 4; ++i) {
        int f    = i * 256 + tid;          // 16B slot in tile, 0..1023
        int row  = f >> 3;
        int ch   = f & 7;
        int m    = m0 + row;
        int n    = m / OHW;
        int sp   = m - n * OHW;
        int oh   = sp / OWD;
        int ow   = sp - oh * OWD;
        nbase[i] = n * (IH * IW);
        ihb[i]   = oh * STRIDE - PAD;
        iwb[i]   = ow * STRIDE - PAD;
        aoff[i]  = (ch ^ (row & 7)) * 8;   // pre-swizzled source chunk (elems)
        brow[i]  = row;
        boff[i]  = (ch ^ (row & 7)) * 8;
    }

    f32x4 acc[4][4];
#pragma unroll
    for (int a = 0; a < 4; ++a)
#pragma unroll
        for (int b = 0; b < 4; ++b) acc[a][b] = {0.f, 0.f, 0.f, 0.f};

    for (int kt = 0; kt < KT; ++kt) {
        const int khw = kt / CKT;
        const int ci0 = (kt - khw * CKT) * BK;
        const int kh  = khw / KW;
        const int kw2 = khw - kh * KW;

#pragma unroll
        for (int i = 0; i < 4; ++i) {   // A tile: gathered activations
            const int ih = ihb[i] + kh;
            const int iw = iwb[i] + kw2;
            const bool ok = ((unsigned)ih < (unsigned)IH) & ((unsigned)iw < (unsigned)IW);
            const ushort_t* src = ok
                ? xin + (size_t)(nbase[i] + ih * IW + iw) * CIN + (ci0 + aoff[i])
                : zbuf;
            async_copy16(src, (const void*)&As[i * 2048 + wv * 512]);
        }
#pragma unroll
        for (int i = 0; i < 4; ++i) {   // B tile: weights [co][ci]
            const ushort_t* src =
                wt + ((size_t)khw * CO + co0 + brow[i]) * CIN + (ci0 + boff[i]);
            async_copy16(src, (const void*)&Bs[i * 2048 + wv * 512]);
        }
        __syncthreads();

#pragma unroll
        for (int s = 0; s < 2; ++s) {
            const int ch = ((s << 2) + q) ^ sw;   // swizzled chunk for this lane
            bf16x8 af[4], bfr[4];
#pragma unroll
            for (int mi = 0; mi < 4; ++mi) {
                int row = wm * 64 + mi * 16 + lrow;
                af[mi] = *(const bf16x8*)&As[row * BK + ch * 8];
            }
#pragma unroll
            for (int ni = 0; ni < 4; ++ni) {
                int row = wn * 64 + ni * 16 + lrow;
                bfr[ni] = *(const bf16x8*)&Bs[row * BK + ch * 8];
            }
#pragma unroll
            for (int mi = 0; mi < 4; ++mi)
#pragma unroll
                for (int ni = 0; ni < 4; ++ni)
                    acc[mi][ni] = __builtin_amdgcn_mfma_f32_16x16x32_bf16(
                        af[mi], bfr[ni], acc[mi][ni], 0, 0, 0);
        }
        __syncthreads();
    }

    // epilogue: D layout col=lane&15, row=(lane>>4)*4+reg
    const int mb = m0 + wm * 64 + q * 4;
    const int cb = co0 + wn * 64 + lrow;
#pragma unroll
    for (int mi = 0; mi < 4; ++mi)
#pragma unroll
        for (int ni = 0; ni < 4; ++ni)
#pragma unroll
            for (int r = 0; r < 4; ++r)
                out[(size_t)(mb + mi * 16 + r) * CO + (cb + ni * 16)] = acc[mi][ni][r];
}

// ---------------------------------------------------------------------------
// 5) instance-norm stats: partial sum/sumsq per (n, c) over spatial chunks
// ---------------------------------------------------------------------------
__global__ void stats_partial_k(const float* __restrict__ h,
                                float* __restrict__ psum, float* __restrict__ pss) {
    const int chunk = blockIdx.x;   // 0..7  (98 rows each)
    const int n     = blockIdx.y;
    const int c0    = threadIdx.x * 2;
    const float* base = h + ((size_t)n * OHW + chunk * 98) * CO + c0;
    float s0 = 0, ss0 = 0, s1 = 0, ss1 = 0;
    for (int r = 0; r < 98; ++r) {
        float2 v = *(const float2*)(base + (size_t)r * CO);
        s0 += v.x; ss0 += v.x * v.x;
        s1 += v.y; ss1 += v.y * v.y;
    }
    size_t o = ((size_t)n * 8 + chunk) * CO + c0;
    psum[o] = s0; psum[o + 1] = s1;
    pss[o]  = ss0; pss[o + 1] = ss1;
}

__global__ void stats_final_k(const float* __restrict__ psum, const float* __restrict__ pss,
                              const float* __restrict__ g, const float* __restrict__ b,
                              float* __restrict__ aout, float* __restrict__ bout) {
    int idx = blockIdx.x * 256 + threadIdx.x;   // 32*512
    int n = idx >> 9, c = idx & 511;
    float s = 0, ss = 0;
#pragma unroll
    for (int j = 0; j < 8; ++j) {
        s  += psum[((size_t)n * 8 + j) * CO + c];
        ss += pss[((size_t)n * 8 + j) * CO + c];
    }
    float mean = s * (1.0f / 784.0f);
    float var  = ss * (1.0f / 784.0f) - mean * mean;
    float rstd = rsqrtf(var + 1e-5f);
    float a = rstd * g[c];
    aout[idx] = a;
    bout[idx] = b[c] - mean * a;
}

// ---------------------------------------------------------------------------
// 6) apply norm1 + quant_a -> bf16 NHWC (input to conv2)
// ---------------------------------------------------------------------------
__device__ __forceinline__ float qact(float xn) {
    float xc = fminf(fmaxf(xn, 0.f), 1.f);
    return rintf(xc * 255.f) / 255.f;
}

__global__ void norm_quant_k(const float* __restrict__ h, const float* __restrict__ a_,
                             const float* __restrict__ b_, ushort_t* __restrict__ o) {
    int idx = blockIdx.x * 256 + threadIdx.x;   // over M*512/4
    int row = idx >> 7;
    int c0  = (idx & 127) * 4;
    int n   = row / OHW;
    float4 v = ((const float4*)h)[idx];
    const float* ap = a_ + n * CO + c0;
    const float* bp = b_ + n * CO + c0;
    ushort4 r;
    r.x = f2bf(qact(v.x * ap[0] + bp[0]));
    r.y = f2bf(qact(v.y * ap[1] + bp[1]));
    r.z = f2bf(qact(v.z * ap[2] + bp[2]));
    r.w = f2bf(qact(v.w * ap[3] + bp[3]));
    ((ushort4*)o)[idx] = r;
}

// ---------------------------------------------------------------------------
// 7) final: out NCHW = norm2(h2) + normp(s), NHWC->NCHW via LDS transpose
// ---------------------------------------------------------------------------
__global__ void final_k(const float* __restrict__ h2, const float* __restrict__ s,
                        const float* __restrict__ a2, const float* __restrict__ b2,
                        const float* __restrict__ ap_, const float* __restrict__ bp_,
                        float* __restrict__ out) {
    __shared__ float tile[32][33];
    const int sp0 = blockIdx.x * 32;    // 25 tiles (last covers 16)
    const int c0  = blockIdx.y * 32;
    const int n   = blockIdx.z;
    const int tx  = threadIdx.x & 31;
    const int ty  = threadIdx.x >> 5;
#pragma unroll
    for (int j = 0; j < 4; ++j) {
        int spl = ty + j * 8;
        int sp  = sp0 + spl;
        if (sp < OHW) {
            int c = c0 + tx;
            size_t ix = ((size_t)n * OHW + sp) * CO + c;
            int ci = n * CO + c;
            tile[spl][tx] = h2[ix] * a2[ci] + b2[ci] + s[ix] * ap_[ci] + bp_[ci];
        }
    }
    __syncthreads();
#pragma unroll
    for (int j = 0; j < 4; ++j) {
        int cl = ty + j * 8;
        int sp = sp0 + tx;
        if (sp < OHW)
            out[((size_t)n * CO + c0 + cl) * OHW + sp] = tile[tx][cl];
    }
}

// ---------------------------------------------------------------------------
extern "C" void kernel_launch(void* const* d_in, const int* in_sizes, int n_in,
                              void* d_out, int out_size, void* d_ws, size_t ws_size,
                              hipStream_t stream) {
    const float* x  = (const float*)d_in[0];
    const float* w1 = (const float*)d_in[1];
    const float* g1 = (const float*)d_in[2];
    const float* b1 = (const float*)d_in[3];
    const float* w2 = (const float*)d_in[4];
    const float* g2 = (const float*)d_in[5];
    const float* b2 = (const float*)d_in[6];
    const float* wp = (const float*)d_in[7];
    const float* gp = (const float*)d_in[8];
    const float* bp = (const float*)d_in[9];
    float* out = (float*)d_out;
    char* ws = (char*)d_ws;

    ushort_t* xh   = (ushort_t*)(ws + OFF_XH);
    ushort_t* a1   = (ushort_t*)(ws + OFF_A1);
    float*    h2   = (float*)(ws + OFF_H2);
    float*    sbuf = (float*)(ws + OFF_S);
    ushort_t* wt1  = (ushort_t*)(ws + OFF_WT1);
    ushort_t* wt2  = (ushort_t*)(ws + OFF_WT2);
    ushort_t* wtp  = (ushort_t*)(ws + OFF_WTP);
    float*    psum = (float*)(ws + OFF_PSUM);
    float*    pss  = (float*)(ws + OFF_PSS);
    float*    a1n  = (float*)(ws + OFF_A1N);
    float*    b1n  = (float*)(ws + OFF_B1N);
    float*    a2n  = (float*)(ws + OFF_A2N);
    float*    b2n  = (float*)(ws + OFF_B2N);
    float*    apn  = (float*)(ws + OFF_APN);
    float*    bpn  = (float*)(ws + OFF_BPN);
    unsigned* mx   = (unsigned*)(ws + OFF_MX);
    ushort_t* zb   = (ushort_t*)(ws + OFF_ZB);
    float*    h1   = out;   // d_out doubles as conv1 output scratch (dead
                            // before final_k writes the real output)

    hipMemsetAsync(ws + OFF_MX, 0, 16 + 256, stream);   // absmax slots + zero page

    // layout transform + weight quant
    to_nhwc_k<<<dim3(2, 8, NB * HIN), 256, 0, stream>>>(x, xh);
    absmax_k<<<dim3(512), 256, 0, stream>>>(w1, CO * C_IN * 9, mx + 0);
    absmax_k<<<dim3(512), 256, 0, stream>>>(w2, CO * CO * 9, mx + 1);
    absmax_k<<<dim3(512), 256, 0, stream>>>(wp, CO * C_IN, mx + 2);
    quantw_k<CO, C_IN, 9><<<dim3(4608), 256, 0, stream>>>(w1, mx + 0, wt1);
    quantw_k<CO, CO, 9><<<dim3(9216), 256, 0, stream>>>(w2, mx + 1, wt2);
    quantw_k<CO, C_IN, 1><<<dim3(512), 256, 0, stream>>>(wp, mx + 2, wtp);

    // conv1 (3x3 s2 p1, 256->512) -> h1 (in d_out)
    conv_gemm_k<C_IN, 3, 3, 2, 1, HIN, HIN>
        <<<dim3(MTOT / 128, 4), 256, 0, stream>>>(xh, wt1, h1, zb);
    stats_partial_k<<<dim3(8, NB), 256, 0, stream>>>(h1, psum, pss);
    stats_final_k<<<dim3(64), 256, 0, stream>>>(psum, pss, g1, b1, a1n, b1n);
    norm_quant_k<<<dim3(MTOT * CO / 4 / 256), 256, 0, stream>>>(h1, a1n, b1n, a1);

    // conv2 (3x3 s1 p1, 512->512) -> h2
    conv_gemm_k<CO, 3, 3, 1, 1, 28, 28>
        <<<dim3(MTOT / 128, 4), 256, 0, stream>>>(a1, wt2, h2, zb);
    // shortcut conv (1x1 s2, 256->512) -> s
    conv_gemm_k<C_IN, 1, 1, 2, 0, HIN, HIN>
        <<<dim3(MTOT / 128, 4), 256, 0, stream>>>(xh, wtp, sbuf, zb);

    stats_partial_k<<<dim3(8, NB), 256, 0, stream>>>(h2, psum, pss);
    stats_final_k<<<dim3(64), 256, 0, stream>>>(psum, pss, g2, b2, a2n, b2n);
    stats_partial_k<<<dim3(8, NB), 256, 0, stream>>>(sbuf, psum, pss);
    stats_final_k<<<dim3(64), 256, 0, stream>>>(psum, pss, gp, bp, apn, bpn);

    final_k<<<dim3(25, 16, NB), 256, 0, stream>>>(h2, sbuf, a2n, b2n, apn, bpn, out);
}

// Round 2
// 459.673 us; speedup vs baseline: 1.0801x; 1.0801x over previous
//
#include <hip/hip_runtime.h>
#include <cstdint>
#include <cstddef>

// ---------------------------------------------------------------------------
// QBasicBlock: qconv3x3(s2) -> inorm -> quant_a -> qconv3x3(s1) -> inorm
//            + qconv1x1(s2) -> inorm  (shortcut), output sum, NCHW f32.
// Strategy: bf16 implicit-GEMM convs on MFMA, NHWC internal layout.
// R2: hoisted gather addressing (masks + base ptrs, khw unrolled),
//     XCD-grouped block swizzle, coalesced to_nhwc, wider stats grid.
// ---------------------------------------------------------------------------

typedef unsigned short ushort_t;
typedef __attribute__((ext_vector_type(8))) short bf16x8;
typedef __attribute__((ext_vector_type(4))) float f32x4;

// ---- problem constants ----
#define NB   32
#define C_IN 256
#define HIN  56
#define CO   512
#define OHW  784           // 28*28
#define OWD  28
#define MTOT (NB * OHW)    // 25088

// ---- workspace layout (bytes) ----
constexpr size_t OFF_XH   = 0;                        // x NHWC bf16: 32*56*56*256
constexpr size_t OFF_A1   = OFF_XH  + 51380224;       // a1 NHWC bf16: 32*784*512
constexpr size_t OFF_H2   = OFF_A1  + 25690112;       // h2 NHWC f32
constexpr size_t OFF_S    = OFF_H2  + 51380224;       // shortcut NHWC f32
constexpr size_t OFF_WT1  = OFF_S   + 51380224;       // wt1 bf16 [9][512][256]
constexpr size_t OFF_WT2  = OFF_WT1 + 2359296;        // wt2 bf16 [9][512][512]
constexpr size_t OFF_WTP  = OFF_WT2 + 4718592;        // wtp bf16 [1][512][256]
constexpr size_t OFF_PSUM = OFF_WTP + 262144;         // [32][16][512] f32
constexpr size_t OFF_PSS  = OFF_PSUM + 1048576;
constexpr size_t OFF_A1N  = OFF_PSS  + 1048576;       // per-(n,c) affine, 16384 f32 each
constexpr size_t OFF_B1N  = OFF_A1N + 65536;
constexpr size_t OFF_A2N  = OFF_B1N + 65536;
constexpr size_t OFF_B2N  = OFF_A2N + 65536;
constexpr size_t OFF_APN  = OFF_B2N + 65536;
constexpr size_t OFF_BPN  = OFF_APN + 65536;
constexpr size_t OFF_MX   = OFF_BPN + 65536;          // 3 uint absmax slots (16 B)
constexpr size_t OFF_ZB   = OFF_MX  + 16;             // 2 KiB zero page for OOB rows

// ---- helpers ----
__device__ __forceinline__ ushort_t f2bf(float f) {  // RNE f32->bf16
    unsigned u = __float_as_uint(f);
    u += 0x7FFFu + ((u >> 16) & 1u);
    return (ushort_t)(u >> 16);
}

__device__ __forceinline__ void async_copy16(const void* g, const void* l) {
    // global -> LDS direct copy, 16 B per lane. LDS dest is wave-uniform base
    // + lane*16 (hardware); global src is per-lane.
    auto gp = (const __attribute__((address_space(1))) unsigned int*)(uintptr_t)g;
    auto lp = (__attribute__((address_space(3))) unsigned int*)(unsigned int)(uintptr_t)l;
    __builtin_amdgcn_global_load_lds(gp, lp, 16, 0, 0);
}

// ---------------------------------------------------------------------------
// 1) x NCHW f32 -> NHWC bf16. Tile [64 c][32 w] in LDS; reads coalesced on w
//    (128B), writes coalesced on c (64 lanes x 2B = 128B).
// ---------------------------------------------------------------------------
__global__ void to_nhwc_k(const float* __restrict__ x, ushort_t* __restrict__ xh) {
    __shared__ float tile[64][33];
    const int wt0 = blockIdx.x * 32;           // w tile: 0 or 32 (56 wide)
    const int ct0 = blockIdx.y * 64;           // c tile (4 tiles of 64)
    const int nh  = blockIdx.z;                // n*56 + h
    const int n = nh / HIN, h = nh - n * HIN;
    {
        const int tx = threadIdx.x & 31;       // w
        const int ty = threadIdx.x >> 5;       // c sub-row 0..7
        const int w  = wt0 + tx;
#pragma unroll
        for (int j = 0; j < 8; ++j) {
            int cl = ty + j * 8;
            if (w < HIN)
                tile[cl][tx] = x[(((size_t)n * C_IN + ct0 + cl) * HIN + h) * HIN + w];
        }
    }
    __syncthreads();
    {
        const int tc = threadIdx.x & 63;       // c
        const int tw = threadIdx.x >> 6;       // 0..3
#pragma unroll
        for (int j = 0; j < 8; ++j) {
            int wl = tw + j * 4;
            int w  = wt0 + wl;
            if (w < HIN)
                xh[(((size_t)n * HIN + h) * HIN + w) * C_IN + ct0 + tc] =
                    f2bf(tile[tc][wl]);
        }
    }
}

// ---------------------------------------------------------------------------
// 2) per-tensor |w| max (wave shuffle reduce + uint atomicMax)
// ---------------------------------------------------------------------------
__global__ void absmax_k(const float* __restrict__ w, int nelem, unsigned* out) {
    int stride = gridDim.x * blockDim.x;
    float m = 0.f;
    for (int i = blockIdx.x * blockDim.x + threadIdx.x; i < nelem; i += stride)
        m = fmaxf(m, fabsf(w[i]));
#pragma unroll
    for (int off = 32; off > 0; off >>= 1)
        m = fmaxf(m, __shfl_down(m, off));
    if ((threadIdx.x & 63) == 0) atomicMax(out, __float_as_uint(m));
}

// ---------------------------------------------------------------------------
// 3) quantize weights (symmetric per-tensor, qmax=127) and transform
//    OIHW f32 -> [kh*kw][co][ci] bf16 (ci contiguous for staging)
// ---------------------------------------------------------------------------
template <int CO_, int CI_, int KHW_>
__global__ void quantw_k(const float* __restrict__ w, const unsigned* __restrict__ mx,
                         ushort_t* __restrict__ wt) {
    const int total = KHW_ * CO_ * CI_;
    int idx = blockIdx.x * 256 + threadIdx.x;
    if (idx >= total) return;
    float scale = __uint_as_float(*mx) * (1.0f / 127.0f);
    float inv   = scale > 0.f ? 1.0f / scale : 0.f;
    int khw = idx / (CO_ * CI_);
    int r   = idx - khw * (CO_ * CI_);
    int co  = r / CI_;
    int ci  = r - co * CI_;
    float v  = w[((size_t)co * CI_ + ci) * KHW_ + khw];
    float qv = rintf(v * inv);
    qv = fminf(127.f, fmaxf(-127.f, qv));
    wt[idx] = f2bf(qv * scale);
}

// ---------------------------------------------------------------------------
// 4) implicit-GEMM conv: out[M=n*oh*ow][CO] f32 (NHWC) = gather(x) * wt
//    128x128 tile, BK=64, 4 waves (2x2 of 64x64), mfma 16x16x32 bf16.
//    Gather addressing hoisted: per-slot base offset + khw validity mask;
//    khw loop unrolled (compile-time offsets), runtime ci-chunk loop.
//    1-D grid with XCD-grouping swizzle (4 co-tiles of an M-tile -> same XCD).
// ---------------------------------------------------------------------------
template <int CIN, int KH, int KW, int STRIDE, int PAD, int IH, int IW>
__launch_bounds__(256, 2)
__global__ void conv_gemm_k(const ushort_t* __restrict__ xin,
                            const ushort_t* __restrict__ wt,
                            float* __restrict__ out,
                            const ushort_t* __restrict__ zbuf) {
    constexpr int BK  = 64;
    constexpr int CKT = CIN / BK;

    __shared__ alignas(16) short As[128 * BK];
    __shared__ alignas(16) short Bs[128 * BK];

    const int tid  = threadIdx.x;
    const int lane = tid & 63;
    const int wv   = tid >> 6;
    const int lrow = lane & 15;
    const int q    = lane >> 4;
    const int wm   = wv >> 1;
    const int wn   = wv & 1;
    const int sw   = lrow & 7;

    // XCD-grouped bijective swizzle: 784 blocks = 8 XCDs x 98.
    // idx = xcd*98 + j ; co-tile = idx&3 so the 4 co-tiles of an M-tile are
    // consecutive in idx -> same XCD -> shared A-gather in that XCD's L2.
    const int bid = blockIdx.x;
    const int idx = (bid & 7) * 98 + (bid >> 3);
    const int m0  = (idx >> 2) * 128;
    const int co0 = (idx & 3) * 128;

    // ---- hoisted per-slot gather state ----
    int64_t  abase[4];            // element offset into xin (valid taps only)
    unsigned amask[4];            // bit khw = tap in-bounds
    const ushort_t* bbase[4];
#pragma unroll
    for (int i = 0; i < 4; ++i) {
        int f    = i * 256 + tid;          // 16B slot in tile, 0..1023
        int row  = f >> 3;
        int ch   = f & 7;
        int m    = m0 + row;
        int n    = m / OHW;
        int sp   = m - n * OHW;
        int oh   = sp / OWD;
        int ow   = sp - oh * OWD;
        int ihb  = oh * STRIDE - PAD;
        int iwb  = ow * STRIDE - PAD;
        int swz  = (ch ^ (row & 7)) * 8;   // pre-swizzled source chunk (elems)
        abase[i] = ((int64_t)n * (IH * IW) + (int64_t)ihb * IW + iwb) * CIN + swz;
        unsigned mk = 0;
#pragma unroll
        for (int kh = 0; kh < KH; ++kh)
#pragma unroll
            for (int kw = 0; kw < KW; ++kw) {
                int ih = ihb + kh, iw = iwb + kw;
                if ((unsigned)ih < (unsigned)IH && (unsigned)iw < (unsigned)IW)
                    mk |= 1u << (kh * KW + kw);
            }
        amask[i] = mk;
        bbase[i] = wt + (size_t)(co0 + row) * CIN + swz;
    }

    f32x4 acc[4][4];
#pragma unroll
    for (int a = 0; a < 4; ++a)
#pragma unroll
        for (int b = 0; b < 4; ++b) acc[a][b] = {0.f, 0.f, 0.f, 0.f};

#pragma unroll
    for (int kh = 0; kh < KH; ++kh)
#pragma unroll
    for (int kw = 0; kw < KW; ++kw) {
        const int khw = kh * KW + kw;                 // compile-time
        const ushort_t* pa[4];
        const ushort_t* pb[4];
#pragma unroll
        for (int i = 0; i < 4; ++i) {
            pa[i] = ((amask[i] >> khw) & 1)
                  ? xin + (abase[i] + (kh * IW + kw) * CIN)
                  : zbuf;                             // zero page (>=512 elems)
            pb[i] = bbase[i] + (size_t)khw * (CO * CIN);
        }
#pragma unroll 1
        for (int ck = 0; ck < CKT; ++ck) {
            const int cko = ck * BK;
#pragma unroll
            for (int i = 0; i < 4; ++i)
                async_copy16(pa[i] + cko, (const void*)&As[i * 2048 + wv * 512]);
#pragma unroll
            for (int i = 0; i < 4; ++i)
                async_copy16(pb[i] + cko, (const void*)&Bs[i * 2048 + wv * 512]);
            __syncthreads();

#pragma unroll
            for (int s = 0; s < 2; ++s) {
                const int ch = ((s << 2) + q) ^ sw;   // swizzled chunk for lane
                bf16x8 af[4], bfr[4];
#pragma unroll
                for (int mi = 0; mi < 4; ++mi) {
                    int row = wm * 64 + mi * 16 + lrow;
                    af[mi] = *(const bf16x8*)&As[row * BK + ch * 8];
                }
#pragma unroll
                for (int ni = 0; ni < 4; ++ni) {
                    int row = wn * 64 + ni * 16 + lrow;
                    bfr[ni] = *(const bf16x8*)&Bs[row * BK + ch * 8];
                }
#pragma unroll
                for (int mi = 0; mi < 4; ++mi)
#pragma unroll
                    for (int ni = 0; ni < 4; ++ni)
                        acc[mi][ni] = __builtin_amdgcn_mfma_f32_16x16x32_bf16(
                            af[mi], bfr[ni], acc[mi][ni], 0, 0, 0);
            }
            __syncthreads();
        }
    }

    // epilogue: D layout col=lane&15, row=(lane>>4)*4+reg
    const int mb = m0 + wm * 64 + q * 4;
    const int cb = co0 + wn * 64 + lrow;
#pragma unroll
    for (int mi = 0; mi < 4; ++mi)
#pragma unroll
        for (int ni = 0; ni < 4; ++ni)
#pragma unroll
            for (int r = 0; r < 4; ++r)
                out[(size_t)(mb + mi * 16 + r) * CO + (cb + ni * 16)] = acc[mi][ni][r];
}

// ---------------------------------------------------------------------------
// 5) instance-norm stats: partial sum/sumsq per (n, c) over spatial chunks
// ---------------------------------------------------------------------------
__global__ void stats_partial_k(const float* __restrict__ h,
                                float* __restrict__ psum, float* __restrict__ pss) {
    const int chunk = blockIdx.x;   // 0..15 (49 rows each)
    const int n     = blockIdx.y;
    const int c0    = threadIdx.x * 2;
    const float* base = h + ((size_t)n * OHW + chunk * 49) * CO + c0;
    float s0 = 0, ss0 = 0, s1 = 0, ss1 = 0;
    for (int r = 0; r < 49; ++r) {
        float2 v = *(const float2*)(base + (size_t)r * CO);
        s0 += v.x; ss0 += v.x * v.x;
        s1 += v.y; ss1 += v.y * v.y;
    }
    size_t o = ((size_t)n * 16 + chunk) * CO + c0;
    psum[o] = s0; psum[o + 1] = s1;
    pss[o]  = ss0; pss[o + 1] = ss1;
}

__global__ void stats_final_k(const float* __restrict__ psum, const float* __restrict__ pss,
                              const float* __restrict__ g, const float* __restrict__ b,
                              float* __restrict__ aout, float* __restrict__ bout) {
    int idx = blockIdx.x * 256 + threadIdx.x;   // 32*512
    int n = idx >> 9, c = idx & 511;
    float s = 0, ss = 0;
#pragma unroll
    for (int j = 0; j < 16; ++j) {
        s  += psum[((size_t)n * 16 + j) * CO + c];
        ss += pss[((size_t)n * 16 + j) * CO + c];
    }
    float mean = s * (1.0f / 784.0f);
    float var  = ss * (1.0f / 784.0f) - mean * mean;
    float rstd = rsqrtf(var + 1e-5f);
    float a = rstd * g[c];
    aout[idx] = a;
    bout[idx] = b[c] - mean * a;
}

// ---------------------------------------------------------------------------
// 6) apply norm1 + quant_a -> bf16 NHWC (input to conv2)
// ---------------------------------------------------------------------------
__device__ __forceinline__ float qact(float xn) {
    float xc = fminf(fmaxf(xn, 0.f), 1.f);
    return rintf(xc * 255.f) / 255.f;
}

__global__ void norm_quant_k(const float* __restrict__ h, const float* __restrict__ a_,
                             const float* __restrict__ b_, ushort_t* __restrict__ o) {
    int idx = blockIdx.x * 256 + threadIdx.x;   // over M*512/4
    int row = idx >> 7;
    int c0  = (idx & 127) * 4;
    int n   = row / OHW;
    float4 v = ((const float4*)h)[idx];
    const float* ap = a_ + n * CO + c0;
    const float* bp = b_ + n * CO + c0;
    ushort4 r;
    r.x = f2bf(qact(v.x * ap[0] + bp[0]));
    r.y = f2bf(qact(v.y * ap[1] + bp[1]));
    r.z = f2bf(qact(v.z * ap[2] + bp[2]));
    r.w = f2bf(qact(v.w * ap[3] + bp[3]));
    ((ushort4*)o)[idx] = r;
}

// ---------------------------------------------------------------------------
// 7) final: out NCHW = norm2(h2) + normp(s), NHWC->NCHW via LDS transpose
// ---------------------------------------------------------------------------
__global__ void final_k(const float* __restrict__ h2, const float* __restrict__ s,
                        const float* __restrict__ a2, const float* __restrict__ b2,
                        const float* __restrict__ ap_, const float* __restrict__ bp_,
                        float* __restrict__ out) {
    __shared__ float tile[32][33];
    const int sp0 = blockIdx.x * 32;    // 25 tiles (last covers 16)
    const int c0  = blockIdx.y * 32;
    const int n   = blockIdx.z;
    const int tx  = threadIdx.x & 31;
    const int ty  = threadIdx.x >> 5;
#pragma unroll
    for (int j = 0; j < 4; ++j) {
        int spl = ty + j * 8;
        int sp  = sp0 + spl;
        if (sp < OHW) {
            int c = c0 + tx;
            size_t ix = ((size_t)n * OHW + sp) * CO + c;
            int ci = n * CO + c;
            tile[spl][tx] = h2[ix] * a2[ci] + b2[ci] + s[ix] * ap_[ci] + bp_[ci];
        }
    }
    __syncthreads();
#pragma unroll
    for (int j = 0; j < 4; ++j) {
        int cl = ty + j * 8;
        int sp = sp0 + tx;
        if (sp < OHW)
            out[((size_t)n * CO + c0 + cl) * OHW + sp] = tile[tx][cl];
    }
}

// ---------------------------------------------------------------------------
extern "C" void kernel_launch(void* const* d_in, const int* in_sizes, int n_in,
                              void* d_out, int out_size, void* d_ws, size_t ws_size,
                              hipStream_t stream) {
    const float* x  = (const float*)d_in[0];
    const float* w1 = (const float*)d_in[1];
    const float* g1 = (const float*)d_in[2];
    const float* b1 = (const float*)d_in[3];
    const float* w2 = (const float*)d_in[4];
    const float* g2 = (const float*)d_in[5];
    const float* b2 = (const float*)d_in[6];
    const float* wp = (const float*)d_in[7];
    const float* gp = (const float*)d_in[8];
    const float* bp = (const float*)d_in[9];
    float* out = (float*)d_out;
    char* ws = (char*)d_ws;

    ushort_t* xh   = (ushort_t*)(ws + OFF_XH);
    ushort_t* a1   = (ushort_t*)(ws + OFF_A1);
    float*    h2   = (float*)(ws + OFF_H2);
    float*    sbuf = (float*)(ws + OFF_S);
    ushort_t* wt1  = (ushort_t*)(ws + OFF_WT1);
    ushort_t* wt2  = (ushort_t*)(ws + OFF_WT2);
    ushort_t* wtp  = (ushort_t*)(ws + OFF_WTP);
    float*    psum = (float*)(ws + OFF_PSUM);
    float*    pss  = (float*)(ws + OFF_PSS);
    float*    a1n  = (float*)(ws + OFF_A1N);
    float*    b1n  = (float*)(ws + OFF_B1N);
    float*    a2n  = (float*)(ws + OFF_A2N);
    float*    b2n  = (float*)(ws + OFF_B2N);
    float*    apn  = (float*)(ws + OFF_APN);
    float*    bpn  = (float*)(ws + OFF_BPN);
    unsigned* mx   = (unsigned*)(ws + OFF_MX);
    ushort_t* zb   = (ushort_t*)(ws + OFF_ZB);
    float*    h1   = out;   // d_out doubles as conv1 output scratch (dead
                            // before final_k writes the real output)

    hipMemsetAsync(ws + OFF_MX, 0, 16 + 2048, stream);  // absmax slots + zero page

    // layout transform + weight quant
    to_nhwc_k<<<dim3(2, 4, NB * HIN), 256, 0, stream>>>(x, xh);
    absmax_k<<<dim3(512), 256, 0, stream>>>(w1, CO * C_IN * 9, mx + 0);
    absmax_k<<<dim3(512), 256, 0, stream>>>(w2, CO * CO * 9, mx + 1);
    absmax_k<<<dim3(512), 256, 0, stream>>>(wp, CO * C_IN, mx + 2);
    quantw_k<CO, C_IN, 9><<<dim3(4608), 256, 0, stream>>>(w1, mx + 0, wt1);
    quantw_k<CO, CO, 9><<<dim3(9216), 256, 0, stream>>>(w2, mx + 1, wt2);
    quantw_k<CO, C_IN, 1><<<dim3(512), 256, 0, stream>>>(wp, mx + 2, wtp);

    // conv1 (3x3 s2 p1, 256->512) -> h1 (in d_out)
    conv_gemm_k<C_IN, 3, 3, 2, 1, HIN, HIN>
        <<<dim3(784), 256, 0, stream>>>(xh, wt1, h1, zb);
    stats_partial_k<<<dim3(16, NB), 256, 0, stream>>>(h1, psum, pss);
    stats_final_k<<<dim3(64), 256, 0, stream>>>(psum, pss, g1, b1, a1n, b1n);
    norm_quant_k<<<dim3(MTOT * CO / 4 / 256), 256, 0, stream>>>(h1, a1n, b1n, a1);

    // conv2 (3x3 s1 p1, 512->512) -> h2
    conv_gemm_k<CO, 3, 3, 1, 1, 28, 28>
        <<<dim3(784), 256, 0, stream>>>(a1, wt2, h2, zb);
    // shortcut conv (1x1 s2, 256->512) -> s
    conv_gemm_k<C_IN, 1, 1, 2, 0, HIN, HIN>
        <<<dim3(784), 256, 0, stream>>>(xh, wtp, sbuf, zb);

    stats_partial_k<<<dim3(16, NB), 256, 0, stream>>>(h2, psum, pss);
    stats_final_k<<<dim3(64), 256, 0, stream>>>(psum, pss, g2, b2, a2n, b2n);
    stats_partial_k<<<dim3(16, NB), 256, 0, stream>>>(sbuf, psum, pss);
    stats_final_k<<<dim3(64), 256, 0, stream>>>(psum, pss, gp, bp, apn, bpn);

    final_k<<<dim3(25, 16, NB), 256, 0, stream>>>(h2, sbuf, a2n, b2n, apn, bpn, out);
}

// Round 4
// 442.226 us; speedup vs baseline: 1.1227x; 1.0395x over previous
//
#include <hip/hip_runtime.h>
#include <cstdint>
#include <cstddef>

// ---------------------------------------------------------------------------
// QBasicBlock: qconv3x3(s2) -> inorm -> quant_a -> qconv3x3(s1) -> inorm
//            + qconv1x1(s2) -> inorm  (shortcut), output sum, NCHW f32.
// R4: fix R3's cross-wave race. Counted vmcnt waits are now placed BEFORE a
//     barrier (wait-own + barrier => all waves' loads landed), per m201:
//       prologue: stage 8, vmcnt(2), s_barrier
//       t.q1 post-MFMA: vmcnt(hn?4:0) + barrier  -> A1,A3 of tile t visible
//       t.q3 post-MFMA: vmcnt(2)      + barrier  -> B*,A0,A2 of t+1 visible
// ---------------------------------------------------------------------------

typedef unsigned short ushort_t;
typedef __attribute__((ext_vector_type(8))) short bf16x8;
typedef __attribute__((ext_vector_type(4))) float f32x4;

// ---- problem constants ----
#define NB   32
#define C_IN 256
#define HIN  56
#define CO   512
#define OHW  784           // 28*28
#define OWD  28
#define MTOT (NB * OHW)    // 25088

// ---- workspace layout (bytes) ----
constexpr size_t OFF_XH   = 0;                        // x NHWC bf16: 32*56*56*256
constexpr size_t OFF_A1   = OFF_XH  + 51380224;       // a1 NHWC bf16: 32*784*512
constexpr size_t OFF_H2   = OFF_A1  + 25690112;       // h2 NHWC f32
constexpr size_t OFF_S    = OFF_H2  + 51380224;       // shortcut NHWC f32
constexpr size_t OFF_WT1  = OFF_S   + 51380224;       // wt1 bf16 [9][512][256]
constexpr size_t OFF_WT2  = OFF_WT1 + 2359296;        // wt2 bf16 [9][512][512]
constexpr size_t OFF_WTP  = OFF_WT2 + 4718592;        // wtp bf16 [1][512][256]
constexpr size_t OFF_PSUM = OFF_WTP + 262144;         // [32][16][512] f32
constexpr size_t OFF_PSS  = OFF_PSUM + 1048576;
constexpr size_t OFF_A1N  = OFF_PSS  + 1048576;       // per-(n,c) affine
constexpr size_t OFF_B1N  = OFF_A1N + 65536;
constexpr size_t OFF_A2N  = OFF_B1N + 65536;
constexpr size_t OFF_B2N  = OFF_A2N + 65536;
constexpr size_t OFF_APN  = OFF_B2N + 65536;
constexpr size_t OFF_BPN  = OFF_APN + 65536;
constexpr size_t OFF_MX   = OFF_BPN + 65536;          // 3 uint absmax slots
constexpr size_t OFF_ZB   = OFF_MX  + 16;             // 2 KiB zero page

// ---- helpers ----
__device__ __forceinline__ ushort_t f2bf(float f) {  // RNE f32->bf16
    unsigned u = __float_as_uint(f);
    u += 0x7FFFu + ((u >> 16) & 1u);
    return (ushort_t)(u >> 16);
}

__device__ __forceinline__ void async_copy16(const void* g, const void* l) {
    // global -> LDS direct copy, 16 B per lane. LDS dest: wave-uniform base +
    // lane*16 (hardware); global src is per-lane (pre-swizzled).
    auto gp = (const __attribute__((address_space(1))) unsigned int*)(uintptr_t)g;
    auto lp = (__attribute__((address_space(3))) unsigned int*)(unsigned int)(uintptr_t)l;
    __builtin_amdgcn_global_load_lds(gp, lp, 16, 0, 0);
}

// ---------------------------------------------------------------------------
// 1) x NCHW f32 -> NHWC bf16
// ---------------------------------------------------------------------------
__global__ void to_nhwc_k(const float* __restrict__ x, ushort_t* __restrict__ xh) {
    __shared__ float tile[64][33];
    const int wt0 = blockIdx.x * 32;
    const int ct0 = blockIdx.y * 64;
    const int nh  = blockIdx.z;
    const int n = nh / HIN, h = nh - n * HIN;
    {
        const int tx = threadIdx.x & 31;
        const int ty = threadIdx.x >> 5;
        const int w  = wt0 + tx;
#pragma unroll
        for (int j = 0; j < 8; ++j) {
            int cl = ty + j * 8;
            if (w < HIN)
                tile[cl][tx] = x[(((size_t)n * C_IN + ct0 + cl) * HIN + h) * HIN + w];
        }
    }
    __syncthreads();
    {
        const int tc = threadIdx.x & 63;
        const int tw = threadIdx.x >> 6;
#pragma unroll
        for (int j = 0; j < 8; ++j) {
            int wl = tw + j * 4;
            int w  = wt0 + wl;
            if (w < HIN)
                xh[(((size_t)n * HIN + h) * HIN + w) * C_IN + ct0 + tc] =
                    f2bf(tile[tc][wl]);
        }
    }
}

// ---------------------------------------------------------------------------
// 2) per-tensor |w| max
// ---------------------------------------------------------------------------
__global__ void absmax_k(const float* __restrict__ w, int nelem, unsigned* out) {
    int stride = gridDim.x * blockDim.x;
    float m = 0.f;
    for (int i = blockIdx.x * blockDim.x + threadIdx.x; i < nelem; i += stride)
        m = fmaxf(m, fabsf(w[i]));
#pragma unroll
    for (int off = 32; off > 0; off >>= 1)
        m = fmaxf(m, __shfl_down(m, off));
    if ((threadIdx.x & 63) == 0) atomicMax(out, __float_as_uint(m));
}

// ---------------------------------------------------------------------------
// 3) weight quant + transform OIHW f32 -> [kh*kw][co][ci] bf16
// ---------------------------------------------------------------------------
template <int CO_, int CI_, int KHW_>
__global__ void quantw_k(const float* __restrict__ w, const unsigned* __restrict__ mx,
                         ushort_t* __restrict__ wt) {
    const int total = KHW_ * CO_ * CI_;
    int idx = blockIdx.x * 256 + threadIdx.x;
    if (idx >= total) return;
    float scale = __uint_as_float(*mx) * (1.0f / 127.0f);
    float inv   = scale > 0.f ? 1.0f / scale : 0.f;
    int khw = idx / (CO_ * CI_);
    int r   = idx - khw * (CO_ * CI_);
    int co  = r / CI_;
    int ci  = r - co * CI_;
    float v  = w[((size_t)co * CI_ + ci) * KHW_ + khw];
    float qv = rintf(v * inv);
    qv = fminf(127.f, fmaxf(-127.f, qv));
    wt[idx] = f2bf(qv * scale);
}

// ---------------------------------------------------------------------------
// 4) 8-phase implicit-GEMM conv.  out[M][CO] f32 (NHWC) = gather(x) * wt.
//    BM=BN=256, BK=64, 512 thr = 8 waves (2M x 4N), per-wave out 128x64.
//    Per K-tile: 4 phases {12 ds_read_b128 | stage 2 gload_lds -> sched_bar
//    -> barrier -> 16 MFMA (setprio) -> [counted vmcnt] -> barrier}.
//    Stage order per K-tile: ph0:{B0,B1} ph1:{B2,B3} ph2:{A0,A2} ph3:{A1,A3}.
//    Ledger (per wave, in-order retirement, waits BEFORE a barrier so the
//    barrier publishes all waves' landings):
//      t.q1 post-MFMA: outstanding [A1^t,A3^t,B0..B3^t+1] -> vmcnt(4)
//                      => A1,A3 of tile t landed; barrier; q2/q3 read them.
//      t.q3 post-MFMA: outstanding [A1,A3,B0..B3,A0,A2 of t+1] -> vmcnt(2)
//                      => B*,A0,A2 of t+1 landed; barrier; t+1.q0 reads safe.
//      last tile q1: vmcnt(0) (only 2 outstanding).
// ---------------------------------------------------------------------------
template <int CIN, int KH, int KW, int STRIDE, int PAD, int IH, int IW>
__launch_bounds__(512, 2)
__global__ void conv8p_k(const ushort_t* __restrict__ xin,
                         const ushort_t* __restrict__ wt,
                         float* __restrict__ out,
                         const ushort_t* __restrict__ zbuf) {
    constexpr int BK  = 64;
    constexpr int CKT = CIN / BK;
    constexpr int KT  = KH * KW * CKT;

    __shared__ alignas(16) short As[2 * 256 * BK];   // 64 KiB
    __shared__ alignas(16) short Bs[2 * 256 * BK];   // 64 KiB

    const int tid  = threadIdx.x;
    const int lane = tid & 63;
    const int wv   = tid >> 6;       // 0..7
    const int wm   = wv >> 2;        // 0..1
    const int wn   = wv & 3;         // 0..3
    const int lrow = lane & 15;
    const int lq   = lane >> 4;      // 0..3
    const int sw   = lrow & 7;

    // bijective XCD swizzle for 196 blocks (q=24, r=4, m204 formula);
    // consecutive wg (two co-tiles of one M-tile) land on the same XCD.
    const int bid = blockIdx.x;
    const int xcd = bid & 7;
    const int j   = bid >> 3;
    const int wg  = (xcd < 4 ? xcd * 25 : 100 + (xcd - 4) * 24) + j;
    const int m0  = (wg >> 1) * 256;
    const int co0 = (wg & 1) * 256;

    // ---- hoisted gather state: chunk c covers rows c*64 + (tid>>3) ----
    const int arow = tid >> 3;        // 0..63
    const int ach  = tid & 7;
    long abase[4]; unsigned amask[4]; int bco[4];
#pragma unroll
    for (int c = 0; c < 4; ++c) {
        int row = c * 64 + arow;
        int m   = m0 + row;
        int n   = m / OHW;
        int sp  = m - n * OHW;
        int oh  = sp / OWD, ow = sp - oh * OWD;
        int ihb = oh * STRIDE - PAD, iwb = ow * STRIDE - PAD;
        int swz = (ach ^ (row & 7)) * 8;          // pre-swizzled source chunk
        abase[c] = ((long)n * (IH * IW) + (long)ihb * IW + iwb) * CIN + swz;
        unsigned mk = 0;
#pragma unroll
        for (int kh = 0; kh < KH; ++kh)
#pragma unroll
            for (int kw = 0; kw < KW; ++kw) {
                int ih = ihb + kh, iw = iwb + kw;
                if ((unsigned)ih < (unsigned)IH && (unsigned)iw < (unsigned)IW)
                    mk |= 1u << (kh * KW + kw);
            }
        amask[c] = mk;
        bco[c]   = (co0 + row) * CIN + swz;
    }

    auto stageA = [&](int c, int nb, long aoff, int khw) {
        const ushort_t* src = ((amask[c] >> khw) & 1)
            ? xin + (abase[c] + aoff) : zbuf;
        async_copy16(src, (const void*)&As[nb * 16384 + c * 4096 + wv * 512]);
    };
    auto stageB = [&](int c, int nb, int boff) {
        async_copy16(wt + (boff + bco[c]),
                     (const void*)&Bs[nb * 16384 + c * 4096 + wv * 512]);
    };

    f32x4 acc[8][4];
#pragma unroll
    for (int a = 0; a < 8; ++a)
#pragma unroll
        for (int b = 0; b < 4; ++b) acc[a][b] = {0.f, 0.f, 0.f, 0.f};

    // ---- prologue: stage K-tile 0 into buf0; A1,A3 provably last-issued ----
    stageB(0, 0, 0); stageB(1, 0, 0); stageB(2, 0, 0); stageB(3, 0, 0);
    stageA(0, 0, 0, 0); stageA(2, 0, 0, 0);
    __builtin_amdgcn_sched_barrier(0);
    stageA(1, 0, 0, 0); stageA(3, 0, 0, 0);
    __builtin_amdgcn_sched_barrier(0);
    asm volatile("s_waitcnt vmcnt(2)" ::: "memory");   // B*,A0,A2 landed (own)
    __builtin_amdgcn_s_barrier();                      // -> landed for ALL waves

    // next-K-tile coords (tile 1): aoff = (kh*IW+kw)*CIN + ck*BK, boff likewise
    int  khw_n = 0, kw_n = 0, ck_n = 1;
    long aoff_n = BK;
    int  boff_n = BK;

    int cur = 0;
    for (int t = 0; t < KT; ++t) {
        const bool hn = (t + 1 < KT);
        const int  nb = cur ^ 1;
        const short* Acur = &As[cur * 16384];
        const short* Bcur = &Bs[cur * 16384];

#pragma unroll
        for (int q = 0; q < 4; ++q) {
            const int qm = q >> 1, qn = q & 1;

            bf16x8 af[4][2], bfr[2][2];
#pragma unroll
            for (int mi = 0; mi < 4; ++mi) {
                const int row = wm * 128 + qm * 64 + mi * 16 + lrow;
#pragma unroll
                for (int ks = 0; ks < 2; ++ks) {
                    const int ch = ((ks * 4 + lq) ^ sw) * 8;
                    af[mi][ks] = *(const bf16x8*)&Acur[row * BK + ch];
                }
            }
#pragma unroll
            for (int ni = 0; ni < 2; ++ni) {
                const int row = wn * 64 + qn * 32 + ni * 16 + lrow;
#pragma unroll
                for (int ks = 0; ks < 2; ++ks) {
                    const int ch = ((ks * 4 + lq) ^ sw) * 8;
                    bfr[ni][ks] = *(const bf16x8*)&Bcur[row * BK + ch];
                }
            }

            if (hn) {
                if (q == 0) { stageB(0, nb, boff_n); stageB(1, nb, boff_n); }
                if (q == 1) { stageB(2, nb, boff_n); stageB(3, nb, boff_n); }
                if (q == 2) { stageA(0, nb, aoff_n, khw_n); stageA(2, nb, aoff_n, khw_n); }
                if (q == 3) { stageA(1, nb, aoff_n, khw_n); stageA(3, nb, aoff_n, khw_n); }
            }

            __builtin_amdgcn_sched_barrier(0);
            __builtin_amdgcn_s_barrier();
            __builtin_amdgcn_s_setprio(1);
#pragma unroll
            for (int mi = 0; mi < 4; ++mi)
#pragma unroll
                for (int ni = 0; ni < 2; ++ni)
#pragma unroll
                    for (int ks = 0; ks < 2; ++ks)
                        acc[qm * 4 + mi][qn * 2 + ni] =
                            __builtin_amdgcn_mfma_f32_16x16x32_bf16(
                                af[mi][ks], bfr[ni][ks],
                                acc[qm * 4 + mi][qn * 2 + ni], 0, 0, 0);
            __builtin_amdgcn_s_setprio(0);

            // counted waits BEFORE the closing barrier (cross-wave publish)
            if (q == 1) {
                if (hn) asm volatile("s_waitcnt vmcnt(4)" ::: "memory");
                else    asm volatile("s_waitcnt vmcnt(0)" ::: "memory");
            }
            if (q == 3 && hn) asm volatile("s_waitcnt vmcnt(2)" ::: "memory");
            __builtin_amdgcn_sched_barrier(0);
            __builtin_amdgcn_s_barrier();
        }

        if (hn) {   // advance coords to K-tile t+2
            ck_n++;
            if (ck_n == CKT) {
                ck_n = 0; khw_n++; kw_n++;
                if (kw_n == KW) { kw_n = 0; aoff_n += (long)(IW - KW) * CIN + BK; }
                else            { aoff_n += BK; }
                boff_n += (CO - 1) * CIN + BK;
            } else {
                aoff_n += BK; boff_n += BK;
            }
        }
        cur ^= 1;
    }

    // epilogue: D layout col=lane&15, row=(lane>>4)*4+reg
    const int mb = m0 + wm * 128 + lq * 4;
    const int cb = co0 + wn * 64 + lrow;
#pragma unroll
    for (int mi = 0; mi < 8; ++mi)
#pragma unroll
        for (int ni = 0; ni < 4; ++ni)
#pragma unroll
            for (int r = 0; r < 4; ++r)
                out[(size_t)(mb + mi * 16 + r) * CO + (cb + ni * 16)] = acc[mi][ni][r];
}

// ---------------------------------------------------------------------------
// 5) instance-norm stats
// ---------------------------------------------------------------------------
__global__ void stats_partial_k(const float* __restrict__ h,
                                float* __restrict__ psum, float* __restrict__ pss) {
    const int chunk = blockIdx.x;   // 0..15 (49 rows each)
    const int n     = blockIdx.y;
    const int c0    = threadIdx.x * 2;
    const float* base = h + ((size_t)n * OHW + chunk * 49) * CO + c0;
    float s0 = 0, ss0 = 0, s1 = 0, ss1 = 0;
    for (int r = 0; r < 49; ++r) {
        float2 v = *(const float2*)(base + (size_t)r * CO);
        s0 += v.x; ss0 += v.x * v.x;
        s1 += v.y; ss1 += v.y * v.y;
    }
    size_t o = ((size_t)n * 16 + chunk) * CO + c0;
    psum[o] = s0; psum[o + 1] = s1;
    pss[o]  = ss0; pss[o + 1] = ss1;
}

__global__ void stats_final_k(const float* __restrict__ psum, const float* __restrict__ pss,
                              const float* __restrict__ g, const float* __restrict__ b,
                              float* __restrict__ aout, float* __restrict__ bout) {
    int idx = blockIdx.x * 256 + threadIdx.x;   // 32*512
    int n = idx >> 9, c = idx & 511;
    float s = 0, ss = 0;
#pragma unroll
    for (int j = 0; j < 16; ++j) {
        s  += psum[((size_t)n * 16 + j) * CO + c];
        ss += pss[((size_t)n * 16 + j) * CO + c];
    }
    float mean = s * (1.0f / 784.0f);
    float var  = ss * (1.0f / 784.0f) - mean * mean;
    float rstd = rsqrtf(var + 1e-5f);
    float a = rstd * g[c];
    aout[idx] = a;
    bout[idx] = b[c] - mean * a;
}

// ---------------------------------------------------------------------------
// 6) apply norm1 + quant_a -> bf16 NHWC
// ---------------------------------------------------------------------------
__device__ __forceinline__ float qact(float xn) {
    float xc = fminf(fmaxf(xn, 0.f), 1.f);
    return rintf(xc * 255.f) / 255.f;
}

__global__ void norm_quant_k(const float* __restrict__ h, const float* __restrict__ a_,
                             const float* __restrict__ b_, ushort_t* __restrict__ o) {
    int idx = blockIdx.x * 256 + threadIdx.x;
    int row = idx >> 7;
    int c0  = (idx & 127) * 4;
    int n   = row / OHW;
    float4 v = ((const float4*)h)[idx];
    const float* ap = a_ + n * CO + c0;
    const float* bp = b_ + n * CO + c0;
    ushort4 r;
    r.x = f2bf(qact(v.x * ap[0] + bp[0]));
    r.y = f2bf(qact(v.y * ap[1] + bp[1]));
    r.z = f2bf(qact(v.z * ap[2] + bp[2]));
    r.w = f2bf(qact(v.w * ap[3] + bp[3]));
    ((ushort4*)o)[idx] = r;
}

// ---------------------------------------------------------------------------
// 7) final: out NCHW = norm2(h2) + normp(s), NHWC->NCHW via LDS transpose
// ---------------------------------------------------------------------------
__global__ void final_k(const float* __restrict__ h2, const float* __restrict__ s,
                        const float* __restrict__ a2, const float* __restrict__ b2,
                        const float* __restrict__ ap_, const float* __restrict__ bp_,
                        float* __restrict__ out) {
    __shared__ float tile[32][33];
    const int sp0 = blockIdx.x * 32;
    const int c0  = blockIdx.y * 32;
    const int n   = blockIdx.z;
    const int tx  = threadIdx.x & 31;
    const int ty  = threadIdx.x >> 5;
#pragma unroll
    for (int j = 0; j < 4; ++j) {
        int spl = ty + j * 8;
        int sp  = sp0 + spl;
        if (sp < OHW) {
            int c = c0 + tx;
            size_t ix = ((size_t)n * OHW + sp) * CO + c;
            int ci = n * CO + c;
            tile[spl][tx] = h2[ix] * a2[ci] + b2[ci] + s[ix] * ap_[ci] + bp_[ci];
        }
    }
    __syncthreads();
#pragma unroll
    for (int j = 0; j < 4; ++j) {
        int cl = ty + j * 8;
        int sp = sp0 + tx;
        if (sp < OHW)
            out[((size_t)n * CO + c0 + cl) * OHW + sp] = tile[tx][cl];
    }
}

// ---------------------------------------------------------------------------
extern "C" void kernel_launch(void* const* d_in, const int* in_sizes, int n_in,
                              void* d_out, int out_size, void* d_ws, size_t ws_size,
                              hipStream_t stream) {
    const float* x  = (const float*)d_in[0];
    const float* w1 = (const float*)d_in[1];
    const float* g1 = (const float*)d_in[2];
    const float* b1 = (const float*)d_in[3];
    const float* w2 = (const float*)d_in[4];
    const float* g2 = (const float*)d_in[5];
    const float* b2 = (const float*)d_in[6];
    const float* wp = (const float*)d_in[7];
    const float* gp = (const float*)d_in[8];
    const float* bp = (const float*)d_in[9];
    float* out = (float*)d_out;
    char* ws = (char*)d_ws;

    ushort_t* xh   = (ushort_t*)(ws + OFF_XH);
    ushort_t* a1   = (ushort_t*)(ws + OFF_A1);
    float*    h2   = (float*)(ws + OFF_H2);
    float*    sbuf = (float*)(ws + OFF_S);
    ushort_t* wt1  = (ushort_t*)(ws + OFF_WT1);
    ushort_t* wt2  = (ushort_t*)(ws + OFF_WT2);
    ushort_t* wtp  = (ushort_t*)(ws + OFF_WTP);
    float*    psum = (float*)(ws + OFF_PSUM);
    float*    pss  = (float*)(ws + OFF_PSS);
    float*    a1n  = (float*)(ws + OFF_A1N);
    float*    b1n  = (float*)(ws + OFF_B1N);
    float*    a2n  = (float*)(ws + OFF_A2N);
    float*    b2n  = (float*)(ws + OFF_B2N);
    float*    apn  = (float*)(ws + OFF_APN);
    float*    bpn  = (float*)(ws + OFF_BPN);
    unsigned* mx   = (unsigned*)(ws + OFF_MX);
    ushort_t* zb   = (ushort_t*)(ws + OFF_ZB);
    float*    h1   = out;   // d_out doubles as conv1 output scratch

    hipMemsetAsync(ws + OFF_MX, 0, 16 + 2048, stream);  // absmax slots + zero page

    // layout transform + weight quant
    to_nhwc_k<<<dim3(2, 4, NB * HIN), 256, 0, stream>>>(x, xh);
    absmax_k<<<dim3(512), 256, 0, stream>>>(w1, CO * C_IN * 9, mx + 0);
    absmax_k<<<dim3(512), 256, 0, stream>>>(w2, CO * CO * 9, mx + 1);
    absmax_k<<<dim3(512), 256, 0, stream>>>(wp, CO * C_IN, mx + 2);
    quantw_k<CO, C_IN, 9><<<dim3(4608), 256, 0, stream>>>(w1, mx + 0, wt1);
    quantw_k<CO, CO, 9><<<dim3(9216), 256, 0, stream>>>(w2, mx + 1, wt2);
    quantw_k<CO, C_IN, 1><<<dim3(512), 256, 0, stream>>>(wp, mx + 2, wtp);

    // conv1 (3x3 s2 p1, 256->512) -> h1 (in d_out)
    conv8p_k<C_IN, 3, 3, 2, 1, HIN, HIN>
        <<<dim3(196), 512, 0, stream>>>(xh, wt1, h1, zb);
    stats_partial_k<<<dim3(16, NB), 256, 0, stream>>>(h1, psum, pss);
    stats_final_k<<<dim3(64), 256, 0, stream>>>(psum, pss, g1, b1, a1n, b1n);
    norm_quant_k<<<dim3(MTOT * CO / 4 / 256), 256, 0, stream>>>(h1, a1n, b1n, a1);

    // conv2 (3x3 s1 p1, 512->512) -> h2
    conv8p_k<CO, 3, 3, 1, 1, 28, 28>
        <<<dim3(196), 512, 0, stream>>>(a1, wt2, h2, zb);
    // shortcut conv (1x1 s2, 256->512) -> s
    conv8p_k<C_IN, 1, 1, 2, 0, HIN, HIN>
        <<<dim3(196), 512, 0, stream>>>(xh, wtp, sbuf, zb);

    stats_partial_k<<<dim3(16, NB), 256, 0, stream>>>(h2, psum, pss);
    stats_final_k<<<dim3(64), 256, 0, stream>>>(psum, pss, g2, b2, a2n, b2n);
    stats_partial_k<<<dim3(16, NB), 256, 0, stream>>>(sbuf, psum, pss);
    stats_final_k<<<dim3(64), 256, 0, stream>>>(psum, pss, gp, bp, apn, bpn);

    final_k<<<dim3(25, 16, NB), 256, 0, stream>>>(h2, sbuf, a2n, b2n, apn, bpn, out);
}

// Round 5
// 413.209 us; speedup vs baseline: 1.2016x; 1.0702x over previous
//
#include <hip/hip_runtime.h>
#include <cstdint>
#include <cstddef>

// ---------------------------------------------------------------------------
// QBasicBlock: qconv3x3(s2) -> inorm -> quant_a -> qconv3x3(s1) -> inorm
//            + qconv1x1(s2) -> inorm  (shortcut), output sum, NCHW f32.
// R5: conv K-loop restructured 4-phase -> 2-phase per K-tile with B-fragment
//     register residency: LDS read traffic halved (48->24 KB/wave/K-tile),
//     barriers halved. vmcnt ledger re-derived (waits before barriers):
//       P0 stages B0-3(t+1);         P0-end vmcnt(hn?4:0)  [A1,A3 of t land]
//       P1 stages A0,A2 | A1,A3;     P1-end vmcnt(2) [B*,A0,A2 of t+1 land]
// ---------------------------------------------------------------------------

typedef unsigned short ushort_t;
typedef __attribute__((ext_vector_type(8))) short bf16x8;
typedef __attribute__((ext_vector_type(4))) float f32x4;

// ---- problem constants ----
#define NB   32
#define C_IN 256
#define HIN  56
#define CO   512
#define OHW  784           // 28*28
#define OWD  28
#define MTOT (NB * OHW)    // 25088

// ---- workspace layout (bytes) ----
constexpr size_t OFF_XH   = 0;                        // x NHWC bf16: 32*56*56*256
constexpr size_t OFF_A1   = OFF_XH  + 51380224;       // a1 NHWC bf16: 32*784*512
constexpr size_t OFF_H2   = OFF_A1  + 25690112;       // h2 NHWC f32
constexpr size_t OFF_S    = OFF_H2  + 51380224;       // shortcut NHWC f32
constexpr size_t OFF_WT1  = OFF_S   + 51380224;       // wt1 bf16 [9][512][256]
constexpr size_t OFF_WT2  = OFF_WT1 + 2359296;        // wt2 bf16 [9][512][512]
constexpr size_t OFF_WTP  = OFF_WT2 + 4718592;        // wtp bf16 [1][512][256]
constexpr size_t OFF_PSUM = OFF_WTP + 262144;         // [32][16][512] f32
constexpr size_t OFF_PSS  = OFF_PSUM + 1048576;
constexpr size_t OFF_A1N  = OFF_PSS  + 1048576;       // per-(n,c) affine
constexpr size_t OFF_B1N  = OFF_A1N + 65536;
constexpr size_t OFF_A2N  = OFF_B1N + 65536;
constexpr size_t OFF_B2N  = OFF_A2N + 65536;
constexpr size_t OFF_APN  = OFF_B2N + 65536;
constexpr size_t OFF_BPN  = OFF_APN + 65536;
constexpr size_t OFF_MX   = OFF_BPN + 65536;          // 3 uint absmax slots
constexpr size_t OFF_ZB   = OFF_MX  + 16;             // 2 KiB zero page

// ---- helpers ----
__device__ __forceinline__ ushort_t f2bf(float f) {  // RNE f32->bf16
    unsigned u = __float_as_uint(f);
    u += 0x7FFFu + ((u >> 16) & 1u);
    return (ushort_t)(u >> 16);
}

__device__ __forceinline__ void async_copy16(const void* g, const void* l) {
    // global -> LDS direct copy, 16 B per lane. LDS dest: wave-uniform base +
    // lane*16 (hardware); global src is per-lane (pre-swizzled).
    auto gp = (const __attribute__((address_space(1))) unsigned int*)(uintptr_t)g;
    auto lp = (__attribute__((address_space(3))) unsigned int*)(unsigned int)(uintptr_t)l;
    __builtin_amdgcn_global_load_lds(gp, lp, 16, 0, 0);
}

// ---------------------------------------------------------------------------
// 1) x NCHW f32 -> NHWC bf16
// ---------------------------------------------------------------------------
__global__ void to_nhwc_k(const float* __restrict__ x, ushort_t* __restrict__ xh) {
    __shared__ float tile[64][33];
    const int wt0 = blockIdx.x * 32;
    const int ct0 = blockIdx.y * 64;
    const int nh  = blockIdx.z;
    const int n = nh / HIN, h = nh - n * HIN;
    {
        const int tx = threadIdx.x & 31;
        const int ty = threadIdx.x >> 5;
        const int w  = wt0 + tx;
#pragma unroll
        for (int j = 0; j < 8; ++j) {
            int cl = ty + j * 8;
            if (w < HIN)
                tile[cl][tx] = x[(((size_t)n * C_IN + ct0 + cl) * HIN + h) * HIN + w];
        }
    }
    __syncthreads();
    {
        const int tc = threadIdx.x & 63;
        const int tw = threadIdx.x >> 6;
#pragma unroll
        for (int j = 0; j < 8; ++j) {
            int wl = tw + j * 4;
            int w  = wt0 + wl;
            if (w < HIN)
                xh[(((size_t)n * HIN + h) * HIN + w) * C_IN + ct0 + tc] =
                    f2bf(tile[tc][wl]);
        }
    }
}

// ---------------------------------------------------------------------------
// 2) per-tensor |w| max
// ---------------------------------------------------------------------------
__global__ void absmax_k(const float* __restrict__ w, int nelem, unsigned* out) {
    int stride = gridDim.x * blockDim.x;
    float m = 0.f;
    for (int i = blockIdx.x * blockDim.x + threadIdx.x; i < nelem; i += stride)
        m = fmaxf(m, fabsf(w[i]));
#pragma unroll
    for (int off = 32; off > 0; off >>= 1)
        m = fmaxf(m, __shfl_down(m, off));
    if ((threadIdx.x & 63) == 0) atomicMax(out, __float_as_uint(m));
}

// ---------------------------------------------------------------------------
// 3) weight quant + transform OIHW f32 -> [kh*kw][co][ci] bf16
// ---------------------------------------------------------------------------
template <int CO_, int CI_, int KHW_>
__global__ void quantw_k(const float* __restrict__ w, const unsigned* __restrict__ mx,
                         ushort_t* __restrict__ wt) {
    const int total = KHW_ * CO_ * CI_;
    int idx = blockIdx.x * 256 + threadIdx.x;
    if (idx >= total) return;
    float scale = __uint_as_float(*mx) * (1.0f / 127.0f);
    float inv   = scale > 0.f ? 1.0f / scale : 0.f;
    int khw = idx / (CO_ * CI_);
    int r   = idx - khw * (CO_ * CI_);
    int co  = r / CI_;
    int ci  = r - co * CI_;
    float v  = w[((size_t)co * CI_ + ci) * KHW_ + khw];
    float qv = rintf(v * inv);
    qv = fminf(127.f, fmaxf(-127.f, qv));
    wt[idx] = f2bf(qv * scale);
}

// ---------------------------------------------------------------------------
// 4) 2-phase implicit-GEMM conv.  out[M][CO] f32 (NHWC) = gather(x) * wt.
//    BM=BN=256, BK=64, 512 thr = 8 waves (2M x 4N), per-wave out 128x64.
//    Per K-tile: 2 phases.  P0 (qm=0): read af(8) + ALL bfr(8), stage
//    B0-3(t+1), 32 MFMA.  P1 (qm=1): read af(8) only (bfr stays in regs),
//    stage A0,A2|A1,A3(t+1), 32 MFMA.  Counted vmcnt before each closing
//    barrier (cross-wave publish):
//      P0-end: outstanding [A1^t,A3^t,B0-3^t+1] -> vmcnt(4) (last tile: 0)
//      P1-end: outstanding [B0-3,A0,A2,A1,A3 of t+1] -> vmcnt(2)
//    sched_barrier between {A0,A2} and {A1,A3} pins the in-order ledger.
// ---------------------------------------------------------------------------
template <int CIN, int KH, int KW, int STRIDE, int PAD, int IH, int IW>
__launch_bounds__(512, 2)
__global__ void conv8p_k(const ushort_t* __restrict__ xin,
                         const ushort_t* __restrict__ wt,
                         float* __restrict__ out,
                         const ushort_t* __restrict__ zbuf) {
    constexpr int BK  = 64;
    constexpr int CKT = CIN / BK;
    constexpr int KT  = KH * KW * CKT;

    __shared__ alignas(16) short As[2 * 256 * BK];   // 64 KiB
    __shared__ alignas(16) short Bs[2 * 256 * BK];   // 64 KiB

    const int tid  = threadIdx.x;
    const int lane = tid & 63;
    const int wv   = tid >> 6;       // 0..7
    const int wm   = wv >> 2;        // 0..1
    const int wn   = wv & 3;         // 0..3
    const int lrow = lane & 15;
    const int lq   = lane >> 4;      // 0..3
    const int sw   = lrow & 7;

    // bijective XCD swizzle for 196 blocks (q=24, r=4, m204 formula);
    // consecutive wg (two co-tiles of one M-tile) land on the same XCD.
    const int bid = blockIdx.x;
    const int xcd = bid & 7;
    const int j   = bid >> 3;
    const int wg  = (xcd < 4 ? xcd * 25 : 100 + (xcd - 4) * 24) + j;
    const int m0  = (wg >> 1) * 256;
    const int co0 = (wg & 1) * 256;

    // ---- hoisted gather state: chunk c covers rows c*64 + (tid>>3) ----
    const int arow = tid >> 3;        // 0..63
    const int ach  = tid & 7;
    long abase[4]; unsigned amask[4]; int bco[4];
#pragma unroll
    for (int c = 0; c < 4; ++c) {
        int row = c * 64 + arow;
        int m   = m0 + row;
        int n   = m / OHW;
        int sp  = m - n * OHW;
        int oh  = sp / OWD, ow = sp - oh * OWD;
        int ihb = oh * STRIDE - PAD, iwb = ow * STRIDE - PAD;
        int swz = (ach ^ (row & 7)) * 8;          // pre-swizzled source chunk
        abase[c] = ((long)n * (IH * IW) + (long)ihb * IW + iwb) * CIN + swz;
        unsigned mk = 0;
#pragma unroll
        for (int kh = 0; kh < KH; ++kh)
#pragma unroll
            for (int kw = 0; kw < KW; ++kw) {
                int ih = ihb + kh, iw = iwb + kw;
                if ((unsigned)ih < (unsigned)IH && (unsigned)iw < (unsigned)IW)
                    mk |= 1u << (kh * KW + kw);
            }
        amask[c] = mk;
        bco[c]   = (co0 + row) * CIN + swz;
    }

    auto stageA = [&](int c, int nb, long aoff, int khw) {
        const ushort_t* src = ((amask[c] >> khw) & 1)
            ? xin + (abase[c] + aoff) : zbuf;
        async_copy16(src, (const void*)&As[nb * 16384 + c * 4096 + wv * 512]);
    };
    auto stageB = [&](int c, int nb, int boff) {
        async_copy16(wt + (boff + bco[c]),
                     (const void*)&Bs[nb * 16384 + c * 4096 + wv * 512]);
    };

    f32x4 acc[8][4];
#pragma unroll
    for (int a = 0; a < 8; ++a)
#pragma unroll
        for (int b = 0; b < 4; ++b) acc[a][b] = {0.f, 0.f, 0.f, 0.f};

    // ---- prologue: stage K-tile 0 into buf0; A1,A3 provably last-issued ----
    stageB(0, 0, 0); stageB(1, 0, 0); stageB(2, 0, 0); stageB(3, 0, 0);
    stageA(0, 0, 0, 0); stageA(2, 0, 0, 0);
    __builtin_amdgcn_sched_barrier(0);
    stageA(1, 0, 0, 0); stageA(3, 0, 0, 0);
    __builtin_amdgcn_sched_barrier(0);
    asm volatile("s_waitcnt vmcnt(2)" ::: "memory");   // B*,A0,A2 landed (own)
    __builtin_amdgcn_s_barrier();                      // -> landed for ALL waves

    // next-K-tile coords (tile 1)
    int  khw_n = 0, kw_n = 0, ck_n = 1;
    long aoff_n = BK;
    int  boff_n = BK;

    int cur = 0;
    for (int t = 0; t < KT; ++t) {
        const bool hn = (t + 1 < KT);
        const int  nb = cur ^ 1;
        const short* Acur = &As[cur * 16384];
        const short* Bcur = &Bs[cur * 16384];

        bf16x8 af[4][2], bfr[2][2][2];

        // ================= P0: qm = 0 =================
#pragma unroll
        for (int mi = 0; mi < 4; ++mi) {
            const int row = wm * 128 + mi * 16 + lrow;
#pragma unroll
            for (int ks = 0; ks < 2; ++ks) {
                const int ch = ((ks * 4 + lq) ^ sw) * 8;
                af[mi][ks] = *(const bf16x8*)&Acur[row * BK + ch];
            }
        }
#pragma unroll
        for (int qn = 0; qn < 2; ++qn)
#pragma unroll
            for (int ni = 0; ni < 2; ++ni) {
                const int row = wn * 64 + qn * 32 + ni * 16 + lrow;
#pragma unroll
                for (int ks = 0; ks < 2; ++ks) {
                    const int ch = ((ks * 4 + lq) ^ sw) * 8;
                    bfr[qn][ni][ks] = *(const bf16x8*)&Bcur[row * BK + ch];
                }
            }
        if (hn) { stageB(0, nb, boff_n); stageB(1, nb, boff_n);
                  stageB(2, nb, boff_n); stageB(3, nb, boff_n); }
        __builtin_amdgcn_sched_barrier(0);
        __builtin_amdgcn_s_barrier();
        __builtin_amdgcn_s_setprio(1);
#pragma unroll
        for (int mi = 0; mi < 4; ++mi)
#pragma unroll
            for (int qn = 0; qn < 2; ++qn)
#pragma unroll
                for (int ni = 0; ni < 2; ++ni)
#pragma unroll
                    for (int ks = 0; ks < 2; ++ks)
                        acc[mi][qn * 2 + ni] =
                            __builtin_amdgcn_mfma_f32_16x16x32_bf16(
                                af[mi][ks], bfr[qn][ni][ks],
                                acc[mi][qn * 2 + ni], 0, 0, 0);
        __builtin_amdgcn_s_setprio(0);
        if (hn) asm volatile("s_waitcnt vmcnt(4)" ::: "memory");
        else    asm volatile("s_waitcnt vmcnt(0)" ::: "memory");
        __builtin_amdgcn_sched_barrier(0);
        __builtin_amdgcn_s_barrier();

        // ================= P1: qm = 1 (bfr reused from registers) =========
#pragma unroll
        for (int mi = 0; mi < 4; ++mi) {
            const int row = wm * 128 + 64 + mi * 16 + lrow;
#pragma unroll
            for (int ks = 0; ks < 2; ++ks) {
                const int ch = ((ks * 4 + lq) ^ sw) * 8;
                af[mi][ks] = *(const bf16x8*)&Acur[row * BK + ch];
            }
        }
        if (hn) {
            stageA(0, nb, aoff_n, khw_n); stageA(2, nb, aoff_n, khw_n);
            __builtin_amdgcn_sched_barrier(0);
            stageA(1, nb, aoff_n, khw_n); stageA(3, nb, aoff_n, khw_n);
        }
        __builtin_amdgcn_sched_barrier(0);
        __builtin_amdgcn_s_barrier();
        __builtin_amdgcn_s_setprio(1);
#pragma unroll
        for (int mi = 0; mi < 4; ++mi)
#pragma unroll
            for (int qn = 0; qn < 2; ++qn)
#pragma unroll
                for (int ni = 0; ni < 2; ++ni)
#pragma unroll
                    for (int ks = 0; ks < 2; ++ks)
                        acc[4 + mi][qn * 2 + ni] =
                            __builtin_amdgcn_mfma_f32_16x16x32_bf16(
                                af[mi][ks], bfr[qn][ni][ks],
                                acc[4 + mi][qn * 2 + ni], 0, 0, 0);
        __builtin_amdgcn_s_setprio(0);
        if (hn) asm volatile("s_waitcnt vmcnt(2)" ::: "memory");
        __builtin_amdgcn_sched_barrier(0);
        __builtin_amdgcn_s_barrier();

        if (hn) {   // advance coords to K-tile t+2
            ck_n++;
            if (ck_n == CKT) {
                ck_n = 0; khw_n++; kw_n++;
                if (kw_n == KW) { kw_n = 0; aoff_n += (long)(IW - KW) * CIN + BK; }
                else            { aoff_n += BK; }
                boff_n += (CO - 1) * CIN + BK;
            } else {
                aoff_n += BK; boff_n += BK;
            }
        }
        cur ^= 1;
    }

    // epilogue: D layout col=lane&15, row=(lane>>4)*4+reg
    const int mb = m0 + wm * 128 + lq * 4;
    const int cb = co0 + wn * 64 + lrow;
#pragma unroll
    for (int mi = 0; mi < 8; ++mi)
#pragma unroll
        for (int ni = 0; ni < 4; ++ni)
#pragma unroll
            for (int r = 0; r < 4; ++r)
                out[(size_t)(mb + mi * 16 + r) * CO + (cb + ni * 16)] = acc[mi][ni][r];
}

// ---------------------------------------------------------------------------
// 5) instance-norm stats
// ---------------------------------------------------------------------------
__global__ void stats_partial_k(const float* __restrict__ h,
                                float* __restrict__ psum, float* __restrict__ pss) {
    const int chunk = blockIdx.x;   // 0..15 (49 rows each)
    const int n     = blockIdx.y;
    const int c0    = threadIdx.x * 2;
    const float* base = h + ((size_t)n * OHW + chunk * 49) * CO + c0;
    float s0 = 0, ss0 = 0, s1 = 0, ss1 = 0;
    for (int r = 0; r < 49; ++r) {
        float2 v = *(const float2*)(base + (size_t)r * CO);
        s0 += v.x; ss0 += v.x * v.x;
        s1 += v.y; ss1 += v.y * v.y;
    }
    size_t o = ((size_t)n * 16 + chunk) * CO + c0;
    psum[o] = s0; psum[o + 1] = s1;
    pss[o]  = ss0; pss[o + 1] = ss1;
}

__global__ void stats_final_k(const float* __restrict__ psum, const float* __restrict__ pss,
                              const float* __restrict__ g, const float* __restrict__ b,
                              float* __restrict__ aout, float* __restrict__ bout) {
    int idx = blockIdx.x * 256 + threadIdx.x;   // 32*512
    int n = idx >> 9, c = idx & 511;
    float s = 0, ss = 0;
#pragma unroll
    for (int j = 0; j < 16; ++j) {
        s  += psum[((size_t)n * 16 + j) * CO + c];
        ss += pss[((size_t)n * 16 + j) * CO + c];
    }
    float mean = s * (1.0f / 784.0f);
    float var  = ss * (1.0f / 784.0f) - mean * mean;
    float rstd = rsqrtf(var + 1e-5f);
    float a = rstd * g[c];
    aout[idx] = a;
    bout[idx] = b[c] - mean * a;
}

// ---------------------------------------------------------------------------
// 6) apply norm1 + quant_a -> bf16 NHWC
// ---------------------------------------------------------------------------
__device__ __forceinline__ float qact(float xn) {
    float xc = fminf(fmaxf(xn, 0.f), 1.f);
    return rintf(xc * 255.f) / 255.f;
}

__global__ void norm_quant_k(const float* __restrict__ h, const float* __restrict__ a_,
                             const float* __restrict__ b_, ushort_t* __restrict__ o) {
    int idx = blockIdx.x * 256 + threadIdx.x;
    int row = idx >> 7;
    int c0  = (idx & 127) * 4;
    int n   = row / OHW;
    float4 v = ((const float4*)h)[idx];
    const float* ap = a_ + n * CO + c0;
    const float* bp = b_ + n * CO + c0;
    ushort4 r;
    r.x = f2bf(qact(v.x * ap[0] + bp[0]));
    r.y = f2bf(qact(v.y * ap[1] + bp[1]));
    r.z = f2bf(qact(v.z * ap[2] + bp[2]));
    r.w = f2bf(qact(v.w * ap[3] + bp[3]));
    ((ushort4*)o)[idx] = r;
}

// ---------------------------------------------------------------------------
// 7) final: out NCHW = norm2(h2) + normp(s), NHWC->NCHW via LDS transpose
// ---------------------------------------------------------------------------
__global__ void final_k(const float* __restrict__ h2, const float* __restrict__ s,
                        const float* __restrict__ a2, const float* __restrict__ b2,
                        const float* __restrict__ ap_, const float* __restrict__ bp_,
                        float* __restrict__ out) {
    __shared__ float tile[32][33];
    const int sp0 = blockIdx.x * 32;
    const int c0  = blockIdx.y * 32;
    const int n   = blockIdx.z;
    const int tx  = threadIdx.x & 31;
    const int ty  = threadIdx.x >> 5;
#pragma unroll
    for (int j = 0; j < 4; ++j) {
        int spl = ty + j * 8;
        int sp  = sp0 + spl;
        if (sp < OHW) {
            int c = c0 + tx;
            size_t ix = ((size_t)n * OHW + sp) * CO + c;
            int ci = n * CO + c;
            tile[spl][tx] = h2[ix] * a2[ci] + b2[ci] + s[ix] * ap_[ci] + bp_[ci];
        }
    }
    __syncthreads();
#pragma unroll
    for (int j = 0; j < 4; ++j) {
        int cl = ty + j * 8;
        int sp = sp0 + tx;
        if (sp < OHW)
            out[((size_t)n * CO + c0 + cl) * OHW + sp] = tile[tx][cl];
    }
}

// ---------------------------------------------------------------------------
extern "C" void kernel_launch(void* const* d_in, const int* in_sizes, int n_in,
                              void* d_out, int out_size, void* d_ws, size_t ws_size,
                              hipStream_t stream) {
    const float* x  = (const float*)d_in[0];
    const float* w1 = (const float*)d_in[1];
    const float* g1 = (const float*)d_in[2];
    const float* b1 = (const float*)d_in[3];
    const float* w2 = (const float*)d_in[4];
    const float* g2 = (const float*)d_in[5];
    const float* b2 = (const float*)d_in[6];
    const float* wp = (const float*)d_in[7];
    const float* gp = (const float*)d_in[8];
    const float* bp = (const float*)d_in[9];
    float* out = (float*)d_out;
    char* ws = (char*)d_ws;

    ushort_t* xh   = (ushort_t*)(ws + OFF_XH);
    ushort_t* a1   = (ushort_t*)(ws + OFF_A1);
    float*    h2   = (float*)(ws + OFF_H2);
    float*    sbuf = (float*)(ws + OFF_S);
    ushort_t* wt1  = (ushort_t*)(ws + OFF_WT1);
    ushort_t* wt2  = (ushort_t*)(ws + OFF_WT2);
    ushort_t* wtp  = (ushort_t*)(ws + OFF_WTP);
    float*    psum = (float*)(ws + OFF_PSUM);
    float*    pss  = (float*)(ws + OFF_PSS);
    float*    a1n  = (float*)(ws + OFF_A1N);
    float*    b1n  = (float*)(ws + OFF_B1N);
    float*    a2n  = (float*)(ws + OFF_A2N);
    float*    b2n  = (float*)(ws + OFF_B2N);
    float*    apn  = (float*)(ws + OFF_APN);
    float*    bpn  = (float*)(ws + OFF_BPN);
    unsigned* mx   = (unsigned*)(ws + OFF_MX);
    ushort_t* zb   = (ushort_t*)(ws + OFF_ZB);
    float*    h1   = out;   // d_out doubles as conv1 output scratch

    hipMemsetAsync(ws + OFF_MX, 0, 16 + 2048, stream);  // absmax slots + zero page

    // layout transform + weight quant
    to_nhwc_k<<<dim3(2, 4, NB * HIN), 256, 0, stream>>>(x, xh);
    absmax_k<<<dim3(512), 256, 0, stream>>>(w1, CO * C_IN * 9, mx + 0);
    absmax_k<<<dim3(512), 256, 0, stream>>>(w2, CO * CO * 9, mx + 1);
    absmax_k<<<dim3(512), 256, 0, stream>>>(wp, C_IN * CO, mx + 2);
    quantw_k<CO, C_IN, 9><<<dim3(4608), 256, 0, stream>>>(w1, mx + 0, wt1);
    quantw_k<CO, CO, 9><<<dim3(9216), 256, 0, stream>>>(w2, mx + 1, wt2);
    quantw_k<CO, C_IN, 1><<<dim3(512), 256, 0, stream>>>(wp, mx + 2, wtp);

    // conv1 (3x3 s2 p1, 256->512) -> h1 (in d_out)
    conv8p_k<C_IN, 3, 3, 2, 1, HIN, HIN>
        <<<dim3(196), 512, 0, stream>>>(xh, wt1, h1, zb);
    stats_partial_k<<<dim3(16, NB), 256, 0, stream>>>(h1, psum, pss);
    stats_final_k<<<dim3(64), 256, 0, stream>>>(psum, pss, g1, b1, a1n, b1n);
    norm_quant_k<<<dim3(MTOT * CO / 4 / 256), 256, 0, stream>>>(h1, a1n, b1n, a1);

    // conv2 (3x3 s1 p1, 512->512) -> h2
    conv8p_k<CO, 3, 3, 1, 1, 28, 28>
        <<<dim3(196), 512, 0, stream>>>(a1, wt2, h2, zb);
    // shortcut conv (1x1 s2, 256->512) -> s
    conv8p_k<C_IN, 1, 1, 2, 0, HIN, HIN>
        <<<dim3(196), 512, 0, stream>>>(xh, wtp, sbuf, zb);

    stats_partial_k<<<dim3(16, NB), 256, 0, stream>>>(h2, psum, pss);
    stats_final_k<<<dim3(64), 256, 0, stream>>>(psum, pss, g2, b2, a2n, b2n);
    stats_partial_k<<<dim3(16, NB), 256, 0, stream>>>(sbuf, psum, pss);
    stats_final_k<<<dim3(64), 256, 0, stream>>>(psum, pss, gp, bp, apn, bpn);

    final_k<<<dim3(25, 16, NB), 256, 0, stream>>>(h2, sbuf, a2n, b2n, apn, bpn, out);
}

// Round 6
// 405.707 us; speedup vs baseline: 1.2238x; 1.0185x over previous
//
#include <hip/hip_runtime.h>
#include <cstdint>
#include <cstddef>

// ---------------------------------------------------------------------------
// QBasicBlock: qconv3x3(s2) -> inorm -> quant_a -> qconv3x3(s1) -> inorm
//            + qconv1x1(s2) -> inorm  (shortcut), output sum, NCHW f32.
// R6: remove mid-phase barriers. Per K-tile: 2 regions, each {ds_reads ||
//     stage || 32 MFMA} with compiler-scheduled incremental lgkmcnt, then
//     counted vmcnt + ONE barrier (the only cross-wave publish points).
//     Wave-slip now hides LDS latency under MFMA of sibling waves.
// ---------------------------------------------------------------------------

typedef unsigned short ushort_t;
typedef __attribute__((ext_vector_type(8))) short bf16x8;
typedef __attribute__((ext_vector_type(4))) float f32x4;

// ---- problem constants ----
#define NB   32
#define C_IN 256
#define HIN  56
#define CO   512
#define OHW  784           // 28*28
#define OWD  28
#define MTOT (NB * OHW)    // 25088

// ---- workspace layout (bytes) ----
constexpr size_t OFF_XH   = 0;                        // x NHWC bf16: 32*56*56*256
constexpr size_t OFF_A1   = OFF_XH  + 51380224;       // a1 NHWC bf16: 32*784*512
constexpr size_t OFF_H2   = OFF_A1  + 25690112;       // h2 NHWC f32
constexpr size_t OFF_S    = OFF_H2  + 51380224;       // shortcut NHWC f32
constexpr size_t OFF_WT1  = OFF_S   + 51380224;       // wt1 bf16 [9][512][256]
constexpr size_t OFF_WT2  = OFF_WT1 + 2359296;        // wt2 bf16 [9][512][512]
constexpr size_t OFF_WTP  = OFF_WT2 + 4718592;        // wtp bf16 [1][512][256]
constexpr size_t OFF_PSUM = OFF_WTP + 262144;         // [32][16][512] f32
constexpr size_t OFF_PSS  = OFF_PSUM + 1048576;
constexpr size_t OFF_A1N  = OFF_PSS  + 1048576;       // per-(n,c) affine
constexpr size_t OFF_B1N  = OFF_A1N + 65536;
constexpr size_t OFF_A2N  = OFF_B1N + 65536;
constexpr size_t OFF_B2N  = OFF_A2N + 65536;
constexpr size_t OFF_APN  = OFF_B2N + 65536;
constexpr size_t OFF_BPN  = OFF_APN + 65536;
constexpr size_t OFF_MX   = OFF_BPN + 65536;          // 3 uint absmax slots
constexpr size_t OFF_ZB   = OFF_MX  + 16;             // 2 KiB zero page

// ---- helpers ----
__device__ __forceinline__ ushort_t f2bf(float f) {  // RNE f32->bf16
    unsigned u = __float_as_uint(f);
    u += 0x7FFFu + ((u >> 16) & 1u);
    return (ushort_t)(u >> 16);
}

__device__ __forceinline__ void async_copy16(const void* g, const void* l) {
    // global -> LDS direct copy, 16 B per lane. LDS dest: wave-uniform base +
    // lane*16 (hardware); global src is per-lane (pre-swizzled).
    auto gp = (const __attribute__((address_space(1))) unsigned int*)(uintptr_t)g;
    auto lp = (__attribute__((address_space(3))) unsigned int*)(unsigned int)(uintptr_t)l;
    __builtin_amdgcn_global_load_lds(gp, lp, 16, 0, 0);
}

// ---------------------------------------------------------------------------
// 1) x NCHW f32 -> NHWC bf16
// ---------------------------------------------------------------------------
__global__ void to_nhwc_k(const float* __restrict__ x, ushort_t* __restrict__ xh) {
    __shared__ float tile[64][33];
    const int wt0 = blockIdx.x * 32;
    const int ct0 = blockIdx.y * 64;
    const int nh  = blockIdx.z;
    const int n = nh / HIN, h = nh - n * HIN;
    {
        const int tx = threadIdx.x & 31;
        const int ty = threadIdx.x >> 5;
        const int w  = wt0 + tx;
#pragma unroll
        for (int j = 0; j < 8; ++j) {
            int cl = ty + j * 8;
            if (w < HIN)
                tile[cl][tx] = x[(((size_t)n * C_IN + ct0 + cl) * HIN + h) * HIN + w];
        }
    }
    __syncthreads();
    {
        const int tc = threadIdx.x & 63;
        const int tw = threadIdx.x >> 6;
#pragma unroll
        for (int j = 0; j < 8; ++j) {
            int wl = tw + j * 4;
            int w  = wt0 + wl;
            if (w < HIN)
                xh[(((size_t)n * HIN + h) * HIN + w) * C_IN + ct0 + tc] =
                    f2bf(tile[tc][wl]);
        }
    }
}

// ---------------------------------------------------------------------------
// 2) per-tensor |w| max
// ---------------------------------------------------------------------------
__global__ void absmax_k(const float* __restrict__ w, int nelem, unsigned* out) {
    int stride = gridDim.x * blockDim.x;
    float m = 0.f;
    for (int i = blockIdx.x * blockDim.x + threadIdx.x; i < nelem; i += stride)
        m = fmaxf(m, fabsf(w[i]));
#pragma unroll
    for (int off = 32; off > 0; off >>= 1)
        m = fmaxf(m, __shfl_down(m, off));
    if ((threadIdx.x & 63) == 0) atomicMax(out, __float_as_uint(m));
}

// ---------------------------------------------------------------------------
// 3) weight quant + transform OIHW f32 -> [kh*kw][co][ci] bf16
// ---------------------------------------------------------------------------
template <int CO_, int CI_, int KHW_>
__global__ void quantw_k(const float* __restrict__ w, const unsigned* __restrict__ mx,
                         ushort_t* __restrict__ wt) {
    const int total = KHW_ * CO_ * CI_;
    int idx = blockIdx.x * 256 + threadIdx.x;
    if (idx >= total) return;
    float scale = __uint_as_float(*mx) * (1.0f / 127.0f);
    float inv   = scale > 0.f ? 1.0f / scale : 0.f;
    int khw = idx / (CO_ * CI_);
    int r   = idx - khw * (CO_ * CI_);
    int co  = r / CI_;
    int ci  = r - co * CI_;
    float v  = w[((size_t)co * CI_ + ci) * KHW_ + khw];
    float qv = rintf(v * inv);
    qv = fminf(127.f, fmaxf(-127.f, qv));
    wt[idx] = f2bf(qv * scale);
}

// ---------------------------------------------------------------------------
// 4) 2-region implicit-GEMM conv.  out[M][CO] f32 (NHWC) = gather(x) * wt.
//    BM=BN=256, BK=64, 512 thr = 8 waves (2M x 4N), per-wave out 128x64.
//    Per K-tile:
//      region A: {read af0(8) + all bfr(8) || stage B0-3(t+1) || 32 MFMA}
//                -> vmcnt(hn?4:0) -> barrier      [publishes A1,A3 of t]
//      region B: {read af1(8) || stage A0,A2|A1,A3(t+1) || 32 MFMA}
//                -> vmcnt(2) -> barrier           [publishes B*,A0,A2 of t+1]
//    No mid-region barriers: ds_reads are wave-private; compiler interleaves
//    reads and MFMA with incremental lgkmcnt; waves slip to hide latency.
//    sched_barrier(0) pins region boundaries (ledger stays in-order).
// ---------------------------------------------------------------------------
template <int CIN, int KH, int KW, int STRIDE, int PAD, int IH, int IW>
__launch_bounds__(512, 2)
__global__ void conv8p_k(const ushort_t* __restrict__ xin,
                         const ushort_t* __restrict__ wt,
                         float* __restrict__ out,
                         const ushort_t* __restrict__ zbuf) {
    constexpr int BK  = 64;
    constexpr int CKT = CIN / BK;
    constexpr int KT  = KH * KW * CKT;

    __shared__ alignas(16) short As[2 * 256 * BK];   // 64 KiB
    __shared__ alignas(16) short Bs[2 * 256 * BK];   // 64 KiB

    const int tid  = threadIdx.x;
    const int lane = tid & 63;
    const int wv   = tid >> 6;       // 0..7
    const int wm   = wv >> 2;        // 0..1
    const int wn   = wv & 3;         // 0..3
    const int lrow = lane & 15;
    const int lq   = lane >> 4;      // 0..3
    const int sw   = lrow & 7;

    // bijective XCD swizzle for 196 blocks (q=24, r=4, m204 formula);
    // consecutive wg (two co-tiles of one M-tile) land on the same XCD.
    const int bid = blockIdx.x;
    const int xcd = bid & 7;
    const int j   = bid >> 3;
    const int wg  = (xcd < 4 ? xcd * 25 : 100 + (xcd - 4) * 24) + j;
    const int m0  = (wg >> 1) * 256;
    const int co0 = (wg & 1) * 256;

    // ---- hoisted gather state: chunk c covers rows c*64 + (tid>>3) ----
    const int arow = tid >> 3;        // 0..63
    const int ach  = tid & 7;
    long abase[4]; unsigned amask[4]; int bco[4];
#pragma unroll
    for (int c = 0; c < 4; ++c) {
        int row = c * 64 + arow;
        int m   = m0 + row;
        int n   = m / OHW;
        int sp  = m - n * OHW;
        int oh  = sp / OWD, ow = sp - oh * OWD;
        int ihb = oh * STRIDE - PAD, iwb = ow * STRIDE - PAD;
        int swz = (ach ^ (row & 7)) * 8;          // pre-swizzled source chunk
        abase[c] = ((long)n * (IH * IW) + (long)ihb * IW + iwb) * CIN + swz;
        unsigned mk = 0;
#pragma unroll
        for (int kh = 0; kh < KH; ++kh)
#pragma unroll
            for (int kw = 0; kw < KW; ++kw) {
                int ih = ihb + kh, iw = iwb + kw;
                if ((unsigned)ih < (unsigned)IH && (unsigned)iw < (unsigned)IW)
                    mk |= 1u << (kh * KW + kw);
            }
        amask[c] = mk;
        bco[c]   = (co0 + row) * CIN + swz;
    }

    auto stageA = [&](int c, int nb, long aoff, int khw) {
        const ushort_t* src = ((amask[c] >> khw) & 1)
            ? xin + (abase[c] + aoff) : zbuf;
        async_copy16(src, (const void*)&As[nb * 16384 + c * 4096 + wv * 512]);
    };
    auto stageB = [&](int c, int nb, int boff) {
        async_copy16(wt + (boff + bco[c]),
                     (const void*)&Bs[nb * 16384 + c * 4096 + wv * 512]);
    };

    f32x4 acc[8][4];
#pragma unroll
    for (int a = 0; a < 8; ++a)
#pragma unroll
        for (int b = 0; b < 4; ++b) acc[a][b] = {0.f, 0.f, 0.f, 0.f};

    // ---- prologue: stage K-tile 0 into buf0; A1,A3 provably last-issued ----
    stageB(0, 0, 0); stageB(1, 0, 0); stageB(2, 0, 0); stageB(3, 0, 0);
    stageA(0, 0, 0, 0); stageA(2, 0, 0, 0);
    __builtin_amdgcn_sched_barrier(0);
    stageA(1, 0, 0, 0); stageA(3, 0, 0, 0);
    __builtin_amdgcn_sched_barrier(0);
    asm volatile("s_waitcnt vmcnt(2)" ::: "memory");   // B*,A0,A2 landed (own)
    __builtin_amdgcn_s_barrier();                      // -> landed for ALL waves

    // next-K-tile coords (tile 1)
    int  khw_n = 0, kw_n = 0, ck_n = 1;
    long aoff_n = BK;
    int  boff_n = BK;

    int cur = 0;
    for (int t = 0; t < KT; ++t) {
        const bool hn = (t + 1 < KT);
        const int  nb = cur ^ 1;
        const short* Acur = &As[cur * 16384];
        const short* Bcur = &Bs[cur * 16384];

        bf16x8 af[4][2], bfr[2][2][2];

        // ========== region A: af0 x all bfr, stage B0-3(t+1) ==========
#pragma unroll
        for (int mi = 0; mi < 4; ++mi) {
            const int row = wm * 128 + mi * 16 + lrow;
#pragma unroll
            for (int ks = 0; ks < 2; ++ks) {
                const int ch = ((ks * 4 + lq) ^ sw) * 8;
                af[mi][ks] = *(const bf16x8*)&Acur[row * BK + ch];
            }
        }
#pragma unroll
        for (int qn = 0; qn < 2; ++qn)
#pragma unroll
            for (int ni = 0; ni < 2; ++ni) {
                const int row = wn * 64 + qn * 32 + ni * 16 + lrow;
#pragma unroll
                for (int ks = 0; ks < 2; ++ks) {
                    const int ch = ((ks * 4 + lq) ^ sw) * 8;
                    bfr[qn][ni][ks] = *(const bf16x8*)&Bcur[row * BK + ch];
                }
            }
        if (hn) { stageB(0, nb, boff_n); stageB(1, nb, boff_n);
                  stageB(2, nb, boff_n); stageB(3, nb, boff_n); }
#pragma unroll
        for (int mi = 0; mi < 4; ++mi)
#pragma unroll
            for (int qn = 0; qn < 2; ++qn)
#pragma unroll
                for (int ni = 0; ni < 2; ++ni)
#pragma unroll
                    for (int ks = 0; ks < 2; ++ks)
                        acc[mi][qn * 2 + ni] =
                            __builtin_amdgcn_mfma_f32_16x16x32_bf16(
                                af[mi][ks], bfr[qn][ni][ks],
                                acc[mi][qn * 2 + ni], 0, 0, 0);
        if (hn) asm volatile("s_waitcnt vmcnt(4)" ::: "memory");
        else    asm volatile("s_waitcnt vmcnt(0)" ::: "memory");
        __builtin_amdgcn_sched_barrier(0);
        __builtin_amdgcn_s_barrier();                  // publish A1,A3 of t

        // ========== region B: af1 x bfr(regs), stage A(t+1) ==========
#pragma unroll
        for (int mi = 0; mi < 4; ++mi) {
            const int row = wm * 128 + 64 + mi * 16 + lrow;
#pragma unroll
            for (int ks = 0; ks < 2; ++ks) {
                const int ch = ((ks * 4 + lq) ^ sw) * 8;
                af[mi][ks] = *(const bf16x8*)&Acur[row * BK + ch];
            }
        }
        if (hn) {
            stageA(0, nb, aoff_n, khw_n); stageA(2, nb, aoff_n, khw_n);
            __builtin_amdgcn_sched_barrier(0);
            stageA(1, nb, aoff_n, khw_n); stageA(3, nb, aoff_n, khw_n);
        }
#pragma unroll
        for (int mi = 0; mi < 4; ++mi)
#pragma unroll
            for (int qn = 0; qn < 2; ++qn)
#pragma unroll
                for (int ni = 0; ni < 2; ++ni)
#pragma unroll
                    for (int ks = 0; ks < 2; ++ks)
                        acc[4 + mi][qn * 2 + ni] =
                            __builtin_amdgcn_mfma_f32_16x16x32_bf16(
                                af[mi][ks], bfr[qn][ni][ks],
                                acc[4 + mi][qn * 2 + ni], 0, 0, 0);
        if (hn) asm volatile("s_waitcnt vmcnt(2)" ::: "memory");
        __builtin_amdgcn_sched_barrier(0);
        __builtin_amdgcn_s_barrier();                  // publish B*,A0,A2 of t+1

        if (hn) {   // advance coords to K-tile t+2
            ck_n++;
            if (ck_n == CKT) {
                ck_n = 0; khw_n++; kw_n++;
                if (kw_n == KW) { kw_n = 0; aoff_n += (long)(IW - KW) * CIN + BK; }
                else            { aoff_n += BK; }
                boff_n += (CO - 1) * CIN + BK;
            } else {
                aoff_n += BK; boff_n += BK;
            }
        }
        cur ^= 1;
    }

    // epilogue: D layout col=lane&15, row=(lane>>4)*4+reg
    const int mb = m0 + wm * 128 + lq * 4;
    const int cb = co0 + wn * 64 + lrow;
#pragma unroll
    for (int mi = 0; mi < 8; ++mi)
#pragma unroll
        for (int ni = 0; ni < 4; ++ni)
#pragma unroll
            for (int r = 0; r < 4; ++r)
                out[(size_t)(mb + mi * 16 + r) * CO + (cb + ni * 16)] = acc[mi][ni][r];
}

// ---------------------------------------------------------------------------
// 5) instance-norm stats
// ---------------------------------------------------------------------------
__global__ void stats_partial_k(const float* __restrict__ h,
                                float* __restrict__ psum, float* __restrict__ pss) {
    const int chunk = blockIdx.x;   // 0..15 (49 rows each)
    const int n     = blockIdx.y;
    const int c0    = threadIdx.x * 2;
    const float* base = h + ((size_t)n * OHW + chunk * 49) * CO + c0;
    float s0 = 0, ss0 = 0, s1 = 0, ss1 = 0;
    for (int r = 0; r < 49; ++r) {
        float2 v = *(const float2*)(base + (size_t)r * CO);
        s0 += v.x; ss0 += v.x * v.x;
        s1 += v.y; ss1 += v.y * v.y;
    }
    size_t o = ((size_t)n * 16 + chunk) * CO + c0;
    psum[o] = s0; psum[o + 1] = s1;
    pss[o]  = ss0; pss[o + 1] = ss1;
}

__global__ void stats_final_k(const float* __restrict__ psum, const float* __restrict__ pss,
                              const float* __restrict__ g, const float* __restrict__ b,
                              float* __restrict__ aout, float* __restrict__ bout) {
    int idx = blockIdx.x * 256 + threadIdx.x;   // 32*512
    int n = idx >> 9, c = idx & 511;
    float s = 0, ss = 0;
#pragma unroll
    for (int j = 0; j < 16; ++j) {
        s  += psum[((size_t)n * 16 + j) * CO + c];
        ss += pss[((size_t)n * 16 + j) * CO + c];
    }
    float mean = s * (1.0f / 784.0f);
    float var  = ss * (1.0f / 784.0f) - mean * mean;
    float rstd = rsqrtf(var + 1e-5f);
    float a = rstd * g[c];
    aout[idx] = a;
    bout[idx] = b[c] - mean * a;
}

// ---------------------------------------------------------------------------
// 6) apply norm1 + quant_a -> bf16 NHWC
// ---------------------------------------------------------------------------
__device__ __forceinline__ float qact(float xn) {
    float xc = fminf(fmaxf(xn, 0.f), 1.f);
    return rintf(xc * 255.f) / 255.f;
}

__global__ void norm_quant_k(const float* __restrict__ h, const float* __restrict__ a_,
                             const float* __restrict__ b_, ushort_t* __restrict__ o) {
    int idx = blockIdx.x * 256 + threadIdx.x;
    int row = idx >> 7;
    int c0  = (idx & 127) * 4;
    int n   = row / OHW;
    float4 v = ((const float4*)h)[idx];
    const float* ap = a_ + n * CO + c0;
    const float* bp = b_ + n * CO + c0;
    ushort4 r;
    r.x = f2bf(qact(v.x * ap[0] + bp[0]));
    r.y = f2bf(qact(v.y * ap[1] + bp[1]));
    r.z = f2bf(qact(v.z * ap[2] + bp[2]));
    r.w = f2bf(qact(v.w * ap[3] + bp[3]));
    ((ushort4*)o)[idx] = r;
}

// ---------------------------------------------------------------------------
// 7) final: out NCHW = norm2(h2) + normp(s), NHWC->NCHW via LDS transpose
// ---------------------------------------------------------------------------
__global__ void final_k(const float* __restrict__ h2, const float* __restrict__ s,
                        const float* __restrict__ a2, const float* __restrict__ b2,
                        const float* __restrict__ ap_, const float* __restrict__ bp_,
                        float* __restrict__ out) {
    __shared__ float tile[32][33];
    const int sp0 = blockIdx.x * 32;
    const int c0  = blockIdx.y * 32;
    const int n   = blockIdx.z;
    const int tx  = threadIdx.x & 31;
    const int ty  = threadIdx.x >> 5;
#pragma unroll
    for (int j = 0; j < 4; ++j) {
        int spl = ty + j * 8;
        int sp  = sp0 + spl;
        if (sp < OHW) {
            int c = c0 + tx;
            size_t ix = ((size_t)n * OHW + sp) * CO + c;
            int ci = n * CO + c;
            tile[spl][tx] = h2[ix] * a2[ci] + b2[ci] + s[ix] * ap_[ci] + bp_[ci];
        }
    }
    __syncthreads();
#pragma unroll
    for (int j = 0; j < 4; ++j) {
        int cl = ty + j * 8;
        int sp = sp0 + tx;
        if (sp < OHW)
            out[((size_t)n * CO + c0 + cl) * OHW + sp] = tile[tx][cl];
    }
}

// ---------------------------------------------------------------------------
extern "C" void kernel_launch(void* const* d_in, const int* in_sizes, int n_in,
                              void* d_out, int out_size, void* d_ws, size_t ws_size,
                              hipStream_t stream) {
    const float* x  = (const float*)d_in[0];
    const float* w1 = (const float*)d_in[1];
    const float* g1 = (const float*)d_in[2];
    const float* b1 = (const float*)d_in[3];
    const float* w2 = (const float*)d_in[4];
    const float* g2 = (const float*)d_in[5];
    const float* b2 = (const float*)d_in[6];
    const float* wp = (const float*)d_in[7];
    const float* gp = (const float*)d_in[8];
    const float* bp = (const float*)d_in[9];
    float* out = (float*)d_out;
    char* ws = (char*)d_ws;

    ushort_t* xh   = (ushort_t*)(ws + OFF_XH);
    ushort_t* a1   = (ushort_t*)(ws + OFF_A1);
    float*    h2   = (float*)(ws + OFF_H2);
    float*    sbuf = (float*)(ws + OFF_S);
    ushort_t* wt1  = (ushort_t*)(ws + OFF_WT1);
    ushort_t* wt2  = (ushort_t*)(ws + OFF_WT2);
    ushort_t* wtp  = (ushort_t*)(ws + OFF_WTP);
    float*    psum = (float*)(ws + OFF_PSUM);
    float*    pss  = (float*)(ws + OFF_PSS);
    float*    a1n  = (float*)(ws + OFF_A1N);
    float*    b1n  = (float*)(ws + OFF_B1N);
    float*    a2n  = (float*)(ws + OFF_A2N);
    float*    b2n  = (float*)(ws + OFF_B2N);
    float*    apn  = (float*)(ws + OFF_APN);
    float*    bpn  = (float*)(ws + OFF_BPN);
    unsigned* mx   = (unsigned*)(ws + OFF_MX);
    ushort_t* zb   = (ushort_t*)(ws + OFF_ZB);
    float*    h1   = out;   // d_out doubles as conv1 output scratch

    hipMemsetAsync(ws + OFF_MX, 0, 16 + 2048, stream);  // absmax slots + zero page

    // layout transform + weight quant
    to_nhwc_k<<<dim3(2, 4, NB * HIN), 256, 0, stream>>>(x, xh);
    absmax_k<<<dim3(512), 256, 0, stream>>>(w1, CO * C_IN * 9, mx + 0);
    absmax_k<<<dim3(512), 256, 0, stream>>>(w2, CO * CO * 9, mx + 1);
    absmax_k<<<dim3(512), 256, 0, stream>>>(wp, C_IN * CO, mx + 2);
    quantw_k<CO, C_IN, 9><<<dim3(4608), 256, 0, stream>>>(w1, mx + 0, wt1);
    quantw_k<CO, CO, 9><<<dim3(9216), 256, 0, stream>>>(w2, mx + 1, wt2);
    quantw_k<CO, C_IN, 1><<<dim3(512), 256, 0, stream>>>(wp, mx + 2, wtp);

    // conv1 (3x3 s2 p1, 256->512) -> h1 (in d_out)
    conv8p_k<C_IN, 3, 3, 2, 1, HIN, HIN>
        <<<dim3(196), 512, 0, stream>>>(xh, wt1, h1, zb);
    stats_partial_k<<<dim3(16, NB), 256, 0, stream>>>(h1, psum, pss);
    stats_final_k<<<dim3(64), 256, 0, stream>>>(psum, pss, g1, b1, a1n, b1n);
    norm_quant_k<<<dim3(MTOT * CO / 4 / 256), 256, 0, stream>>>(h1, a1n, b1n, a1);

    // conv2 (3x3 s1 p1, 512->512) -> h2
    conv8p_k<CO, 3, 3, 1, 1, 28, 28>
        <<<dim3(196), 512, 0, stream>>>(a1, wt2, h2, zb);
    // shortcut conv (1x1 s2, 256->512) -> s
    conv8p_k<C_IN, 1, 1, 2, 0, HIN, HIN>
        <<<dim3(196), 512, 0, stream>>>(xh, wtp, sbuf, zb);

    stats_partial_k<<<dim3(16, NB), 256, 0, stream>>>(h2, psum, pss);
    stats_final_k<<<dim3(64), 256, 0, stream>>>(psum, pss, g2, b2, a2n, b2n);
    stats_partial_k<<<dim3(16, NB), 256, 0, stream>>>(sbuf, psum, pss);
    stats_final_k<<<dim3(64), 256, 0, stream>>>(psum, pss, gp, bp, apn, bpn);

    final_k<<<dim3(25, 16, NB), 256, 0, stream>>>(h2, sbuf, a2n, b2n, apn, bpn, out);
}

// Round 7
// 374.963 us; speedup vs baseline: 1.3241x; 1.0820x over previous
//
#include <hip/hip_runtime.h>
#include <cstdint>
#include <cstddef>

// ---------------------------------------------------------------------------
// QBasicBlock: qconv3x3(s2) -> inorm -> quant_a -> qconv3x3(s1) -> inorm
//            + qconv1x1(s2) -> inorm  (shortcut), output sum, NCHW f32.
// R7: fusion round (conv schedule untouched from R6):
//   - instance-norm stats fused into conv epilogues (shfl-reduce + atomicAdd)
//     -> stats_partial x3 kernels deleted (-154 MB of re-reads)
//   - conv outputs stored bf16 (stats come from exact f32 acc)
//   - norm_quant / final_k read bf16 (half the bytes)
// ---------------------------------------------------------------------------

typedef unsigned short ushort_t;
typedef __attribute__((ext_vector_type(8))) short bf16x8;
typedef __attribute__((ext_vector_type(4))) float f32x4;

// ---- problem constants ----
#define NB   32
#define C_IN 256
#define HIN  56
#define CO   512
#define OHW  784           // 28*28
#define OWD  28
#define MTOT (NB * OHW)    // 25088

// ---- workspace layout (bytes) ----
constexpr size_t OFF_XH   = 0;                        // x NHWC bf16: 32*56*56*256
constexpr size_t OFF_A1   = OFF_XH  + 51380224;       // a1 NHWC bf16
constexpr size_t OFF_H2   = OFF_A1  + 25690112;       // h2 NHWC bf16 (region sized f32)
constexpr size_t OFF_S    = OFF_H2  + 51380224;       // shortcut NHWC bf16
constexpr size_t OFF_WT1  = OFF_S   + 51380224;       // wt1 bf16 [9][512][256]
constexpr size_t OFF_WT2  = OFF_WT1 + 2359296;        // wt2 bf16 [9][512][512]
constexpr size_t OFF_WTP  = OFF_WT2 + 4718592;        // wtp bf16 [1][512][256]
constexpr size_t OFF_PSUM = OFF_WTP + 262144;         // 6 x [32][512] f32 (384 KiB)
constexpr size_t OFF_A1N  = OFF_PSUM + 2097152;       // per-(n,c) affine
constexpr size_t OFF_B1N  = OFF_A1N + 65536;
constexpr size_t OFF_A2N  = OFF_B1N + 65536;
constexpr size_t OFF_B2N  = OFF_A2N + 65536;
constexpr size_t OFF_APN  = OFF_B2N + 65536;
constexpr size_t OFF_BPN  = OFF_APN + 65536;
constexpr size_t OFF_MX   = OFF_BPN + 65536;          // 3 uint absmax slots
constexpr size_t OFF_ZB   = OFF_MX  + 16;             // 2 KiB zero page

// ---- helpers ----
__device__ __forceinline__ ushort_t f2bf(float f) {  // RNE f32->bf16
    unsigned u = __float_as_uint(f);
    u += 0x7FFFu + ((u >> 16) & 1u);
    return (ushort_t)(u >> 16);
}
__device__ __forceinline__ float bf2f(ushort_t u) {
    return __uint_as_float(((unsigned)u) << 16);
}

__device__ __forceinline__ void async_copy16(const void* g, const void* l) {
    auto gp = (const __attribute__((address_space(1))) unsigned int*)(uintptr_t)g;
    auto lp = (__attribute__((address_space(3))) unsigned int*)(unsigned int)(uintptr_t)l;
    __builtin_amdgcn_global_load_lds(gp, lp, 16, 0, 0);
}

// ---------------------------------------------------------------------------
// 1) x NCHW f32 -> NHWC bf16
// ---------------------------------------------------------------------------
__global__ void to_nhwc_k(const float* __restrict__ x, ushort_t* __restrict__ xh) {
    __shared__ float tile[64][33];
    const int wt0 = blockIdx.x * 32;
    const int ct0 = blockIdx.y * 64;
    const int nh  = blockIdx.z;
    const int n = nh / HIN, h = nh - n * HIN;
    {
        const int tx = threadIdx.x & 31;
        const int ty = threadIdx.x >> 5;
        const int w  = wt0 + tx;
#pragma unroll
        for (int j = 0; j < 8; ++j) {
            int cl = ty + j * 8;
            if (w < HIN)
                tile[cl][tx] = x[(((size_t)n * C_IN + ct0 + cl) * HIN + h) * HIN + w];
        }
    }
    __syncthreads();
    {
        const int tc = threadIdx.x & 63;
        const int tw = threadIdx.x >> 6;
#pragma unroll
        for (int j = 0; j < 8; ++j) {
            int wl = tw + j * 4;
            int w  = wt0 + wl;
            if (w < HIN)
                xh[(((size_t)n * HIN + h) * HIN + w) * C_IN + ct0 + tc] =
                    f2bf(tile[tc][wl]);
        }
    }
}

// ---------------------------------------------------------------------------
// 2) per-tensor |w| max
// ---------------------------------------------------------------------------
__global__ void absmax_k(const float* __restrict__ w, int nelem, unsigned* out) {
    int stride = gridDim.x * blockDim.x;
    float m = 0.f;
    for (int i = blockIdx.x * blockDim.x + threadIdx.x; i < nelem; i += stride)
        m = fmaxf(m, fabsf(w[i]));
#pragma unroll
    for (int off = 32; off > 0; off >>= 1)
        m = fmaxf(m, __shfl_down(m, off));
    if ((threadIdx.x & 63) == 0) atomicMax(out, __float_as_uint(m));
}

// ---------------------------------------------------------------------------
// 3) weight quant + transform OIHW f32 -> [kh*kw][co][ci] bf16
// ---------------------------------------------------------------------------
template <int CO_, int CI_, int KHW_>
__global__ void quantw_k(const float* __restrict__ w, const unsigned* __restrict__ mx,
                         ushort_t* __restrict__ wt) {
    const int total = KHW_ * CO_ * CI_;
    int idx = blockIdx.x * 256 + threadIdx.x;
    if (idx >= total) return;
    float scale = __uint_as_float(*mx) * (1.0f / 127.0f);
    float inv   = scale > 0.f ? 1.0f / scale : 0.f;
    int khw = idx / (CO_ * CI_);
    int r   = idx - khw * (CO_ * CI_);
    int co  = r / CI_;
    int ci  = r - co * CI_;
    float v  = w[((size_t)co * CI_ + ci) * KHW_ + khw];
    float qv = rintf(v * inv);
    qv = fminf(127.f, fmaxf(-127.f, qv));
    wt[idx] = f2bf(qv * scale);
}

// ---------------------------------------------------------------------------
// 4) 2-region implicit-GEMM conv (R6 schedule) + fused stats epilogue.
//    Output written bf16; per-(n,c) sum/sumsq accumulated from f32 acc via
//    lq-lane shfl reduce + global f32 atomicAdd into psum/pss.
// ---------------------------------------------------------------------------
template <int CIN, int KH, int KW, int STRIDE, int PAD, int IH, int IW>
__launch_bounds__(512, 2)
__global__ void conv8p_k(const ushort_t* __restrict__ xin,
                         const ushort_t* __restrict__ wt,
                         ushort_t* __restrict__ out,
                         const ushort_t* __restrict__ zbuf,
                         float* __restrict__ psum, float* __restrict__ pss) {
    constexpr int BK  = 64;
    constexpr int CKT = CIN / BK;
    constexpr int KT  = KH * KW * CKT;

    __shared__ alignas(16) short As[2 * 256 * BK];   // 64 KiB
    __shared__ alignas(16) short Bs[2 * 256 * BK];   // 64 KiB

    const int tid  = threadIdx.x;
    const int lane = tid & 63;
    const int wv   = tid >> 6;       // 0..7
    const int wm   = wv >> 2;        // 0..1
    const int wn   = wv & 3;         // 0..3
    const int lrow = lane & 15;
    const int lq   = lane >> 4;      // 0..3
    const int sw   = lrow & 7;

    const int bid = blockIdx.x;
    const int xcd = bid & 7;
    const int j   = bid >> 3;
    const int wg  = (xcd < 4 ? xcd * 25 : 100 + (xcd - 4) * 24) + j;
    const int m0  = (wg >> 1) * 256;
    const int co0 = (wg & 1) * 256;

    const int arow = tid >> 3;        // 0..63
    const int ach  = tid & 7;
    long abase[4]; unsigned amask[4]; int bco[4];
#pragma unroll
    for (int c = 0; c < 4; ++c) {
        int row = c * 64 + arow;
        int m   = m0 + row;
        int n   = m / OHW;
        int sp  = m - n * OHW;
        int oh  = sp / OWD, ow = sp - oh * OWD;
        int ihb = oh * STRIDE - PAD, iwb = ow * STRIDE - PAD;
        int swz = (ach ^ (row & 7)) * 8;
        abase[c] = ((long)n * (IH * IW) + (long)ihb * IW + iwb) * CIN + swz;
        unsigned mk = 0;
#pragma unroll
        for (int kh = 0; kh < KH; ++kh)
#pragma unroll
            for (int kw = 0; kw < KW; ++kw) {
                int ih = ihb + kh, iw = iwb + kw;
                if ((unsigned)ih < (unsigned)IH && (unsigned)iw < (unsigned)IW)
                    mk |= 1u << (kh * KW + kw);
            }
        amask[c] = mk;
        bco[c]   = (co0 + row) * CIN + swz;
    }

    auto stageA = [&](int c, int nb, long aoff, int khw) {
        const ushort_t* src = ((amask[c] >> khw) & 1)
            ? xin + (abase[c] + aoff) : zbuf;
        async_copy16(src, (const void*)&As[nb * 16384 + c * 4096 + wv * 512]);
    };
    auto stageB = [&](int c, int nb, int boff) {
        async_copy16(wt + (boff + bco[c]),
                     (const void*)&Bs[nb * 16384 + c * 4096 + wv * 512]);
    };

    f32x4 acc[8][4];
#pragma unroll
    for (int a = 0; a < 8; ++a)
#pragma unroll
        for (int b = 0; b < 4; ++b) acc[a][b] = {0.f, 0.f, 0.f, 0.f};

    // ---- prologue: stage K-tile 0 into buf0 ----
    stageB(0, 0, 0); stageB(1, 0, 0); stageB(2, 0, 0); stageB(3, 0, 0);
    stageA(0, 0, 0, 0); stageA(2, 0, 0, 0);
    __builtin_amdgcn_sched_barrier(0);
    stageA(1, 0, 0, 0); stageA(3, 0, 0, 0);
    __builtin_amdgcn_sched_barrier(0);
    asm volatile("s_waitcnt vmcnt(2)" ::: "memory");
    __builtin_amdgcn_s_barrier();

    int  khw_n = 0, kw_n = 0, ck_n = 1;
    long aoff_n = BK;
    int  boff_n = BK;

    int cur = 0;
    for (int t = 0; t < KT; ++t) {
        const bool hn = (t + 1 < KT);
        const int  nb = cur ^ 1;
        const short* Acur = &As[cur * 16384];
        const short* Bcur = &Bs[cur * 16384];

        bf16x8 af[4][2], bfr[2][2][2];

        // ========== region A: af0 x all bfr, stage B0-3(t+1) ==========
#pragma unroll
        for (int mi = 0; mi < 4; ++mi) {
            const int row = wm * 128 + mi * 16 + lrow;
#pragma unroll
            for (int ks = 0; ks < 2; ++ks) {
                const int ch = ((ks * 4 + lq) ^ sw) * 8;
                af[mi][ks] = *(const bf16x8*)&Acur[row * BK + ch];
            }
        }
#pragma unroll
        for (int qn = 0; qn < 2; ++qn)
#pragma unroll
            for (int ni = 0; ni < 2; ++ni) {
                const int row = wn * 64 + qn * 32 + ni * 16 + lrow;
#pragma unroll
                for (int ks = 0; ks < 2; ++ks) {
                    const int ch = ((ks * 4 + lq) ^ sw) * 8;
                    bfr[qn][ni][ks] = *(const bf16x8*)&Bcur[row * BK + ch];
                }
            }
        if (hn) { stageB(0, nb, boff_n); stageB(1, nb, boff_n);
                  stageB(2, nb, boff_n); stageB(3, nb, boff_n); }
#pragma unroll
        for (int mi = 0; mi < 4; ++mi)
#pragma unroll
            for (int qn = 0; qn < 2; ++qn)
#pragma unroll
                for (int ni = 0; ni < 2; ++ni)
#pragma unroll
                    for (int ks = 0; ks < 2; ++ks)
                        acc[mi][qn * 2 + ni] =
                            __builtin_amdgcn_mfma_f32_16x16x32_bf16(
                                af[mi][ks], bfr[qn][ni][ks],
                                acc[mi][qn * 2 + ni], 0, 0, 0);
        if (hn) asm volatile("s_waitcnt vmcnt(4)" ::: "memory");
        else    asm volatile("s_waitcnt vmcnt(0)" ::: "memory");
        __builtin_amdgcn_sched_barrier(0);
        __builtin_amdgcn_s_barrier();

        // ========== region B: af1 x bfr(regs), stage A(t+1) ==========
#pragma unroll
        for (int mi = 0; mi < 4; ++mi) {
            const int row = wm * 128 + 64 + mi * 16 + lrow;
#pragma unroll
            for (int ks = 0; ks < 2; ++ks) {
                const int ch = ((ks * 4 + lq) ^ sw) * 8;
                af[mi][ks] = *(const bf16x8*)&Acur[row * BK + ch];
            }
        }
        if (hn) {
            stageA(0, nb, aoff_n, khw_n); stageA(2, nb, aoff_n, khw_n);
            __builtin_amdgcn_sched_barrier(0);
            stageA(1, nb, aoff_n, khw_n); stageA(3, nb, aoff_n, khw_n);
        }
#pragma unroll
        for (int mi = 0; mi < 4; ++mi)
#pragma unroll
            for (int qn = 0; qn < 2; ++qn)
#pragma unroll
                for (int ni = 0; ni < 2; ++ni)
#pragma unroll
                    for (int ks = 0; ks < 2; ++ks)
                        acc[4 + mi][qn * 2 + ni] =
                            __builtin_amdgcn_mfma_f32_16x16x32_bf16(
                                af[mi][ks], bfr[qn][ni][ks],
                                acc[4 + mi][qn * 2 + ni], 0, 0, 0);
        if (hn) asm volatile("s_waitcnt vmcnt(2)" ::: "memory");
        __builtin_amdgcn_sched_barrier(0);
        __builtin_amdgcn_s_barrier();

        if (hn) {
            ck_n++;
            if (ck_n == CKT) {
                ck_n = 0; khw_n++; kw_n++;
                if (kw_n == KW) { kw_n = 0; aoff_n += (long)(IW - KW) * CIN + BK; }
                else            { aoff_n += BK; }
                boff_n += (CO - 1) * CIN + BK;
            } else {
                aoff_n += BK; boff_n += BK;
            }
        }
        cur ^= 1;
    }

    // ---- epilogue: bf16 store (D layout col=lane&15, row=(lane>>4)*4+reg) ----
    const int mb = m0 + wm * 128 + lq * 4;
    const int cb = co0 + wn * 64 + lrow;
#pragma unroll
    for (int mi = 0; mi < 8; ++mi)
#pragma unroll
        for (int ni = 0; ni < 4; ++ni)
#pragma unroll
            for (int r = 0; r < 4; ++r)
                out[(size_t)(mb + mi * 16 + r) * CO + (cb + ni * 16)] =
                    f2bf(acc[mi][ni][r]);

    // ---- fused instance-norm partial stats ----
    const int n0 = m0 / OHW;
    const int mS = (n0 + 1) * OHW;           // n-boundary split row
    float sv[2][4], qv[2][4];
#pragma unroll
    for (int g = 0; g < 2; ++g)
#pragma unroll
        for (int ni = 0; ni < 4; ++ni) { sv[g][ni] = 0.f; qv[g][ni] = 0.f; }
#pragma unroll
    for (int mi = 0; mi < 8; ++mi)
#pragma unroll
        for (int ni = 0; ni < 4; ++ni)
#pragma unroll
            for (int r = 0; r < 4; ++r) {
                float v = acc[mi][ni][r];
                int m = mb + mi * 16 + r;
                int g = (m >= mS) ? 1 : 0;
                sv[g][ni] += v; qv[g][ni] += v * v;
            }
    // reduce across the 4 lq groups (lanes ^16, ^32 share column & split)
#pragma unroll
    for (int d = 16; d <= 32; d <<= 1)
#pragma unroll
        for (int g = 0; g < 2; ++g)
#pragma unroll
            for (int ni = 0; ni < 4; ++ni) {
                sv[g][ni] += __shfl_xor(sv[g][ni], d);
                qv[g][ni] += __shfl_xor(qv[g][ni], d);
            }
    if (lq == 0) {
        const bool split = (mS < m0 + 256);
#pragma unroll
        for (int ni = 0; ni < 4; ++ni) {
            atomicAdd(&psum[n0 * CO + cb + ni * 16], sv[0][ni]);
            atomicAdd(&pss [n0 * CO + cb + ni * 16], qv[0][ni]);
            if (split) {
                atomicAdd(&psum[(n0 + 1) * CO + cb + ni * 16], sv[1][ni]);
                atomicAdd(&pss [(n0 + 1) * CO + cb + ni * 16], qv[1][ni]);
            }
        }
    }
}

// ---------------------------------------------------------------------------
// 5) stats finalize: psum/pss -> per-(n,c) affine (a, b)
// ---------------------------------------------------------------------------
__global__ void stats_final_k(const float* __restrict__ psum, const float* __restrict__ pss,
                              const float* __restrict__ g, const float* __restrict__ b,
                              float* __restrict__ aout, float* __restrict__ bout) {
    int idx = blockIdx.x * 256 + threadIdx.x;   // 32*512
    int c = idx & 511;
    float s  = psum[idx];
    float ss = pss[idx];
    float mean = s * (1.0f / 784.0f);
    float var  = ss * (1.0f / 784.0f) - mean * mean;
    float rstd = rsqrtf(var + 1e-5f);
    float a = rstd * g[c];
    aout[idx] = a;
    bout[idx] = b[c] - mean * a;
}

// ---------------------------------------------------------------------------
// 6) apply norm1 + quant_a: bf16 h1 -> bf16 a1 (8-wide)
// ---------------------------------------------------------------------------
__device__ __forceinline__ float qact(float xn) {
    float xc = fminf(fmaxf(xn, 0.f), 1.f);
    return rintf(xc * 255.f) / 255.f;
}

__global__ void norm_quant_k(const ushort_t* __restrict__ h, const float* __restrict__ a_,
                             const float* __restrict__ b_, ushort_t* __restrict__ o) {
    int idx = blockIdx.x * 256 + threadIdx.x;   // over M*512/8
    int row = idx >> 6;
    int c0  = (idx & 63) * 8;
    int n   = row / OHW;
    bf16x8 v = ((const bf16x8*)h)[idx];
    const float* ap = a_ + n * CO + c0;
    const float* bp = b_ + n * CO + c0;
    bf16x8 r;
#pragma unroll
    for (int k = 0; k < 8; ++k) {
        float f = bf2f((ushort_t)v[k]) * ap[k] + bp[k];
        r[k] = (short)f2bf(qact(f));
    }
    ((bf16x8*)o)[idx] = r;
}

// ---------------------------------------------------------------------------
// 7) final: out NCHW f32 = norm2(h2) + normp(s), bf16 in, LDS transpose
// ---------------------------------------------------------------------------
__global__ void final_k(const ushort_t* __restrict__ h2, const ushort_t* __restrict__ s,
                        const float* __restrict__ a2, const float* __restrict__ b2,
                        const float* __restrict__ ap_, const float* __restrict__ bp_,
                        float* __restrict__ out) {
    __shared__ float tile[64][33];
    const int sp0 = blockIdx.x * 32;    // 25 tiles (last covers 16)
    const int c0  = blockIdx.y * 64;    // 8 c-tiles
    const int n   = blockIdx.z;
    const int tx  = threadIdx.x & 31;
    const int ty  = threadIdx.x >> 5;
#pragma unroll
    for (int j = 0; j < 4; ++j) {
        int spl = ty + j * 8;           // 0..31
        int sp  = sp0 + spl;
        if (sp < OHW) {
            int c = c0 + tx * 2;
            size_t ix = ((size_t)n * OHW + sp) * CO + c;
            int ci = n * CO + c;
            ushort2 vh = *(const ushort2*)&h2[ix];
            ushort2 vs = *(const ushort2*)&s[ix];
            tile[tx * 2][spl] =
                bf2f(vh.x) * a2[ci] + b2[ci] + bf2f(vs.x) * ap_[ci] + bp_[ci];
            tile[tx * 2 + 1][spl] =
                bf2f(vh.y) * a2[ci + 1] + b2[ci + 1] + bf2f(vs.y) * ap_[ci + 1] + bp_[ci + 1];
        }
    }
    __syncthreads();
    const int sp = sp0 + tx;
#pragma unroll
    for (int j = 0; j < 8; ++j) {
        int cl = ty + j * 8;            // 0..63
        if (sp < OHW)
            out[((size_t)n * CO + c0 + cl) * OHW + sp] = tile[cl][tx];
    }
}

// ---------------------------------------------------------------------------
extern "C" void kernel_launch(void* const* d_in, const int* in_sizes, int n_in,
                              void* d_out, int out_size, void* d_ws, size_t ws_size,
                              hipStream_t stream) {
    const float* x  = (const float*)d_in[0];
    const float* w1 = (const float*)d_in[1];
    const float* g1 = (const float*)d_in[2];
    const float* b1 = (const float*)d_in[3];
    const float* w2 = (const float*)d_in[4];
    const float* g2 = (const float*)d_in[5];
    const float* b2 = (const float*)d_in[6];
    const float* wp = (const float*)d_in[7];
    const float* gp = (const float*)d_in[8];
    const float* bp = (const float*)d_in[9];
    float* out = (float*)d_out;
    char* ws = (char*)d_ws;

    ushort_t* xh   = (ushort_t*)(ws + OFF_XH);
    ushort_t* a1   = (ushort_t*)(ws + OFF_A1);
    ushort_t* h2   = (ushort_t*)(ws + OFF_H2);
    ushort_t* sbuf = (ushort_t*)(ws + OFF_S);
    ushort_t* wt1  = (ushort_t*)(ws + OFF_WT1);
    ushort_t* wt2  = (ushort_t*)(ws + OFF_WT2);
    ushort_t* wtp  = (ushort_t*)(ws + OFF_WTP);
    float*    psum1 = (float*)(ws + OFF_PSUM);
    float*    pss1  = (float*)(ws + OFF_PSUM + 65536);
    float*    psum2 = (float*)(ws + OFF_PSUM + 131072);
    float*    pss2  = (float*)(ws + OFF_PSUM + 196608);
    float*    psump = (float*)(ws + OFF_PSUM + 262144);
    float*    pssp  = (float*)(ws + OFF_PSUM + 327680);
    float*    a1n  = (float*)(ws + OFF_A1N);
    float*    b1n  = (float*)(ws + OFF_B1N);
    float*    a2n  = (float*)(ws + OFF_A2N);
    float*    b2n  = (float*)(ws + OFF_B2N);
    float*    apn  = (float*)(ws + OFF_APN);
    float*    bpn  = (float*)(ws + OFF_BPN);
    unsigned* mx   = (unsigned*)(ws + OFF_MX);
    ushort_t* zb   = (ushort_t*)(ws + OFF_ZB);
    ushort_t* h1   = (ushort_t*)out;   // d_out doubles as conv1 bf16 scratch
                                       // (dead before final_k writes f32 out)

    hipMemsetAsync(ws + OFF_MX, 0, 16 + 2048, stream);    // absmax + zero page
    hipMemsetAsync(ws + OFF_PSUM, 0, 393216, stream);     // 6 stat buffers

    // layout transform + weight quant
    to_nhwc_k<<<dim3(2, 4, NB * HIN), 256, 0, stream>>>(x, xh);
    absmax_k<<<dim3(512), 256, 0, stream>>>(w1, CO * C_IN * 9, mx + 0);
    absmax_k<<<dim3(512), 256, 0, stream>>>(w2, CO * CO * 9, mx + 1);
    absmax_k<<<dim3(512), 256, 0, stream>>>(wp, C_IN * CO, mx + 2);
    quantw_k<CO, C_IN, 9><<<dim3(4608), 256, 0, stream>>>(w1, mx + 0, wt1);
    quantw_k<CO, CO, 9><<<dim3(9216), 256, 0, stream>>>(w2, mx + 1, wt2);
    quantw_k<CO, C_IN, 1><<<dim3(512), 256, 0, stream>>>(wp, mx + 2, wtp);

    // conv1 (3x3 s2 p1, 256->512) -> h1 bf16 (in d_out) + stats1
    conv8p_k<C_IN, 3, 3, 2, 1, HIN, HIN>
        <<<dim3(196), 512, 0, stream>>>(xh, wt1, h1, zb, psum1, pss1);
    stats_final_k<<<dim3(64), 256, 0, stream>>>(psum1, pss1, g1, b1, a1n, b1n);
    norm_quant_k<<<dim3(MTOT * CO / 8 / 256), 256, 0, stream>>>(h1, a1n, b1n, a1);

    // conv2 (3x3 s1 p1, 512->512) -> h2 bf16 + stats2
    conv8p_k<CO, 3, 3, 1, 1, 28, 28>
        <<<dim3(196), 512, 0, stream>>>(a1, wt2, h2, zb, psum2, pss2);
    // shortcut conv (1x1 s2, 256->512) -> s bf16 + statsp
    conv8p_k<C_IN, 1, 1, 2, 0, HIN, HIN>
        <<<dim3(196), 512, 0, stream>>>(xh, wtp, sbuf, zb, psump, pssp);

    stats_final_k<<<dim3(64), 256, 0, stream>>>(psum2, pss2, g2, b2, a2n, b2n);
    stats_final_k<<<dim3(64), 256, 0, stream>>>(psump, pssp, gp, bp, apn, bpn);

    final_k<<<dim3(25, 8, NB), 256, 0, stream>>>(h2, sbuf, a2n, b2n, apn, bpn, out);
}

// Round 8
// 357.422 us; speedup vs baseline: 1.3891x; 1.0491x over previous
//
#include <hip/hip_runtime.h>
#include <cstdint>
#include <cstddef>

// ---------------------------------------------------------------------------
// QBasicBlock: qconv3x3(s2) -> inorm -> quant_a -> qconv3x3(s1) -> inorm
//            + qconv1x1(s2) -> inorm  (shortcut), output sum, NCHW f32.
// R8: single-barrier K-tile. All 8 stage issues for tile t+1 at the TOP of
//     tile t (full-tile in-flight window >> HBM latency); mid-tile publish
//     removed; regions fuse into one read||MFMA stream; ONE vmcnt(0)+barrier
//     per K-tile. absmax x3 and stats_final x3 merged into single launches.
// ---------------------------------------------------------------------------

typedef unsigned short ushort_t;
typedef __attribute__((ext_vector_type(8))) short bf16x8;
typedef __attribute__((ext_vector_type(4))) float f32x4;

// ---- problem constants ----
#define NB   32
#define C_IN 256
#define HIN  56
#define CO   512
#define OHW  784           // 28*28
#define OWD  28
#define MTOT (NB * OHW)    // 25088

// ---- workspace layout (bytes) ----
constexpr size_t OFF_XH   = 0;                        // x NHWC bf16: 32*56*56*256
constexpr size_t OFF_A1   = OFF_XH  + 51380224;       // a1 NHWC bf16
constexpr size_t OFF_H2   = OFF_A1  + 25690112;       // h2 NHWC bf16
constexpr size_t OFF_S    = OFF_H2  + 51380224;       // shortcut NHWC bf16
constexpr size_t OFF_WT1  = OFF_S   + 51380224;       // wt1 bf16 [9][512][256]
constexpr size_t OFF_WT2  = OFF_WT1 + 2359296;        // wt2 bf16 [9][512][512]
constexpr size_t OFF_WTP  = OFF_WT2 + 4718592;        // wtp bf16 [1][512][256]
constexpr size_t OFF_PSUM = OFF_WTP + 262144;         // 6 x [32][512] f32
constexpr size_t OFF_A1N  = OFF_PSUM + 2097152;       // per-(n,c) affine
constexpr size_t OFF_B1N  = OFF_A1N + 65536;
constexpr size_t OFF_A2N  = OFF_B1N + 65536;
constexpr size_t OFF_B2N  = OFF_A2N + 65536;
constexpr size_t OFF_APN  = OFF_B2N + 65536;
constexpr size_t OFF_BPN  = OFF_APN + 65536;
constexpr size_t OFF_MX   = OFF_BPN + 65536;          // 3 uint absmax slots
constexpr size_t OFF_ZB   = OFF_MX  + 16;             // 2 KiB zero page

// ---- helpers ----
__device__ __forceinline__ ushort_t f2bf(float f) {  // RNE f32->bf16
    unsigned u = __float_as_uint(f);
    u += 0x7FFFu + ((u >> 16) & 1u);
    return (ushort_t)(u >> 16);
}
__device__ __forceinline__ float bf2f(ushort_t u) {
    return __uint_as_float(((unsigned)u) << 16);
}

__device__ __forceinline__ void async_copy16(const void* g, const void* l) {
    auto gp = (const __attribute__((address_space(1))) unsigned int*)(uintptr_t)g;
    auto lp = (__attribute__((address_space(3))) unsigned int*)(unsigned int)(uintptr_t)l;
    __builtin_amdgcn_global_load_lds(gp, lp, 16, 0, 0);
}

// ---------------------------------------------------------------------------
// 1) x NCHW f32 -> NHWC bf16
// ---------------------------------------------------------------------------
__global__ void to_nhwc_k(const float* __restrict__ x, ushort_t* __restrict__ xh) {
    __shared__ float tile[64][33];
    const int wt0 = blockIdx.x * 32;
    const int ct0 = blockIdx.y * 64;
    const int nh  = blockIdx.z;
    const int n = nh / HIN, h = nh - n * HIN;
    {
        const int tx = threadIdx.x & 31;
        const int ty = threadIdx.x >> 5;
        const int w  = wt0 + tx;
#pragma unroll
        for (int j = 0; j < 8; ++j) {
            int cl = ty + j * 8;
            if (w < HIN)
                tile[cl][tx] = x[(((size_t)n * C_IN + ct0 + cl) * HIN + h) * HIN + w];
        }
    }
    __syncthreads();
    {
        const int tc = threadIdx.x & 63;
        const int tw = threadIdx.x >> 6;
#pragma unroll
        for (int j = 0; j < 8; ++j) {
            int wl = tw + j * 4;
            int w  = wt0 + wl;
            if (w < HIN)
                xh[(((size_t)n * HIN + h) * HIN + w) * C_IN + ct0 + tc] =
                    f2bf(tile[tc][wl]);
        }
    }
}

// ---------------------------------------------------------------------------
// 2) per-tensor |w| max — 3 tensors in one launch (blockIdx.y selects)
// ---------------------------------------------------------------------------
__global__ void absmax3_k(const float* __restrict__ w1, int n1,
                          const float* __restrict__ w2, int n2,
                          const float* __restrict__ wp, int np,
                          unsigned* out) {
    const float* w; int nelem;
    if (blockIdx.y == 0)      { w = w1; nelem = n1; }
    else if (blockIdx.y == 1) { w = w2; nelem = n2; }
    else                      { w = wp; nelem = np; }
    int stride = gridDim.x * blockDim.x;
    float m = 0.f;
    for (int i = blockIdx.x * blockDim.x + threadIdx.x; i < nelem; i += stride)
        m = fmaxf(m, fabsf(w[i]));
#pragma unroll
    for (int off = 32; off > 0; off >>= 1)
        m = fmaxf(m, __shfl_down(m, off));
    if ((threadIdx.x & 63) == 0) atomicMax(out + blockIdx.y, __float_as_uint(m));
}

// ---------------------------------------------------------------------------
// 3) weight quant + transform OIHW f32 -> [kh*kw][co][ci] bf16
// ---------------------------------------------------------------------------
template <int CO_, int CI_, int KHW_>
__global__ void quantw_k(const float* __restrict__ w, const unsigned* __restrict__ mx,
                         ushort_t* __restrict__ wt) {
    const int total = KHW_ * CO_ * CI_;
    int idx = blockIdx.x * 256 + threadIdx.x;
    if (idx >= total) return;
    float scale = __uint_as_float(*mx) * (1.0f / 127.0f);
    float inv   = scale > 0.f ? 1.0f / scale : 0.f;
    int khw = idx / (CO_ * CI_);
    int r   = idx - khw * (CO_ * CI_);
    int co  = r / CI_;
    int ci  = r - co * CI_;
    float v  = w[((size_t)co * CI_ + ci) * KHW_ + khw];
    float qv = rintf(v * inv);
    qv = fminf(127.f, fmaxf(-127.f, qv));
    wt[idx] = f2bf(qv * scale);
}

// ---------------------------------------------------------------------------
// 4) single-barrier implicit-GEMM conv + fused stats epilogue, bf16 out.
//    BM=BN=256, BK=64, 8 waves (2M x 4N), per-wave 128x64.
//    Per K-tile t: {issue all 8 stages for t+1} -> sched_bar ->
//    {24 ds_read || 64 MFMA (compiler lgkmcnt interleave)} ->
//    vmcnt(0) [loads issued a full tile ago - cheap] -> barrier.
// ---------------------------------------------------------------------------
template <int CIN, int KH, int KW, int STRIDE, int PAD, int IH, int IW>
__launch_bounds__(512, 2)
__global__ void conv8p_k(const ushort_t* __restrict__ xin,
                         const ushort_t* __restrict__ wt,
                         ushort_t* __restrict__ out,
                         const ushort_t* __restrict__ zbuf,
                         float* __restrict__ psum, float* __restrict__ pss) {
    constexpr int BK  = 64;
    constexpr int CKT = CIN / BK;
    constexpr int KT  = KH * KW * CKT;

    __shared__ alignas(16) short As[2 * 256 * BK];   // 64 KiB
    __shared__ alignas(16) short Bs[2 * 256 * BK];   // 64 KiB

    const int tid  = threadIdx.x;
    const int lane = tid & 63;
    const int wv   = tid >> 6;       // 0..7
    const int wm   = wv >> 2;        // 0..1
    const int wn   = wv & 3;         // 0..3
    const int lrow = lane & 15;
    const int lq   = lane >> 4;      // 0..3
    const int sw   = lrow & 7;

    const int bid = blockIdx.x;
    const int xcd = bid & 7;
    const int j   = bid >> 3;
    const int wg  = (xcd < 4 ? xcd * 25 : 100 + (xcd - 4) * 24) + j;
    const int m0  = (wg >> 1) * 256;
    const int co0 = (wg & 1) * 256;

    const int arow = tid >> 3;        // 0..63
    const int ach  = tid & 7;
    long abase[4]; unsigned amask[4]; int bco[4];
#pragma unroll
    for (int c = 0; c < 4; ++c) {
        int row = c * 64 + arow;
        int m   = m0 + row;
        int n   = m / OHW;
        int sp  = m - n * OHW;
        int oh  = sp / OWD, ow = sp - oh * OWD;
        int ihb = oh * STRIDE - PAD, iwb = ow * STRIDE - PAD;
        int swz = (ach ^ (row & 7)) * 8;
        abase[c] = ((long)n * (IH * IW) + (long)ihb * IW + iwb) * CIN + swz;
        unsigned mk = 0;
#pragma unroll
        for (int kh = 0; kh < KH; ++kh)
#pragma unroll
            for (int kw = 0; kw < KW; ++kw) {
                int ih = ihb + kh, iw = iwb + kw;
                if ((unsigned)ih < (unsigned)IH && (unsigned)iw < (unsigned)IW)
                    mk |= 1u << (kh * KW + kw);
            }
        amask[c] = mk;
        bco[c]   = (co0 + row) * CIN + swz;
    }

    auto stageA = [&](int c, int nb, long aoff, int khw) {
        const ushort_t* src = ((amask[c] >> khw) & 1)
            ? xin + (abase[c] + aoff) : zbuf;
        async_copy16(src, (const void*)&As[nb * 16384 + c * 4096 + wv * 512]);
    };
    auto stageB = [&](int c, int nb, int boff) {
        async_copy16(wt + (boff + bco[c]),
                     (const void*)&Bs[nb * 16384 + c * 4096 + wv * 512]);
    };

    f32x4 acc[8][4];
#pragma unroll
    for (int a = 0; a < 8; ++a)
#pragma unroll
        for (int b = 0; b < 4; ++b) acc[a][b] = {0.f, 0.f, 0.f, 0.f};

    // ---- prologue: stage K-tile 0 into buf0, drain, publish ----
    stageB(0, 0, 0); stageB(1, 0, 0); stageB(2, 0, 0); stageB(3, 0, 0);
    stageA(0, 0, 0, 0); stageA(1, 0, 0, 0); stageA(2, 0, 0, 0); stageA(3, 0, 0, 0);
    asm volatile("s_waitcnt vmcnt(0)" ::: "memory");
    __builtin_amdgcn_s_barrier();

    int  khw_n = 0, kw_n = 0, ck_n = 1;
    long aoff_n = BK;
    int  boff_n = BK;

    int cur = 0;
    for (int t = 0; t < KT; ++t) {
        const bool hn = (t + 1 < KT);
        const int  nb = cur ^ 1;
        const short* Acur = &As[cur * 16384];
        const short* Bcur = &Bs[cur * 16384];

        // ---- top: issue ALL stages for tile t+1 (full tile to land) ----
        if (hn) {
            stageB(0, nb, boff_n); stageB(1, nb, boff_n);
            stageB(2, nb, boff_n); stageB(3, nb, boff_n);
            stageA(0, nb, aoff_n, khw_n); stageA(1, nb, aoff_n, khw_n);
            stageA(2, nb, aoff_n, khw_n); stageA(3, nb, aoff_n, khw_n);
        }
        __builtin_amdgcn_sched_barrier(0);

        bf16x8 af[4][2], bfr[2][2][2];

        // ---- half 1: af0 (chunks 2wm) x all bfr -> acc[0..3] ----
#pragma unroll
        for (int mi = 0; mi < 4; ++mi) {
            const int row = wm * 128 + mi * 16 + lrow;
#pragma unroll
            for (int ks = 0; ks < 2; ++ks) {
                const int ch = ((ks * 4 + lq) ^ sw) * 8;
                af[mi][ks] = *(const bf16x8*)&Acur[row * BK + ch];
            }
        }
#pragma unroll
        for (int qn = 0; qn < 2; ++qn)
#pragma unroll
            for (int ni = 0; ni < 2; ++ni) {
                const int row = wn * 64 + qn * 32 + ni * 16 + lrow;
#pragma unroll
                for (int ks = 0; ks < 2; ++ks) {
                    const int ch = ((ks * 4 + lq) ^ sw) * 8;
                    bfr[qn][ni][ks] = *(const bf16x8*)&Bcur[row * BK + ch];
                }
            }
#pragma unroll
        for (int mi = 0; mi < 4; ++mi)
#pragma unroll
            for (int qn = 0; qn < 2; ++qn)
#pragma unroll
                for (int ni = 0; ni < 2; ++ni)
#pragma unroll
                    for (int ks = 0; ks < 2; ++ks)
                        acc[mi][qn * 2 + ni] =
                            __builtin_amdgcn_mfma_f32_16x16x32_bf16(
                                af[mi][ks], bfr[qn][ni][ks],
                                acc[mi][qn * 2 + ni], 0, 0, 0);

        // ---- half 2: af1 (chunks 2wm+1, resident since tile start) ----
#pragma unroll
        for (int mi = 0; mi < 4; ++mi) {
            const int row = wm * 128 + 64 + mi * 16 + lrow;
#pragma unroll
            for (int ks = 0; ks < 2; ++ks) {
                const int ch = ((ks * 4 + lq) ^ sw) * 8;
                af[mi][ks] = *(const bf16x8*)&Acur[row * BK + ch];
            }
        }
#pragma unroll
        for (int mi = 0; mi < 4; ++mi)
#pragma unroll
            for (int qn = 0; qn < 2; ++qn)
#pragma unroll
                for (int ni = 0; ni < 2; ++ni)
#pragma unroll
                    for (int ks = 0; ks < 2; ++ks)
                        acc[4 + mi][qn * 2 + ni] =
                            __builtin_amdgcn_mfma_f32_16x16x32_bf16(
                                af[mi][ks], bfr[qn][ni][ks],
                                acc[4 + mi][qn * 2 + ni], 0, 0, 0);

        // ---- single publish: t+1's loads landed (issued a full tile ago) ----
        asm volatile("s_waitcnt vmcnt(0)" ::: "memory");
        __builtin_amdgcn_sched_barrier(0);
        __builtin_amdgcn_s_barrier();

        if (hn) {
            ck_n++;
            if (ck_n == CKT) {
                ck_n = 0; khw_n++; kw_n++;
                if (kw_n == KW) { kw_n = 0; aoff_n += (long)(IW - KW) * CIN + BK; }
                else            { aoff_n += BK; }
                boff_n += (CO - 1) * CIN + BK;
            } else {
                aoff_n += BK; boff_n += BK;
            }
        }
        cur ^= 1;
    }

    // ---- epilogue: bf16 store ----
    const int mb = m0 + wm * 128 + lq * 4;
    const int cb = co0 + wn * 64 + lrow;
#pragma unroll
    for (int mi = 0; mi < 8; ++mi)
#pragma unroll
        for (int ni = 0; ni < 4; ++ni)
#pragma unroll
            for (int r = 0; r < 4; ++r)
                out[(size_t)(mb + mi * 16 + r) * CO + (cb + ni * 16)] =
                    f2bf(acc[mi][ni][r]);

    // ---- fused instance-norm partial stats ----
    const int n0 = m0 / OHW;
    const int mS = (n0 + 1) * OHW;
    float sv[2][4], qv[2][4];
#pragma unroll
    for (int g = 0; g < 2; ++g)
#pragma unroll
        for (int ni = 0; ni < 4; ++ni) { sv[g][ni] = 0.f; qv[g][ni] = 0.f; }
#pragma unroll
    for (int mi = 0; mi < 8; ++mi)
#pragma unroll
        for (int ni = 0; ni < 4; ++ni)
#pragma unroll
            for (int r = 0; r < 4; ++r) {
                float v = acc[mi][ni][r];
                int m = mb + mi * 16 + r;
                int g = (m >= mS) ? 1 : 0;
                sv[g][ni] += v; qv[g][ni] += v * v;
            }
#pragma unroll
    for (int d = 16; d <= 32; d <<= 1)
#pragma unroll
        for (int g = 0; g < 2; ++g)
#pragma unroll
            for (int ni = 0; ni < 4; ++ni) {
                sv[g][ni] += __shfl_xor(sv[g][ni], d);
                qv[g][ni] += __shfl_xor(qv[g][ni], d);
            }
    if (lq == 0) {
        const bool split = (mS < m0 + 256);
#pragma unroll
        for (int ni = 0; ni < 4; ++ni) {
            atomicAdd(&psum[n0 * CO + cb + ni * 16], sv[0][ni]);
            atomicAdd(&pss [n0 * CO + cb + ni * 16], qv[0][ni]);
            if (split) {
                atomicAdd(&psum[(n0 + 1) * CO + cb + ni * 16], sv[1][ni]);
                atomicAdd(&pss [(n0 + 1) * CO + cb + ni * 16], qv[1][ni]);
            }
        }
    }
}

// ---------------------------------------------------------------------------
// 5) stats finalize x3 in one launch (blockIdx.y selects tensor)
// ---------------------------------------------------------------------------
__global__ void statsf3_k(const float* __restrict__ ps0, const float* __restrict__ qs0,
                          const float* __restrict__ g0, const float* __restrict__ bb0,
                          float* __restrict__ ao0, float* __restrict__ bo0,
                          const float* __restrict__ ps1, const float* __restrict__ qs1,
                          const float* __restrict__ g1, const float* __restrict__ bb1,
                          float* __restrict__ ao1, float* __restrict__ bo1,
                          const float* __restrict__ ps2, const float* __restrict__ qs2,
                          const float* __restrict__ g2, const float* __restrict__ bb2,
                          float* __restrict__ ao2, float* __restrict__ bo2) {
    const float *ps, *qs, *g, *bb; float *ao, *bo;
    if (blockIdx.y == 0)      { ps = ps0; qs = qs0; g = g0; bb = bb0; ao = ao0; bo = bo0; }
    else if (blockIdx.y == 1) { ps = ps1; qs = qs1; g = g1; bb = bb1; ao = ao1; bo = bo1; }
    else                      { ps = ps2; qs = qs2; g = g2; bb = bb2; ao = ao2; bo = bo2; }
    int idx = blockIdx.x * 256 + threadIdx.x;   // 32*512
    int c = idx & 511;
    float s  = ps[idx];
    float ss = qs[idx];
    float mean = s * (1.0f / 784.0f);
    float var  = ss * (1.0f / 784.0f) - mean * mean;
    float rstd = rsqrtf(var + 1e-5f);
    float a = rstd * g[c];
    ao[idx] = a;
    bo[idx] = bb[c] - mean * a;
}

// ---------------------------------------------------------------------------
// 6) apply norm1 + quant_a: bf16 h1 -> bf16 a1 (8-wide)
// ---------------------------------------------------------------------------
__device__ __forceinline__ float qact(float xn) {
    float xc = fminf(fmaxf(xn, 0.f), 1.f);
    return rintf(xc * 255.f) / 255.f;
}

__global__ void norm_quant_k(const ushort_t* __restrict__ h, const float* __restrict__ a_,
                             const float* __restrict__ b_, ushort_t* __restrict__ o) {
    int idx = blockIdx.x * 256 + threadIdx.x;   // over M*512/8
    int row = idx >> 6;
    int c0  = (idx & 63) * 8;
    int n   = row / OHW;
    bf16x8 v = ((const bf16x8*)h)[idx];
    const float* ap = a_ + n * CO + c0;
    const float* bp = b_ + n * CO + c0;
    bf16x8 r;
#pragma unroll
    for (int k = 0; k < 8; ++k) {
        float f = bf2f((ushort_t)v[k]) * ap[k] + bp[k];
        r[k] = (short)f2bf(qact(f));
    }
    ((bf16x8*)o)[idx] = r;
}

// ---------------------------------------------------------------------------
// 7) final: out NCHW f32 = norm2(h2) + normp(s), bf16 in, LDS transpose
// ---------------------------------------------------------------------------
__global__ void final_k(const ushort_t* __restrict__ h2, const ushort_t* __restrict__ s,
                        const float* __restrict__ a2, const float* __restrict__ b2,
                        const float* __restrict__ ap_, const float* __restrict__ bp_,
                        float* __restrict__ out) {
    __shared__ float tile[64][33];
    const int sp0 = blockIdx.x * 32;    // 25 tiles (last covers 16)
    const int c0  = blockIdx.y * 64;    // 8 c-tiles
    const int n   = blockIdx.z;
    const int tx  = threadIdx.x & 31;
    const int ty  = threadIdx.x >> 5;
#pragma unroll
    for (int j = 0; j < 4; ++j) {
        int spl = ty + j * 8;           // 0..31
        int sp  = sp0 + spl;
        if (sp < OHW) {
            int c = c0 + tx * 2;
            size_t ix = ((size_t)n * OHW + sp) * CO + c;
            int ci = n * CO + c;
            ushort2 vh = *(const ushort2*)&h2[ix];
            ushort2 vs = *(const ushort2*)&s[ix];
            tile[tx * 2][spl] =
                bf2f(vh.x) * a2[ci] + b2[ci] + bf2f(vs.x) * ap_[ci] + bp_[ci];
            tile[tx * 2 + 1][spl] =
                bf2f(vh.y) * a2[ci + 1] + b2[ci + 1] + bf2f(vs.y) * ap_[ci + 1] + bp_[ci + 1];
        }
    }
    __syncthreads();
    const int sp = sp0 + tx;
#pragma unroll
    for (int j = 0; j < 8; ++j) {
        int cl = ty + j * 8;            // 0..63
        if (sp < OHW)
            out[((size_t)n * CO + c0 + cl) * OHW + sp] = tile[cl][tx];
    }
}

// ---------------------------------------------------------------------------
extern "C" void kernel_launch(void* const* d_in, const int* in_sizes, int n_in,
                              void* d_out, int out_size, void* d_ws, size_t ws_size,
                              hipStream_t stream) {
    const float* x  = (const float*)d_in[0];
    const float* w1 = (const float*)d_in[1];
    const float* g1 = (const float*)d_in[2];
    const float* b1 = (const float*)d_in[3];
    const float* w2 = (const float*)d_in[4];
    const float* g2 = (const float*)d_in[5];
    const float* b2 = (const float*)d_in[6];
    const float* wp = (const float*)d_in[7];
    const float* gp = (const float*)d_in[8];
    const float* bp = (const float*)d_in[9];
    float* out = (float*)d_out;
    char* ws = (char*)d_ws;

    ushort_t* xh   = (ushort_t*)(ws + OFF_XH);
    ushort_t* a1   = (ushort_t*)(ws + OFF_A1);
    ushort_t* h2   = (ushort_t*)(ws + OFF_H2);
    ushort_t* sbuf = (ushort_t*)(ws + OFF_S);
    ushort_t* wt1  = (ushort_t*)(ws + OFF_WT1);
    ushort_t* wt2  = (ushort_t*)(ws + OFF_WT2);
    ushort_t* wtp  = (ushort_t*)(ws + OFF_WTP);
    float*    psum1 = (float*)(ws + OFF_PSUM);
    float*    pss1  = (float*)(ws + OFF_PSUM + 65536);
    float*    psum2 = (float*)(ws + OFF_PSUM + 131072);
    float*    pss2  = (float*)(ws + OFF_PSUM + 196608);
    float*    psump = (float*)(ws + OFF_PSUM + 262144);
    float*    pssp  = (float*)(ws + OFF_PSUM + 327680);
    float*    a1n  = (float*)(ws + OFF_A1N);
    float*    b1n  = (float*)(ws + OFF_B1N);
    float*    a2n  = (float*)(ws + OFF_A2N);
    float*    b2n  = (float*)(ws + OFF_B2N);
    float*    apn  = (float*)(ws + OFF_APN);
    float*    bpn  = (float*)(ws + OFF_BPN);
    unsigned* mx   = (unsigned*)(ws + OFF_MX);
    ushort_t* zb   = (ushort_t*)(ws + OFF_ZB);
    ushort_t* h1   = (ushort_t*)out;   // d_out doubles as conv1 bf16 scratch

    hipMemsetAsync(ws + OFF_MX, 0, 16 + 2048, stream);    // absmax + zero page
    hipMemsetAsync(ws + OFF_PSUM, 0, 393216, stream);     // 6 stat buffers

    // layout transform + weight quant
    to_nhwc_k<<<dim3(2, 4, NB * HIN), 256, 0, stream>>>(x, xh);
    absmax3_k<<<dim3(512, 3), 256, 0, stream>>>(w1, CO * C_IN * 9,
                                                w2, CO * CO * 9,
                                                wp, C_IN * CO, mx);
    quantw_k<CO, C_IN, 9><<<dim3(4608), 256, 0, stream>>>(w1, mx + 0, wt1);
    quantw_k<CO, CO, 9><<<dim3(9216), 256, 0, stream>>>(w2, mx + 1, wt2);
    quantw_k<CO, C_IN, 1><<<dim3(512), 256, 0, stream>>>(wp, mx + 2, wtp);

    // conv1 (3x3 s2 p1, 256->512) -> h1 bf16 (in d_out) + stats1
    conv8p_k<C_IN, 3, 3, 2, 1, HIN, HIN>
        <<<dim3(196), 512, 0, stream>>>(xh, wt1, h1, zb, psum1, pss1);
    statsf3_k<<<dim3(64, 1), 256, 0, stream>>>(psum1, pss1, g1, b1, a1n, b1n,
                                               psum1, pss1, g1, b1, a1n, b1n,
                                               psum1, pss1, g1, b1, a1n, b1n);
    norm_quant_k<<<dim3(MTOT * CO / 8 / 256), 256, 0, stream>>>(h1, a1n, b1n, a1);

    // conv2 (3x3 s1 p1, 512->512) -> h2 bf16 + stats2
    conv8p_k<CO, 3, 3, 1, 1, 28, 28>
        <<<dim3(196), 512, 0, stream>>>(a1, wt2, h2, zb, psum2, pss2);
    // shortcut conv (1x1 s2, 256->512) -> s bf16 + statsp
    conv8p_k<C_IN, 1, 1, 2, 0, HIN, HIN>
        <<<dim3(196), 512, 0, stream>>>(xh, wtp, sbuf, zb, psump, pssp);

    statsf3_k<<<dim3(64, 2), 256, 0, stream>>>(psum2, pss2, g2, b2, a2n, b2n,
                                               psump, pssp, gp, bp, apn, bpn,
                                               psum2, pss2, g2, b2, a2n, b2n);

    final_k<<<dim3(25, 8, NB), 256, 0, stream>>>(h2, sbuf, a2n, b2n, apn, bpn, out);
}

// Round 9
// 319.534 us; speedup vs baseline: 1.5538x; 1.1186x over previous
//
#include <hip/hip_runtime.h>
#include <cstdint>
#include <cstddef>

// ---------------------------------------------------------------------------
// QBasicBlock: qconv3x3(s2) -> inorm -> quant_a -> qconv3x3(s1) -> inorm
//            + qconv1x1(s2) -> inorm  (shortcut), output sum, NCHW f32.
// R9: conv2 moved to EXACT int8 MFMA (mfma_i32_16x16x64_i8, 2x bf16 rate):
//     a1 stored as (k-128) i8, wt2 as q i8; conv = sc*dot + 128*sc*T with
//     per-row border correction T from colsum[9][512]. Halves MFMA count,
//     LDS traffic, staging bytes for the largest conv. conv1/convp unchanged.
// ---------------------------------------------------------------------------

typedef unsigned short ushort_t;
typedef __attribute__((ext_vector_type(8))) short bf16x8;
typedef __attribute__((ext_vector_type(4))) float f32x4;
typedef __attribute__((ext_vector_type(4))) int i32x4;

// ---- problem constants ----
#define NB   32
#define C_IN 256
#define HIN  56
#define CO   512
#define OHW  784           // 28*28
#define OWD  28
#define MTOT (NB * OHW)    // 25088

// ---- workspace layout (bytes) ----
constexpr size_t OFF_XH   = 0;                        // x NHWC bf16
constexpr size_t OFF_A1   = OFF_XH  + 51380224;       // a1 NHWC i8 [M][512]
constexpr size_t OFF_H2   = OFF_A1  + 25690112;       // h2 NHWC bf16
constexpr size_t OFF_S    = OFF_H2  + 51380224;       // shortcut NHWC bf16
constexpr size_t OFF_WT1  = OFF_S   + 51380224;       // wt1 bf16 [9][512][256]
constexpr size_t OFF_WT2  = OFF_WT1 + 2359296;        // wt2 i8 [9][512][512]
constexpr size_t OFF_WTP  = OFF_WT2 + 4718592;        // wtp bf16 [1][512][256]
constexpr size_t OFF_PSUM = OFF_WTP + 262144;         // 6 x [32][512] f32
constexpr size_t OFF_A1N  = OFF_PSUM + 2097152;
constexpr size_t OFF_B1N  = OFF_A1N + 65536;
constexpr size_t OFF_A2N  = OFF_B1N + 65536;
constexpr size_t OFF_B2N  = OFF_A2N + 65536;
constexpr size_t OFF_APN  = OFF_B2N + 65536;
constexpr size_t OFF_BPN  = OFF_APN + 65536;
constexpr size_t OFF_MX   = OFF_BPN + 65536;          // 3 uint absmax slots
constexpr size_t OFF_ZB   = OFF_MX  + 16;             // 2 KiB zero page
constexpr size_t OFF_CS   = OFF_ZB  + 2048;           // colsum f32 [9][512]

// ---- helpers ----
__device__ __forceinline__ ushort_t f2bf(float f) {  // RNE f32->bf16
    unsigned u = __float_as_uint(f);
    u += 0x7FFFu + ((u >> 16) & 1u);
    return (ushort_t)(u >> 16);
}
__device__ __forceinline__ float bf2f(ushort_t u) {
    return __uint_as_float(((unsigned)u) << 16);
}

__device__ __forceinline__ void async_copy16(const void* g, const void* l) {
    auto gp = (const __attribute__((address_space(1))) unsigned int*)(uintptr_t)g;
    auto lp = (__attribute__((address_space(3))) unsigned int*)(unsigned int)(uintptr_t)l;
    __builtin_amdgcn_global_load_lds(gp, lp, 16, 0, 0);
}

// ---------------------------------------------------------------------------
// 1) x NCHW f32 -> NHWC bf16
// ---------------------------------------------------------------------------
__global__ void to_nhwc_k(const float* __restrict__ x, ushort_t* __restrict__ xh) {
    __shared__ float tile[64][33];
    const int wt0 = blockIdx.x * 32;
    const int ct0 = blockIdx.y * 64;
    const int nh  = blockIdx.z;
    const int n = nh / HIN, h = nh - n * HIN;
    {
        const int tx = threadIdx.x & 31;
        const int ty = threadIdx.x >> 5;
        const int w  = wt0 + tx;
#pragma unroll
        for (int j = 0; j < 8; ++j) {
            int cl = ty + j * 8;
            if (w < HIN)
                tile[cl][tx] = x[(((size_t)n * C_IN + ct0 + cl) * HIN + h) * HIN + w];
        }
    }
    __syncthreads();
    {
        const int tc = threadIdx.x & 63;
        const int tw = threadIdx.x >> 6;
#pragma unroll
        for (int j = 0; j < 8; ++j) {
            int wl = tw + j * 4;
            int w  = wt0 + wl;
            if (w < HIN)
                xh[(((size_t)n * HIN + h) * HIN + w) * C_IN + ct0 + tc] =
                    f2bf(tile[tc][wl]);
        }
    }
}

// ---------------------------------------------------------------------------
// 2) per-tensor |w| max — 3 tensors in one launch
// ---------------------------------------------------------------------------
__global__ void absmax3_k(const float* __restrict__ w1, int n1,
                          const float* __restrict__ w2, int n2,
                          const float* __restrict__ wp, int np,
                          unsigned* out) {
    const float* w; int nelem;
    if (blockIdx.y == 0)      { w = w1; nelem = n1; }
    else if (blockIdx.y == 1) { w = w2; nelem = n2; }
    else                      { w = wp; nelem = np; }
    int stride = gridDim.x * blockDim.x;
    float m = 0.f;
    for (int i = blockIdx.x * blockDim.x + threadIdx.x; i < nelem; i += stride)
        m = fmaxf(m, fabsf(w[i]));
#pragma unroll
    for (int off = 32; off > 0; off >>= 1)
        m = fmaxf(m, __shfl_down(m, off));
    if ((threadIdx.x & 63) == 0) atomicMax(out + blockIdx.y, __float_as_uint(m));
}

// ---------------------------------------------------------------------------
// 3a) weight quant bf16: OIHW f32 -> [khw][co][ci] bf16 (conv1, convp)
// ---------------------------------------------------------------------------
template <int CO_, int CI_, int KHW_>
__global__ void quantw_k(const float* __restrict__ w, const unsigned* __restrict__ mx,
                         ushort_t* __restrict__ wt) {
    const int total = KHW_ * CO_ * CI_;
    int idx = blockIdx.x * 256 + threadIdx.x;
    if (idx >= total) return;
    float scale = __uint_as_float(*mx) * (1.0f / 127.0f);
    float inv   = scale > 0.f ? 1.0f / scale : 0.f;
    int khw = idx / (CO_ * CI_);
    int r   = idx - khw * (CO_ * CI_);
    int co  = r / CI_;
    int ci  = r - co * CI_;
    float v  = w[((size_t)co * CI_ + ci) * KHW_ + khw];
    float qv = rintf(v * inv);
    qv = fminf(127.f, fmaxf(-127.f, qv));
    wt[idx] = f2bf(qv * scale);
}

// 3b) weight quant i8 (conv2): OIHW f32 -> [khw][co][ci] signed char q
__global__ void quantw_i8_k(const float* __restrict__ w, const unsigned* __restrict__ mx,
                            signed char* __restrict__ wt) {
    const int total = 9 * CO * CO;
    int idx = blockIdx.x * 256 + threadIdx.x;
    if (idx >= total) return;
    float scale = __uint_as_float(*mx) * (1.0f / 127.0f);
    float inv   = scale > 0.f ? 1.0f / scale : 0.f;
    int khw = idx / (CO * CO);
    int r   = idx - khw * (CO * CO);
    int co  = r / CO;
    int ci  = r - co * CO;
    float v  = w[((size_t)co * CO + ci) * 9 + khw];
    float qv = rintf(v * inv);
    qv = fminf(127.f, fmaxf(-127.f, qv));
    wt[idx] = (signed char)(int)qv;
}

// 3c) colsum[khw][co] = sum_ci q  (f32), for the +128 offset correction
__global__ void colsum_k(const signed char* __restrict__ wt, float* __restrict__ cs) {
    const int khw = blockIdx.x;                 // 0..8
    const int co  = blockIdx.y * 32 + (threadIdx.x & 31);
    const int cig = threadIdx.x >> 5;           // 0..7
    const signed char* p = wt + ((size_t)khw * CO + co) * CO + cig * 64;
    int s = 0;
#pragma unroll
    for (int i = 0; i < 64; ++i) s += p[i];
    __shared__ int red[8][32];
    red[cig][threadIdx.x & 31] = s;
    __syncthreads();
    if (cig == 0) {
        int tot = 0;
#pragma unroll
        for (int g = 0; g < 8; ++g) tot += red[g][threadIdx.x & 31];
        cs[khw * CO + co] = (float)tot;
    }
}

// ---------------------------------------------------------------------------
// 4a) bf16 conv (R8 single-barrier schedule) — conv1 & convp, unchanged
// ---------------------------------------------------------------------------
template <int CIN, int KH, int KW, int STRIDE, int PAD, int IH, int IW>
__launch_bounds__(512, 2)
__global__ void conv8p_k(const ushort_t* __restrict__ xin,
                         const ushort_t* __restrict__ wt,
                         ushort_t* __restrict__ out,
                         const ushort_t* __restrict__ zbuf,
                         float* __restrict__ psum, float* __restrict__ pss) {
    constexpr int BK  = 64;
    constexpr int CKT = CIN / BK;
    constexpr int KT  = KH * KW * CKT;

    __shared__ alignas(16) short As[2 * 256 * BK];
    __shared__ alignas(16) short Bs[2 * 256 * BK];

    const int tid  = threadIdx.x;
    const int lane = tid & 63;
    const int wv   = tid >> 6;
    const int wm   = wv >> 2;
    const int wn   = wv & 3;
    const int lrow = lane & 15;
    const int lq   = lane >> 4;
    const int sw   = lrow & 7;

    const int bid = blockIdx.x;
    const int xcd = bid & 7;
    const int j   = bid >> 3;
    const int wg  = (xcd < 4 ? xcd * 25 : 100 + (xcd - 4) * 24) + j;
    const int m0  = (wg >> 1) * 256;
    const int co0 = (wg & 1) * 256;

    const int arow = tid >> 3;
    const int ach  = tid & 7;
    long abase[4]; unsigned amask[4]; int bco[4];
#pragma unroll
    for (int c = 0; c < 4; ++c) {
        int row = c * 64 + arow;
        int m   = m0 + row;
        int n   = m / OHW;
        int sp  = m - n * OHW;
        int oh  = sp / OWD, ow = sp - oh * OWD;
        int ihb = oh * STRIDE - PAD, iwb = ow * STRIDE - PAD;
        int swz = (ach ^ (row & 7)) * 8;
        abase[c] = ((long)n * (IH * IW) + (long)ihb * IW + iwb) * CIN + swz;
        unsigned mk = 0;
#pragma unroll
        for (int kh = 0; kh < KH; ++kh)
#pragma unroll
            for (int kw = 0; kw < KW; ++kw) {
                int ih = ihb + kh, iw = iwb + kw;
                if ((unsigned)ih < (unsigned)IH && (unsigned)iw < (unsigned)IW)
                    mk |= 1u << (kh * KW + kw);
            }
        amask[c] = mk;
        bco[c]   = (co0 + row) * CIN + swz;
    }

    auto stageA = [&](int c, int nb, long aoff, int khw) {
        const ushort_t* src = ((amask[c] >> khw) & 1)
            ? xin + (abase[c] + aoff) : zbuf;
        async_copy16(src, (const void*)&As[nb * 16384 + c * 4096 + wv * 512]);
    };
    auto stageB = [&](int c, int nb, int boff) {
        async_copy16(wt + (boff + bco[c]),
                     (const void*)&Bs[nb * 16384 + c * 4096 + wv * 512]);
    };

    f32x4 acc[8][4];
#pragma unroll
    for (int a = 0; a < 8; ++a)
#pragma unroll
        for (int b = 0; b < 4; ++b) acc[a][b] = {0.f, 0.f, 0.f, 0.f};

    stageB(0, 0, 0); stageB(1, 0, 0); stageB(2, 0, 0); stageB(3, 0, 0);
    stageA(0, 0, 0, 0); stageA(1, 0, 0, 0); stageA(2, 0, 0, 0); stageA(3, 0, 0, 0);
    asm volatile("s_waitcnt vmcnt(0)" ::: "memory");
    __builtin_amdgcn_s_barrier();

    int  khw_n = 0, kw_n = 0, ck_n = 1;
    long aoff_n = BK;
    int  boff_n = BK;

    int cur = 0;
    for (int t = 0; t < KT; ++t) {
        const bool hn = (t + 1 < KT);
        const int  nb = cur ^ 1;
        const short* Acur = &As[cur * 16384];
        const short* Bcur = &Bs[cur * 16384];

        if (hn) {
            stageB(0, nb, boff_n); stageB(1, nb, boff_n);
            stageB(2, nb, boff_n); stageB(3, nb, boff_n);
            stageA(0, nb, aoff_n, khw_n); stageA(1, nb, aoff_n, khw_n);
            stageA(2, nb, aoff_n, khw_n); stageA(3, nb, aoff_n, khw_n);
        }
        __builtin_amdgcn_sched_barrier(0);

        bf16x8 af[4][2], bfr[2][2][2];

#pragma unroll
        for (int mi = 0; mi < 4; ++mi) {
            const int row = wm * 128 + mi * 16 + lrow;
#pragma unroll
            for (int ks = 0; ks < 2; ++ks) {
                const int ch = ((ks * 4 + lq) ^ sw) * 8;
                af[mi][ks] = *(const bf16x8*)&Acur[row * BK + ch];
            }
        }
#pragma unroll
        for (int qn = 0; qn < 2; ++qn)
#pragma unroll
            for (int ni = 0; ni < 2; ++ni) {
                const int row = wn * 64 + qn * 32 + ni * 16 + lrow;
#pragma unroll
                for (int ks = 0; ks < 2; ++ks) {
                    const int ch = ((ks * 4 + lq) ^ sw) * 8;
                    bfr[qn][ni][ks] = *(const bf16x8*)&Bcur[row * BK + ch];
                }
            }
#pragma unroll
        for (int mi = 0; mi < 4; ++mi)
#pragma unroll
            for (int qn = 0; qn < 2; ++qn)
#pragma unroll
                for (int ni = 0; ni < 2; ++ni)
#pragma unroll
                    for (int ks = 0; ks < 2; ++ks)
                        acc[mi][qn * 2 + ni] =
                            __builtin_amdgcn_mfma_f32_16x16x32_bf16(
                                af[mi][ks], bfr[qn][ni][ks],
                                acc[mi][qn * 2 + ni], 0, 0, 0);

#pragma unroll
        for (int mi = 0; mi < 4; ++mi) {
            const int row = wm * 128 + 64 + mi * 16 + lrow;
#pragma unroll
            for (int ks = 0; ks < 2; ++ks) {
                const int ch = ((ks * 4 + lq) ^ sw) * 8;
                af[mi][ks] = *(const bf16x8*)&Acur[row * BK + ch];
            }
        }
#pragma unroll
        for (int mi = 0; mi < 4; ++mi)
#pragma unroll
            for (int qn = 0; qn < 2; ++qn)
#pragma unroll
                for (int ni = 0; ni < 2; ++ni)
#pragma unroll
                    for (int ks = 0; ks < 2; ++ks)
                        acc[4 + mi][qn * 2 + ni] =
                            __builtin_amdgcn_mfma_f32_16x16x32_bf16(
                                af[mi][ks], bfr[qn][ni][ks],
                                acc[4 + mi][qn * 2 + ni], 0, 0, 0);

        asm volatile("s_waitcnt vmcnt(0)" ::: "memory");
        __builtin_amdgcn_sched_barrier(0);
        __builtin_amdgcn_s_barrier();

        if (hn) {
            ck_n++;
            if (ck_n == CKT) {
                ck_n = 0; khw_n++; kw_n++;
                if (kw_n == KW) { kw_n = 0; aoff_n += (long)(IW - KW) * CIN + BK; }
                else            { aoff_n += BK; }
                boff_n += (CO - 1) * CIN + BK;
            } else {
                aoff_n += BK; boff_n += BK;
            }
        }
        cur ^= 1;
    }

    const int mb = m0 + wm * 128 + lq * 4;
    const int cb = co0 + wn * 64 + lrow;
#pragma unroll
    for (int mi = 0; mi < 8; ++mi)
#pragma unroll
        for (int ni = 0; ni < 4; ++ni)
#pragma unroll
            for (int r = 0; r < 4; ++r)
                out[(size_t)(mb + mi * 16 + r) * CO + (cb + ni * 16)] =
                    f2bf(acc[mi][ni][r]);

    const int n0 = m0 / OHW;
    const int mS = (n0 + 1) * OHW;
    float sv[2][4], qv[2][4];
#pragma unroll
    for (int g = 0; g < 2; ++g)
#pragma unroll
        for (int ni = 0; ni < 4; ++ni) { sv[g][ni] = 0.f; qv[g][ni] = 0.f; }
#pragma unroll
    for (int mi = 0; mi < 8; ++mi)
#pragma unroll
        for (int ni = 0; ni < 4; ++ni)
#pragma unroll
            for (int r = 0; r < 4; ++r) {
                float v = acc[mi][ni][r];
                int m = mb + mi * 16 + r;
                int g = (m >= mS) ? 1 : 0;
                sv[g][ni] += v; qv[g][ni] += v * v;
            }
#pragma unroll
    for (int d = 16; d <= 32; d <<= 1)
#pragma unroll
        for (int g = 0; g < 2; ++g)
#pragma unroll
            for (int ni = 0; ni < 4; ++ni) {
                sv[g][ni] += __shfl_xor(sv[g][ni], d);
                qv[g][ni] += __shfl_xor(qv[g][ni], d);
            }
    if (lq == 0) {
        const bool split = (mS < m0 + 256);
#pragma unroll
        for (int ni = 0; ni < 4; ++ni) {
            atomicAdd(&psum[n0 * CO + cb + ni * 16], sv[0][ni]);
            atomicAdd(&pss [n0 * CO + cb + ni * 16], qv[0][ni]);
            if (split) {
                atomicAdd(&psum[(n0 + 1) * CO + cb + ni * 16], sv[1][ni]);
                atomicAdd(&pss [(n0 + 1) * CO + cb + ni * 16], qv[1][ni]);
            }
        }
    }
}

// ---------------------------------------------------------------------------
// 4b) INT8 conv2 (3x3 s1 p1, 512->512): exact integer MFMA + offset fixup.
//     A = a1 (k-128 i8), B = wt2 (q i8). BK=64 (i8), 16x16x64 MFMA,
//     32 MFMA/wave/K-tile, 12 ds_read_b128, 4 stage issues. Single-barrier
//     schedule. Epilogue: val = sc*dot + 128*sc*T(m,co), T via colsum.
// ---------------------------------------------------------------------------
__launch_bounds__(512, 2)
__global__ void conv_i8_k(const signed char* __restrict__ xin,
                          const signed char* __restrict__ wt,
                          const float* __restrict__ colsum,
                          const unsigned* __restrict__ mxp,
                          ushort_t* __restrict__ out,
                          const signed char* __restrict__ zbuf,
                          float* __restrict__ psum, float* __restrict__ pss) {
    constexpr int CIN = 512, BK = 64, CKT = 8, KT = 72;
    constexpr int IH = 28, IW = 28;

    __shared__ alignas(16) signed char As[2 * 256 * BK];   // 32 KiB
    __shared__ alignas(16) signed char Bs[2 * 256 * BK];   // 32 KiB

    const int tid  = threadIdx.x;
    const int lane = tid & 63;
    const int wv   = tid >> 6;
    const int wm   = wv >> 2;
    const int wn   = wv & 3;
    const int lrow = lane & 15;
    const int lq   = lane >> 4;

    const int bid = blockIdx.x;
    const int xcd = bid & 7;
    const int j   = bid >> 3;
    const int wg  = (xcd < 4 ? xcd * 25 : 100 + (xcd - 4) * 24) + j;
    const int m0  = (wg >> 1) * 256;
    const int co0 = (wg & 1) * 256;

    // slots: g = i*512+tid, row = g>>2 (i*128 + tid>>2), ch = g&3 (16B chunks)
    const int arow2 = tid >> 2;       // 0..127
    const int ach2  = tid & 3;
    long abase[2]; unsigned amask[2]; int bco[2];
#pragma unroll
    for (int c = 0; c < 2; ++c) {
        int row = c * 128 + arow2;
        int m   = m0 + row;
        int n   = m / OHW;
        int sp  = m - n * OHW;
        int oh  = sp / OWD, ow = sp - oh * OWD;
        int ihb = oh - 1, iwb = ow - 1;
        int swz = (ach2 ^ (row & 3)) * 16;       // pre-swizzled 16B chunk
        abase[c] = ((long)n * (IH * IW) + (long)ihb * IW + iwb) * CIN + swz;
        unsigned mk = 0;
#pragma unroll
        for (int kh = 0; kh < 3; ++kh)
#pragma unroll
            for (int kw = 0; kw < 3; ++kw) {
                int ih = ihb + kh, iw = iwb + kw;
                if ((unsigned)ih < (unsigned)IH && (unsigned)iw < (unsigned)IW)
                    mk |= 1u << (kh * 3 + kw);
            }
        amask[c] = mk;
        bco[c]   = (co0 + row) * CIN + swz;
    }

    auto stageA = [&](int c, int nb, long aoff, int khw) {
        const signed char* src = ((amask[c] >> khw) & 1)
            ? xin + (abase[c] + aoff) : zbuf;
        async_copy16(src, (const void*)&As[nb * 16384 + c * 8192 + wv * 1024]);
    };
    auto stageB = [&](int c, int nb, int boff) {
        async_copy16(wt + (boff + bco[c]),
                     (const void*)&Bs[nb * 16384 + c * 8192 + wv * 1024]);
    };

    i32x4 acc[8][4];
#pragma unroll
    for (int a = 0; a < 8; ++a)
#pragma unroll
        for (int b = 0; b < 4; ++b) acc[a][b] = {0, 0, 0, 0};

    // prologue
    stageB(0, 0, 0); stageB(1, 0, 0);
    stageA(0, 0, 0, 0); stageA(1, 0, 0, 0);
    asm volatile("s_waitcnt vmcnt(0)" ::: "memory");
    __builtin_amdgcn_s_barrier();

    int  khw_n = 0, kw_n = 0, ck_n = 1;
    long aoff_n = BK;
    int  boff_n = BK;

    int cur = 0;
    for (int t = 0; t < KT; ++t) {
        const bool hn = (t + 1 < KT);
        const int  nb = cur ^ 1;
        const signed char* Acur = &As[cur * 16384];
        const signed char* Bcur = &Bs[cur * 16384];

        if (hn) {
            stageB(0, nb, boff_n); stageB(1, nb, boff_n);
            stageA(0, nb, aoff_n, khw_n); stageA(1, nb, aoff_n, khw_n);
        }
        __builtin_amdgcn_sched_barrier(0);

        i32x4 af[8], bfr[4];
#pragma unroll
        for (int mi = 0; mi < 8; ++mi) {
            const int row = wm * 128 + mi * 16 + lrow;
            const int byt = row * BK + ((lq ^ (row & 3)) * 16);
            af[mi] = *(const i32x4*)&Acur[byt];
        }
#pragma unroll
        for (int ni = 0; ni < 4; ++ni) {
            const int row = wn * 64 + ni * 16 + lrow;
            const int byt = row * BK + ((lq ^ (row & 3)) * 16);
            bfr[ni] = *(const i32x4*)&Bcur[byt];
        }
#pragma unroll
        for (int mi = 0; mi < 8; ++mi)
#pragma unroll
            for (int ni = 0; ni < 4; ++ni)
                acc[mi][ni] = __builtin_amdgcn_mfma_i32_16x16x64_i8(
                    af[mi], bfr[ni], acc[mi][ni], 0, 0, 0);

        asm volatile("s_waitcnt vmcnt(0)" ::: "memory");
        __builtin_amdgcn_sched_barrier(0);
        __builtin_amdgcn_s_barrier();

        if (hn) {
            ck_n++;
            if (ck_n == CKT) {
                ck_n = 0; khw_n++; kw_n++;
                if (kw_n == 3) { kw_n = 0; aoff_n += (long)(IW - 3) * CIN + BK; }
                else           { aoff_n += BK; }
                boff_n += (CO - 1) * CIN + BK;
            } else {
                aoff_n += BK; boff_n += BK;
            }
        }
        cur ^= 1;
    }

    // ---- epilogue: dequant + border fixup + bf16 store + fused stats ----
    const int mb = m0 + wm * 128 + lq * 4;
    const int cb = co0 + wn * 64 + lrow;
    const float scale = __uint_as_float(*mxp) * (1.0f / 127.0f);
    const float sc    = scale * (1.0f / 255.0f);
    const float c128  = 128.0f * sc;

    // per-ni colsum aggregates (all-taps, row0/2, col0/2, corners)
    float Sall[4], Sr0[4], Sr2[4], Sc0[4], Sc2[4], K0[4], K2[4], K6[4], K8[4];
#pragma unroll
    for (int ni = 0; ni < 4; ++ni) {
        float cs[9];
#pragma unroll
        for (int k = 0; k < 9; ++k) cs[k] = colsum[k * CO + cb + ni * 16];
        Sall[ni] = cs[0]+cs[1]+cs[2]+cs[3]+cs[4]+cs[5]+cs[6]+cs[7]+cs[8];
        Sr0[ni] = cs[0]+cs[1]+cs[2];  Sr2[ni] = cs[6]+cs[7]+cs[8];
        Sc0[ni] = cs[0]+cs[3]+cs[6];  Sc2[ni] = cs[2]+cs[5]+cs[8];
        K0[ni] = cs[0]; K2[ni] = cs[2]; K6[ni] = cs[6]; K8[ni] = cs[8];
    }

    const int n0 = m0 / OHW;
    const int mS = (n0 + 1) * OHW;
    float sv[2][4], qvv[2][4];
#pragma unroll
    for (int g = 0; g < 2; ++g)
#pragma unroll
        for (int ni = 0; ni < 4; ++ni) { sv[g][ni] = 0.f; qvv[g][ni] = 0.f; }

#pragma unroll
    for (int mi = 0; mi < 8; ++mi)
#pragma unroll
        for (int r = 0; r < 4; ++r) {
            const int m  = mb + mi * 16 + r;
            const int n  = m / OHW;
            const int sp = m - n * OHW;
            const int oh = sp / OWD, ow = sp - oh * OWD;
            const int g  = (m >= mS) ? 1 : 0;
#pragma unroll
            for (int ni = 0; ni < 4; ++ni) {
                float T = Sall[ni];
                if (oh == 0)       T -= Sr0[ni];
                if (oh == OWD - 1) T -= Sr2[ni];
                if (ow == 0)       T -= Sc0[ni];
                if (ow == OWD - 1) T -= Sc2[ni];
                if (oh == 0 && ow == 0)             T += K0[ni];
                if (oh == 0 && ow == OWD - 1)       T += K2[ni];
                if (oh == OWD - 1 && ow == 0)       T += K6[ni];
                if (oh == OWD - 1 && ow == OWD - 1) T += K8[ni];
                float val = sc * (float)acc[mi][ni][r] + c128 * T;
                out[(size_t)m * CO + (cb + ni * 16)] = f2bf(val);
                sv[g][ni] += val; qvv[g][ni] += val * val;
            }
        }
#pragma unroll
    for (int d = 16; d <= 32; d <<= 1)
#pragma unroll
        for (int g = 0; g < 2; ++g)
#pragma unroll
            for (int ni = 0; ni < 4; ++ni) {
                sv[g][ni]  += __shfl_xor(sv[g][ni], d);
                qvv[g][ni] += __shfl_xor(qvv[g][ni], d);
            }
    if (lq == 0) {
        const bool split = (mS < m0 + 256);
#pragma unroll
        for (int ni = 0; ni < 4; ++ni) {
            atomicAdd(&psum[n0 * CO + cb + ni * 16], sv[0][ni]);
            atomicAdd(&pss [n0 * CO + cb + ni * 16], qvv[0][ni]);
            if (split) {
                atomicAdd(&psum[(n0 + 1) * CO + cb + ni * 16], sv[1][ni]);
                atomicAdd(&pss [(n0 + 1) * CO + cb + ni * 16], qvv[1][ni]);
            }
        }
    }
}

// ---------------------------------------------------------------------------
// 5) stats finalize x3 in one launch
// ---------------------------------------------------------------------------
__global__ void statsf3_k(const float* __restrict__ ps0, const float* __restrict__ qs0,
                          const float* __restrict__ g0, const float* __restrict__ bb0,
                          float* __restrict__ ao0, float* __restrict__ bo0,
                          const float* __restrict__ ps1, const float* __restrict__ qs1,
                          const float* __restrict__ g1, const float* __restrict__ bb1,
                          float* __restrict__ ao1, float* __restrict__ bo1,
                          const float* __restrict__ ps2, const float* __restrict__ qs2,
                          const float* __restrict__ g2, const float* __restrict__ bb2,
                          float* __restrict__ ao2, float* __restrict__ bo2) {
    const float *ps, *qs, *g, *bb; float *ao, *bo;
    if (blockIdx.y == 0)      { ps = ps0; qs = qs0; g = g0; bb = bb0; ao = ao0; bo = bo0; }
    else if (blockIdx.y == 1) { ps = ps1; qs = qs1; g = g1; bb = bb1; ao = ao1; bo = bo1; }
    else                      { ps = ps2; qs = qs2; g = g2; bb = bb2; ao = ao2; bo = bo2; }
    int idx = blockIdx.x * 256 + threadIdx.x;
    int c = idx & 511;
    float s  = ps[idx];
    float ss = qs[idx];
    float mean = s * (1.0f / 784.0f);
    float var  = ss * (1.0f / 784.0f) - mean * mean;
    float rstd = rsqrtf(var + 1e-5f);
    float a = rstd * g[c];
    ao[idx] = a;
    bo[idx] = bb[c] - mean * a;
}

// ---------------------------------------------------------------------------
// 6) apply norm1 + quant_a: bf16 h1 -> i8 (k-128) a1
// ---------------------------------------------------------------------------
__global__ void norm_quant_i8_k(const ushort_t* __restrict__ h, const float* __restrict__ a_,
                                const float* __restrict__ b_, signed char* __restrict__ o) {
    int idx = blockIdx.x * 256 + threadIdx.x;   // over M*512/8
    int row = idx >> 6;
    int c0  = (idx & 63) * 8;
    int n   = row / OHW;
    bf16x8 v = ((const bf16x8*)h)[idx];
    const float* ap = a_ + n * CO + c0;
    const float* bp = b_ + n * CO + c0;
    unsigned lo = 0, hi = 0;
#pragma unroll
    for (int k = 0; k < 8; ++k) {
        float f = bf2f((ushort_t)v[k]) * ap[k] + bp[k];
        float kq = rintf(fminf(fmaxf(f, 0.f), 1.f) * 255.f);
        int s8 = (int)kq - 128;
        unsigned b = (unsigned)(s8 & 0xFF);
        if (k < 4) lo |= b << (8 * k);
        else       hi |= b << (8 * (k - 4));
    }
    ((uint2*)o)[idx] = make_uint2(lo, hi);
}

// ---------------------------------------------------------------------------
// 7) final: out NCHW f32 = norm2(h2) + normp(s), bf16 in, LDS transpose
// ---------------------------------------------------------------------------
__global__ void final_k(const ushort_t* __restrict__ h2, const ushort_t* __restrict__ s,
                        const float* __restrict__ a2, const float* __restrict__ b2,
                        const float* __restrict__ ap_, const float* __restrict__ bp_,
                        float* __restrict__ out) {
    __shared__ float tile[64][33];
    const int sp0 = blockIdx.x * 32;
    const int c0  = blockIdx.y * 64;
    const int n   = blockIdx.z;
    const int tx  = threadIdx.x & 31;
    const int ty  = threadIdx.x >> 5;
#pragma unroll
    for (int j = 0; j < 4; ++j) {
        int spl = ty + j * 8;
        int sp  = sp0 + spl;
        if (sp < OHW) {
            int c = c0 + tx * 2;
            size_t ix = ((size_t)n * OHW + sp) * CO + c;
            int ci = n * CO + c;
            ushort2 vh = *(const ushort2*)&h2[ix];
            ushort2 vs = *(const ushort2*)&s[ix];
            tile[tx * 2][spl] =
                bf2f(vh.x) * a2[ci] + b2[ci] + bf2f(vs.x) * ap_[ci] + bp_[ci];
            tile[tx * 2 + 1][spl] =
                bf2f(vh.y) * a2[ci + 1] + b2[ci + 1] + bf2f(vs.y) * ap_[ci + 1] + bp_[ci + 1];
        }
    }
    __syncthreads();
    const int sp = sp0 + tx;
#pragma unroll
    for (int j = 0; j < 8; ++j) {
        int cl = ty + j * 8;
        if (sp < OHW)
            out[((size_t)n * CO + c0 + cl) * OHW + sp] = tile[cl][tx];
    }
}

// ---------------------------------------------------------------------------
extern "C" void kernel_launch(void* const* d_in, const int* in_sizes, int n_in,
                              void* d_out, int out_size, void* d_ws, size_t ws_size,
                              hipStream_t stream) {
    const float* x  = (const float*)d_in[0];
    const float* w1 = (const float*)d_in[1];
    const float* g1 = (const float*)d_in[2];
    const float* b1 = (const float*)d_in[3];
    const float* w2 = (const float*)d_in[4];
    const float* g2 = (const float*)d_in[5];
    const float* b2 = (const float*)d_in[6];
    const float* wp = (const float*)d_in[7];
    const float* gp = (const float*)d_in[8];
    const float* bp = (const float*)d_in[9];
    float* out = (float*)d_out;
    char* ws = (char*)d_ws;

    ushort_t*    xh    = (ushort_t*)(ws + OFF_XH);
    signed char* a1    = (signed char*)(ws + OFF_A1);
    ushort_t*    h2    = (ushort_t*)(ws + OFF_H2);
    ushort_t*    sbuf  = (ushort_t*)(ws + OFF_S);
    ushort_t*    wt1   = (ushort_t*)(ws + OFF_WT1);
    signed char* wt2i  = (signed char*)(ws + OFF_WT2);
    ushort_t*    wtp   = (ushort_t*)(ws + OFF_WTP);
    float*    psum1 = (float*)(ws + OFF_PSUM);
    float*    pss1  = (float*)(ws + OFF_PSUM + 65536);
    float*    psum2 = (float*)(ws + OFF_PSUM + 131072);
    float*    pss2  = (float*)(ws + OFF_PSUM + 196608);
    float*    psump = (float*)(ws + OFF_PSUM + 262144);
    float*    pssp  = (float*)(ws + OFF_PSUM + 327680);
    float*    a1n  = (float*)(ws + OFF_A1N);
    float*    b1n  = (float*)(ws + OFF_B1N);
    float*    a2n  = (float*)(ws + OFF_A2N);
    float*    b2n  = (float*)(ws + OFF_B2N);
    float*    apn  = (float*)(ws + OFF_APN);
    float*    bpn  = (float*)(ws + OFF_BPN);
    unsigned* mx   = (unsigned*)(ws + OFF_MX);
    ushort_t* zb   = (ushort_t*)(ws + OFF_ZB);
    float*    cs   = (float*)(ws + OFF_CS);
    ushort_t* h1   = (ushort_t*)out;   // d_out doubles as conv1 bf16 scratch

    hipMemsetAsync(ws + OFF_MX, 0, 16 + 2048, stream);    // absmax + zero page
    hipMemsetAsync(ws + OFF_PSUM, 0, 393216, stream);     // 6 stat buffers

    to_nhwc_k<<<dim3(2, 4, NB * HIN), 256, 0, stream>>>(x, xh);
    absmax3_k<<<dim3(512, 3), 256, 0, stream>>>(w1, CO * C_IN * 9,
                                                w2, CO * CO * 9,
                                                wp, C_IN * CO, mx);
    quantw_k<CO, C_IN, 9><<<dim3(4608), 256, 0, stream>>>(w1, mx + 0, wt1);
    quantw_i8_k<<<dim3(9216), 256, 0, stream>>>(w2, mx + 1, wt2i);
    quantw_k<CO, C_IN, 1><<<dim3(512), 256, 0, stream>>>(wp, mx + 2, wtp);
    colsum_k<<<dim3(9, 16), 256, 0, stream>>>(wt2i, cs);

    // conv1 (bf16) -> h1 + stats1
    conv8p_k<C_IN, 3, 3, 2, 1, HIN, HIN>
        <<<dim3(196), 512, 0, stream>>>(xh, wt1, h1, (const ushort_t*)zb, psum1, pss1);
    statsf3_k<<<dim3(64, 1), 256, 0, stream>>>(psum1, pss1, g1, b1, a1n, b1n,
                                               psum1, pss1, g1, b1, a1n, b1n,
                                               psum1, pss1, g1, b1, a1n, b1n);
    norm_quant_i8_k<<<dim3(MTOT * CO / 8 / 256), 256, 0, stream>>>(h1, a1n, b1n, a1);

    // conv2 (i8 exact) -> h2 + stats2
    conv_i8_k<<<dim3(196), 512, 0, stream>>>(a1, wt2i, cs, mx + 1, h2,
                                             (const signed char*)zb, psum2, pss2);
    // shortcut conv (bf16) -> s + statsp
    conv8p_k<C_IN, 1, 1, 2, 0, HIN, HIN>
        <<<dim3(196), 512, 0, stream>>>(xh, wtp, sbuf, (const ushort_t*)zb, psump, pssp);

    statsf3_k<<<dim3(64, 2), 256, 0, stream>>>(psum2, pss2, g2, b2, a2n, b2n,
                                               psump, pssp, gp, bp, apn, bpn,
                                               psum2, pss2, g2, b2, a2n, b2n);

    final_k<<<dim3(25, 8, NB), 256, 0, stream>>>(h2, sbuf, a2n, b2n, apn, bpn, out);
}